// Round 5
// baseline (738.985 us; speedup 1.0000x reference)
//
#include <hip/hip_runtime.h>
#include <hip/hip_bf16.h>
#include <math.h>

// ---------------------------------------------------------------------------
// B=4, L_IN=1024, D=512, H=8, DK=64, DFF=2048, NL=4, WINDOW=[4,4,4], INNER=5.
// all_size=[1024,256,64,16], L_tot=1360, rows M=5440 padded to M_PAD=5504.
// ---------------------------------------------------------------------------

typedef __attribute__((ext_vector_type(8))) short short8;
typedef __attribute__((ext_vector_type(4))) float f32x4;

__device__ inline ushort f2bf(float x) {
  union { __hip_bfloat16 h; ushort u; } cv; cv.h = __float2bfloat16(x); return cv.u;
}
__device__ inline float bf2f(ushort u) {
  union { unsigned int i; float f; } cv; cv.i = (unsigned)u << 16; return cv.f;
}
__device__ inline float lo16(unsigned u) { union { unsigned i; float f; } c; c.i = u << 16; return c.f; }
__device__ inline float hi16(unsigned u) { union { unsigned i; float f; } c; c.i = u & 0xffff0000u; return c.f; }

// tanh-form GELU (max |err| vs exact erf-GELU ~3e-3; well within budget)
__device__ inline float gelu_f(float x) {
  float y = 0.7978845608028654f * (x + 0.044715f * x * x * x);
  float t = __expf(-2.0f * y);
  float th = (1.0f - t) / (1.0f + t);
  return 0.5f * x * (1.0f + th);
}

#define GLD16(gp, lp)                                                        \
  __builtin_amdgcn_global_load_lds(                                          \
      (const __attribute__((address_space(1))) void*)(gp),                   \
      (__attribute__((address_space(3))) void*)(lp), 16, 0, 0)

// ---------------- embed: circular conv3 + posenc + mark projection ---------
__global__ __launch_bounds__(512) void embed_kernel(
    const float* __restrict__ x_enc, const float* __restrict__ x_mark,
    const float* __restrict__ conv_w, const float* __restrict__ conv_b,
    const float* __restrict__ temp_w, const float* __restrict__ temp_b,
    float* __restrict__ e) {
  int bl = blockIdx.x;
  int b = bl >> 10, l = bl & 1023;
  int d = threadIdx.x;
  int lm1 = (l + 1023) & 1023;
  int lp1 = (l + 1) & 1023;
  const float* w  = conv_w + d * 21;
  const float* x0 = x_enc + (size_t)(b * 1024 + lm1) * 7;
  const float* x1 = x_enc + (size_t)(b * 1024 + l)   * 7;
  const float* x2 = x_enc + (size_t)(b * 1024 + lp1) * 7;
  float acc = conv_b[d];
#pragma unroll
  for (int ci = 0; ci < 7; ci++) {
    acc = fmaf(x0[ci], w[ci * 3 + 0], acc);
    acc = fmaf(x1[ci], w[ci * 3 + 1], acc);
    acc = fmaf(x2[ci], w[ci * 3 + 2], acc);
  }
  int j = d >> 1;
  float dv = expf((float)(2 * j) * (-9.210340371976184f / 512.0f));
  float ang = (float)l * dv;
  float pe = (d & 1) ? cosf(ang) : sinf(ang);
  const float* xm = x_mark + (size_t)(b * 1024 + l) * 4;
  float mk = temp_b[d];
  mk = fmaf(xm[0], temp_w[d],        mk);
  mk = fmaf(xm[1], temp_w[512 + d],  mk);
  mk = fmaf(xm[2], temp_w[1024 + d], mk);
  mk = fmaf(xm[3], temp_w[1536 + d], mk);
  e[(size_t)bl * 512 + d] = acc + pe + mk;
}

// ---------------- weight cast+transpose: f32 [K][N] -> bf16 [N][K] ---------
__global__ __launch_bounds__(256) void transpose_cast(
    const float* __restrict__ src, ushort* __restrict__ dst,
    int K, int N, size_t src_lstride, size_t dst_lstride) {
  src += (size_t)blockIdx.z * src_lstride;
  dst += (size_t)blockIdx.z * dst_lstride;
  __shared__ float t[32][33];
  int k0 = blockIdx.y * 32, n0 = blockIdx.x * 32;
  int tx = threadIdx.x, ty = threadIdx.y;  // (32,8)
#pragma unroll
  for (int i = 0; i < 4; i++)
    t[ty + i * 8][tx] = src[(size_t)(k0 + ty + i * 8) * N + n0 + tx];
  __syncthreads();
#pragma unroll
  for (int i = 0; i < 4; i++)
    dst[(size_t)(n0 + ty + i * 8) * K + k0 + tx] = f2bf(t[tx][ty + i * 8]);
}

// ---------------- bf16 MFMA GEMM, 128x128 tile, 3-buffer counted-vmcnt -----
// A: [M_pad][K] bf16.  Bt: [N][K] bf16 (pre-transposed).  act 1 = GELU.
// Pipeline: stage(t) 2 tiles ahead; per step wait OWN vmcnt(4) (tile-t loads
// done, t+1 in flight) -> s_barrier (collective: all waves' t-loads done AND
// all finished compute(t-1), so restaging buf[(t-1)%3] is race-free) ->
// stage(t+2) -> compute(t). vmcnt never drains to 0 in steady state.
__global__ __launch_bounds__(256) void gemm_bf16(
    const ushort* __restrict__ A, const ushort* __restrict__ Bt,
    const float* __restrict__ bias, void* __restrict__ C,
    int N, int K, int act, int out_bf16) {
  __shared__ short As[3][4096];   // 3 x (128 x 32)
  __shared__ short Bs[3][4096];
  int tid = threadIdx.x;
  int w = tid >> 6, lane = tid & 63;
  int bm = blockIdx.y << 7, bn = blockIdx.x << 7;
  const short* Ab = (const short*)A + (size_t)(bm + (tid >> 2)) * K + (tid & 3) * 8;
  const short* Bb = (const short*)Bt + (size_t)(bn + (tid >> 2)) * K + (tid & 3) * 8;
  int ldsw = (tid & 192) * 8;          // wave-uniform: w*512 shorts
  int wr = (w >> 1) << 6, wc = (w & 1) << 6;
  int lr = lane & 15, kg = lane >> 4;
  f32x4 acc[4][4] = {};
  int nt = K >> 5;
#define STAGE128(t, buf) do { int kt_ = (t) << 5;                            \
    GLD16(Ab + kt_,                  &As[buf][ldsw]);                        \
    GLD16(Ab + kt_ + (size_t)64 * K, &As[buf][2048 + ldsw]);                 \
    GLD16(Bb + kt_,                  &Bs[buf][ldsw]);                        \
    GLD16(Bb + kt_ + (size_t)64 * K, &Bs[buf][2048 + ldsw]); } while (0)
  STAGE128(0, 0);
  STAGE128(1, 1);
  for (int t = 0; t < nt; t++) {
    int cur = t % 3;
    if (t + 1 < nt) asm volatile("s_waitcnt vmcnt(4)" ::: "memory");
    else            asm volatile("s_waitcnt vmcnt(0)" ::: "memory");
    __builtin_amdgcn_s_barrier();
    __builtin_amdgcn_sched_barrier(0);
    if (t + 2 < nt) STAGE128(t + 2, (t + 2) % 3);
    __builtin_amdgcn_sched_barrier(0);
    short8 a_[4], b_[4];
#pragma unroll
    for (int m = 0; m < 4; m++)
      a_[m] = *(const short8*)&As[cur][(wr + m * 16 + lr) * 32 + kg * 8];
#pragma unroll
    for (int n = 0; n < 4; n++)
      b_[n] = *(const short8*)&Bs[cur][(wc + n * 16 + lr) * 32 + kg * 8];
#pragma unroll
    for (int m = 0; m < 4; m++)
#pragma unroll
      for (int n = 0; n < 4; n++)
        acc[m][n] = __builtin_amdgcn_mfma_f32_16x16x32_bf16(a_[m], b_[n], acc[m][n], 0, 0, 0);
  }
#undef STAGE128
  int r0 = bm + wr + kg * 4;
  int c0 = bn + wc + lr;
#pragma unroll
  for (int m = 0; m < 4; m++) {
#pragma unroll
    for (int n = 0; n < 4; n++) {
      int col = c0 + n * 16;
      float bv = bias ? bias[col] : 0.0f;
#pragma unroll
      for (int j = 0; j < 4; j++) {
        int row = r0 + m * 16 + j;
        float v = acc[m][n][j] + bv;
        if (act == 1) v = gelu_f(v);
        if (out_bf16) ((ushort*)C)[(size_t)row * N + col] = f2bf(v);
        else          ((float*)C)[(size_t)row * N + col] = v;
      }
    }
  }
}

// ---------------- bf16 MFMA GEMM, 64x64 tile, 3-buffer counted-vmcnt -------
__global__ __launch_bounds__(256) void gemm_bf16_t64(
    const ushort* __restrict__ A, const ushort* __restrict__ Bt,
    const float* __restrict__ bias, void* __restrict__ C,
    int N, int K, int out_bf16) {
  __shared__ short As[3][2048];   // 3 x (64 x 32)
  __shared__ short Bs[3][2048];
  int tid = threadIdx.x;
  int w = tid >> 6, lane = tid & 63;
  int bm = blockIdx.y << 6, bn = blockIdx.x << 6;
  const short* Ab = (const short*)A + (size_t)(bm + (tid >> 2)) * K + (tid & 3) * 8;
  const short* Bb = (const short*)Bt + (size_t)(bn + (tid >> 2)) * K + (tid & 3) * 8;
  int ldsw = w * 512;                  // wave-uniform base (shorts)
  int wr = (w >> 1) << 5, wc = (w & 1) << 5;
  int lr = lane & 15, kg = lane >> 4;
  f32x4 acc[2][2] = {};
  int nt = K >> 5;
#define STAGE64(t, buf) do { int kt_ = (t) << 5;                             \
    GLD16(Ab + kt_, &As[buf][ldsw]);                                         \
    GLD16(Bb + kt_, &Bs[buf][ldsw]); } while (0)
  STAGE64(0, 0);
  STAGE64(1, 1);
  for (int t = 0; t < nt; t++) {
    int cur = t % 3;
    if (t + 1 < nt) asm volatile("s_waitcnt vmcnt(2)" ::: "memory");
    else            asm volatile("s_waitcnt vmcnt(0)" ::: "memory");
    __builtin_amdgcn_s_barrier();
    __builtin_amdgcn_sched_barrier(0);
    if (t + 2 < nt) STAGE64(t + 2, (t + 2) % 3);
    __builtin_amdgcn_sched_barrier(0);
    short8 a_[2], b_[2];
#pragma unroll
    for (int m = 0; m < 2; m++)
      a_[m] = *(const short8*)&As[cur][(wr + m * 16 + lr) * 32 + kg * 8];
#pragma unroll
    for (int n = 0; n < 2; n++)
      b_[n] = *(const short8*)&Bs[cur][(wc + n * 16 + lr) * 32 + kg * 8];
#pragma unroll
    for (int m = 0; m < 2; m++)
#pragma unroll
      for (int n = 0; n < 2; n++)
        acc[m][n] = __builtin_amdgcn_mfma_f32_16x16x32_bf16(a_[m], b_[n], acc[m][n], 0, 0, 0);
  }
#undef STAGE64
  int r0 = bm + wr + kg * 4;
  int c0 = bn + wc + lr;
#pragma unroll
  for (int m = 0; m < 2; m++) {
#pragma unroll
    for (int n = 0; n < 2; n++) {
      int col = c0 + n * 16;
      float bv = bias ? bias[col] : 0.0f;
#pragma unroll
      for (int j = 0; j < 4; j++) {
        int row = r0 + m * 16 + j;
        float v = acc[m][n][j] + bv;
        if (out_bf16) ((ushort*)C)[(size_t)row * N + col] = f2bf(v);
        else          ((float*)C)[(size_t)row * N + col] = v;
      }
    }
  }
}

// ---------------- small f32 GEMM (down / up projections) -------------------
__global__ __launch_bounds__(256) void gemm_f32(
    const float* __restrict__ A, const float* __restrict__ B,
    const float* __restrict__ bias, float* __restrict__ C,
    int M, int N, int K) {
  __shared__ float As[16][68];
  __shared__ float Bs[16][64];
  int tid = threadIdx.x;
  int tx = tid & 15, ty = tid >> 4;
  int bm = blockIdx.y << 6, bn = blockIdx.x << 6;
  const float* Ab = A + (size_t)bm * K;
  const float* Bb = B + bn;
  float acc[4][4] = {};
  for (int kt = 0; kt < K; kt += 16) {
#pragma unroll
    for (int r = 0; r < 4; r++) {
      int e2 = r * 256 + tid;
      As[e2 & 15][e2 >> 4] = Ab[(size_t)(e2 >> 4) * K + kt + (e2 & 15)];
    }
#pragma unroll
    for (int r = 0; r < 4; r++) {
      int e2 = r * 256 + tid;
      Bs[e2 >> 6][e2 & 63] = Bb[(size_t)(kt + (e2 >> 6)) * N + (e2 & 63)];
    }
    __syncthreads();
#pragma unroll
    for (int kk = 0; kk < 16; kk++) {
      float a0 = As[kk][(ty << 2) + 0], a1 = As[kk][(ty << 2) + 1];
      float a2 = As[kk][(ty << 2) + 2], a3 = As[kk][(ty << 2) + 3];
      float b0 = Bs[kk][(tx << 2) + 0], b1 = Bs[kk][(tx << 2) + 1];
      float b2 = Bs[kk][(tx << 2) + 2], b3 = Bs[kk][(tx << 2) + 3];
      acc[0][0] = fmaf(a0, b0, acc[0][0]); acc[0][1] = fmaf(a0, b1, acc[0][1]);
      acc[0][2] = fmaf(a0, b2, acc[0][2]); acc[0][3] = fmaf(a0, b3, acc[0][3]);
      acc[1][0] = fmaf(a1, b0, acc[1][0]); acc[1][1] = fmaf(a1, b1, acc[1][1]);
      acc[1][2] = fmaf(a1, b2, acc[1][2]); acc[1][3] = fmaf(a1, b3, acc[1][3]);
      acc[2][0] = fmaf(a2, b0, acc[2][0]); acc[2][1] = fmaf(a2, b1, acc[2][1]);
      acc[2][2] = fmaf(a2, b2, acc[2][2]); acc[2][3] = fmaf(a2, b3, acc[2][3]);
      acc[3][0] = fmaf(a3, b0, acc[3][0]); acc[3][1] = fmaf(a3, b1, acc[3][1]);
      acc[3][2] = fmaf(a3, b2, acc[3][2]); acc[3][3] = fmaf(a3, b3, acc[3][3]);
    }
    __syncthreads();
  }
#pragma unroll
  for (int i2 = 0; i2 < 4; i2++) {
    int row = bm + (ty << 2) + i2;
#pragma unroll
    for (int j2 = 0; j2 < 4; j2++) {
      int col = bn + (tx << 2) + j2;
      C[(size_t)row * N + col] = acc[i2][j2] + (bias ? bias[col] : 0.0f);
    }
  }
}

// ---------------- pyramid conv level ---------------------------------------
__global__ __launch_bounds__(64) void pyr_conv(
    const float* __restrict__ in, int in_base, int in_bstr,
    float* __restrict__ out, int out_base, int out_bstr, int out_len,
    const float* __restrict__ w, const float* __restrict__ bias,
    const float* __restrict__ bng, const float* __restrict__ bnb) {
  int blk = blockIdx.x;
  int b = blk / out_len, to = blk - b * out_len;
  int co = threadIdx.x;
  __shared__ float xin[4][64];
  const float* src = in + (size_t)(b * in_bstr + in_base + 4 * to) * 64;
#pragma unroll
  for (int r2 = 0; r2 < 4; r2++) xin[r2][co] = src[r2 * 64 + co];
  __syncthreads();
  const float* wr = w + (size_t)co * 256;
  float acc = bias[co];
#pragma unroll 16
  for (int ci = 0; ci < 64; ci++) {
    acc = fmaf(xin[0][ci], wr[ci * 4 + 0], acc);
    acc = fmaf(xin[1][ci], wr[ci * 4 + 1], acc);
    acc = fmaf(xin[2][ci], wr[ci * 4 + 2], acc);
    acc = fmaf(xin[3][ci], wr[ci * 4 + 3], acc);
  }
  float y = fmaf(bng[co], acc, bnb[co]);
  y = y > 0.0f ? y : expm1f(y);
  out[(size_t)(b * out_bstr + out_base + to) * 64 + co] = y;
}

// ---------------- LayerNorm over concat([embed, pyr_up]); dual output ------
__global__ __launch_bounds__(256) void ln_concat(
    const float* __restrict__ e, const float* __restrict__ pyru,
    const float* __restrict__ g, const float* __restrict__ bta,
    float* __restrict__ seq, ushort* __restrict__ seq_bf) {
  int r = blockIdx.x;
  int b = r / 1360, i = r - b * 1360;
  int tid = threadIdx.x;
  const float* src = (i < 1024)
      ? (e    + (size_t)(b * 1024 + i) * 512)
      : (pyru + (size_t)(b * 336 + (i - 1024)) * 512);
  float v0 = src[tid], v1 = src[tid + 256];
  __shared__ float red[256];
  red[tid] = v0 + v1;
  __syncthreads();
  for (int st = 128; st > 0; st >>= 1) { if (tid < st) red[tid] += red[tid + st]; __syncthreads(); }
  float mu = red[0] * (1.0f / 512.0f);
  __syncthreads();
  float d0 = v0 - mu, d1 = v1 - mu;
  red[tid] = d0 * d0 + d1 * d1;
  __syncthreads();
  for (int st = 128; st > 0; st >>= 1) { if (tid < st) red[tid] += red[tid + st]; __syncthreads(); }
  float inv = rsqrtf(red[0] * (1.0f / 512.0f) + 1e-5f);
  float o0 = d0 * inv * g[tid]       + bta[tid];
  float o1 = d1 * inv * g[tid + 256] + bta[tid + 256];
  float* dst = seq + (size_t)r * 512;
  dst[tid] = o0; dst[tid + 256] = o1;
  ushort* dbf = seq_bf + (size_t)r * 512;
  dbf[tid] = f2bf(o0); dbf[tid + 256] = f2bf(o1);
}

// ---------------- residual add + LayerNorm (in-place), dual output ---------
__global__ __launch_bounds__(256) void ln_add(
    float* __restrict__ seq, const float* __restrict__ t1,
    const float* __restrict__ g, const float* __restrict__ bta,
    ushort* __restrict__ seq_bf) {
  int r = blockIdx.x;
  int tid = threadIdx.x;
  float* row = seq + (size_t)r * 512;
  const float* trow = t1 + (size_t)r * 512;
  float v0 = row[tid] + trow[tid];
  float v1 = row[tid + 256] + trow[tid + 256];
  __shared__ float red[256];
  red[tid] = v0 + v1;
  __syncthreads();
  for (int st = 128; st > 0; st >>= 1) { if (tid < st) red[tid] += red[tid + st]; __syncthreads(); }
  float mu = red[0] * (1.0f / 512.0f);
  __syncthreads();
  float d0 = v0 - mu, d1 = v1 - mu;
  red[tid] = d0 * d0 + d1 * d1;
  __syncthreads();
  for (int st = 128; st > 0; st >>= 1) { if (tid < st) red[tid] += red[tid + st]; __syncthreads(); }
  float inv = rsqrtf(red[0] * (1.0f / 512.0f) + 1e-5f);
  float o0 = d0 * inv * g[tid]       + bta[tid];
  float o1 = d1 * inv * g[tid + 256] + bta[tid + 256];
  row[tid] = o0; row[tid + 256] = o1;
  ushort* dbf = seq_bf + (size_t)r * 512;
  dbf[tid] = f2bf(o0); dbf[tid + 256] = f2bf(o1);
}

// ---------------- sparse pyramidal attention (bf16 qkv in, bf16 o out) -----
__global__ __launch_bounds__(512) void attn_sparse(
    const ushort* __restrict__ qkv, ushort* __restrict__ o) {
  int r = blockIdx.x;
  int b = r / 1360, i = r - b * 1360;
  int h = threadIdx.x >> 6, lane = threadIdx.x & 63;
  __shared__ float sc[8][16];
  __shared__ int keys_s[16];
  __shared__ int nk_s;
  if (threadIdx.x == 0) {
    int S, sz, li;
    if (i < 1024)      { li = 0; S = 0;    sz = 1024; }
    else if (i < 1280) { li = 1; S = 1024; sz = 256; }
    else if (i < 1344) { li = 2; S = 1280; sz = 64; }
    else               { li = 3; S = 1344; sz = 16; }
    int p = i - S;
    int nk = 0;
    int lo = p - 2; if (lo < 0) lo = 0;
    int hi = p + 2; if (hi > sz - 1) hi = sz - 1;
    for (int j2 = lo; j2 <= hi; j2++) keys_s[nk++] = S + j2;
    if (li > 0) {
      int Sprev = (li == 1) ? 0 : (li == 2) ? 1024 : 1280;
      int cb = Sprev + 4 * p;
      keys_s[nk++] = cb; keys_s[nk++] = cb + 1;
      keys_s[nk++] = cb + 2; keys_s[nk++] = cb + 3;
    }
    if (li < 3) {
      int Snext = (li == 0) ? 1024 : (li == 1) ? 1280 : 1344;
      keys_s[nk++] = Snext + (p >> 2);
    }
    nk_s = nk;
  }
  __syncthreads();
  int nk = nk_s;
  if (lane < nk) {
    const uint4* qv = (const uint4*)(qkv + (size_t)r * 1536 + h * 64);
    const uint4* kv = (const uint4*)(qkv + (size_t)(b * 1360 + keys_s[lane]) * 1536 + 512 + h * 64);
    float s = 0.0f;
#pragma unroll
    for (int c = 0; c < 8; c++) {
      uint4 a = qv[c], k4 = kv[c];
      s = fmaf(lo16(a.x), lo16(k4.x), s); s = fmaf(hi16(a.x), hi16(k4.x), s);
      s = fmaf(lo16(a.y), lo16(k4.y), s); s = fmaf(hi16(a.y), hi16(k4.y), s);
      s = fmaf(lo16(a.z), lo16(k4.z), s); s = fmaf(hi16(a.z), hi16(k4.z), s);
      s = fmaf(lo16(a.w), lo16(k4.w), s); s = fmaf(hi16(a.w), hi16(k4.w), s);
    }
    sc[h][lane] = s * 0.125f;
  }
  __syncthreads();
  float m = -1e30f;
  for (int j2 = 0; j2 < nk; j2++) m = fmaxf(m, sc[h][j2]);
  float denom = 0.0f;
  for (int j2 = 0; j2 < nk; j2++) denom += expf(sc[h][j2] - m);
  float inv = 1.0f / denom;
  float acc = 0.0f;
  for (int j2 = 0; j2 < nk; j2++) {
    float pj = expf(sc[h][j2] - m) * inv;
    float vv = bf2f(qkv[(size_t)(b * 1360 + keys_s[j2]) * 1536 + 1024 + h * 64 + lane]);
    acc = fmaf(pj, vv, acc);
  }
  o[(size_t)r * 512 + h * 64 + lane] = f2bf(acc);
}

// ---------------- output gather --------------------------------------------
__global__ __launch_bounds__(512) void gather_out(
    const float* __restrict__ seq, float* __restrict__ out) {
  int bl = blockIdx.x;
  int b = bl >> 10, i = bl & 1023;
  int d = threadIdx.x;
  size_t ob = (size_t)bl * 2048 + d;
  size_t base = (size_t)b * 1360;
  out[ob]        = seq[(base + i) * 512 + d];
  out[ob + 512]  = seq[(base + 1024 + (i >> 2)) * 512 + d];
  out[ob + 1024] = seq[(base + 1280 + (i >> 4)) * 512 + d];
  out[ob + 1536] = seq[(base + 1344 + (i >> 6)) * 512 + d];
}

// ---------------------------------------------------------------------------
extern "C" void kernel_launch(void* const* d_in, const int* in_sizes, int n_in,
                              void* d_out, int out_size, void* d_ws, size_t ws_size,
                              hipStream_t stream) {
  const float* x_enc   = (const float*)d_in[0];
  const float* x_mark  = (const float*)d_in[1];
  const float* conv_w  = (const float*)d_in[2];
  const float* conv_b  = (const float*)d_in[3];
  const float* temp_w  = (const float*)d_in[4];
  const float* temp_b  = (const float*)d_in[5];
  const float* down_w  = (const float*)d_in[6];
  const float* down_b  = (const float*)d_in[7];
  const float* pyr_w   = (const float*)d_in[8];
  const float* pyr_b   = (const float*)d_in[9];
  const float* bn_g    = (const float*)d_in[10];
  const float* bn_b    = (const float*)d_in[11];
  const float* up_w    = (const float*)d_in[12];
  const float* up_b    = (const float*)d_in[13];
  const float* norm_g  = (const float*)d_in[14];
  const float* norm_b  = (const float*)d_in[15];
  const float* wq      = (const float*)d_in[16];
  const float* wk      = (const float*)d_in[17];
  const float* wv      = (const float*)d_in[18];
  const float* fc_w    = (const float*)d_in[19];
  const float* fc_b    = (const float*)d_in[20];
  const float* ln1_g   = (const float*)d_in[21];
  const float* ln1_b   = (const float*)d_in[22];
  const float* w1      = (const float*)d_in[23];
  const float* b1      = (const float*)d_in[24];
  const float* w2      = (const float*)d_in[25];
  const float* b2      = (const float*)d_in[26];
  const float* ln2_g   = (const float*)d_in[27];
  const float* ln2_b   = (const float*)d_in[28];

  // ---- workspace layout (f32-word offsets); total 18,972,672 words = 72.4MB
  float* ws = (float*)d_ws;
  float*  e      = ws;                         // 2,097,152 w
  float*  tmp0   = ws + 2097152;               //   262,144 w
  float*  pyrf   = ws + 2359296;               //    86,016 w
  float*  pyru   = ws + 2445312;               //   688,128 w
  ushort* qkv_bf = (ushort*)ws;                // [5504][1536] bf16
  ushort* o_bf   = (ushort*)(ws + 4227072);    // [5504][512] bf16
  ushort* th_bf  = (ushort*)ws;                // [5504][2048] bf16
  float*  t1     = ws + 5636096;               // [5504][512] f32
  float*  seq    = ws + 8454144;               // [5504][512] f32
  ushort* seq_bf = (ushort*)(ws + 11272192);   // [5504][512] bf16
  ushort* qkvw   = (ushort*)(ws + 12681216);   // 4 x [1536][512] bf16
  ushort* fcw    = (ushort*)(ws + 14254080);   // 4 x [512][512] bf16
  ushort* w1t    = (ushort*)(ws + 14778368);   // 4 x [2048][512] bf16
  ushort* w2t    = (ushort*)(ws + 16875520);   // 4 x [512][2048] bf16

  // ---- weight cast+transpose (once per call) ----
  dim3 tb(32, 8);
  transpose_cast<<<dim3(16, 16, 4), tb, 0, stream>>>(wq, qkvw,          512, 512,  262144, 786432);
  transpose_cast<<<dim3(16, 16, 4), tb, 0, stream>>>(wk, qkvw + 262144, 512, 512,  262144, 786432);
  transpose_cast<<<dim3(16, 16, 4), tb, 0, stream>>>(wv, qkvw + 524288, 512, 512,  262144, 786432);
  transpose_cast<<<dim3(16, 16, 4), tb, 0, stream>>>(fc_w, fcw,         512, 512,  262144, 262144);
  transpose_cast<<<dim3(64, 16, 4), tb, 0, stream>>>(w1, w1t,           512, 2048, 1048576, 1048576);
  transpose_cast<<<dim3(16, 64, 4), tb, 0, stream>>>(w2, w2t,           2048, 512, 1048576, 1048576);

  // ---- prologue ----
  embed_kernel<<<4096, 512, 0, stream>>>(x_enc, x_mark, conv_w, conv_b,
                                         temp_w, temp_b, e);
  gemm_f32<<<dim3(1, 64), 256, 0, stream>>>(e, down_w, down_b, tmp0, 4096, 64, 512);
  pyr_conv<<<4 * 256, 64, 0, stream>>>(tmp0, 0, 1024, pyrf, 0, 336, 256,
                                       pyr_w, pyr_b, bn_g, bn_b);
  pyr_conv<<<4 * 64, 64, 0, stream>>>(pyrf, 0, 336, pyrf, 256, 336, 64,
                                      pyr_w + 16384, pyr_b + 64, bn_g + 64, bn_b + 64);
  pyr_conv<<<4 * 16, 64, 0, stream>>>(pyrf, 256, 336, pyrf, 320, 336, 16,
                                      pyr_w + 32768, pyr_b + 128, bn_g + 128, bn_b + 128);
  gemm_f32<<<dim3(8, 21), 256, 0, stream>>>(pyrf, up_w, up_b, pyru, 1344, 512, 64);
  ln_concat<<<5440, 256, 0, stream>>>(e, pyru, norm_g, norm_b, seq, seq_bf);

  // ---- layers ----
  for (int l = 0; l < 4; l++) {
    gemm_bf16<<<dim3(12, 43), 256, 0, stream>>>(seq_bf, qkvw + (size_t)l * 786432,
                                                nullptr, qkv_bf, 1536, 512, 0, 1);
    attn_sparse<<<5440, 512, 0, stream>>>(qkv_bf, o_bf);
    gemm_bf16_t64<<<dim3(8, 86), 256, 0, stream>>>(o_bf, fcw + (size_t)l * 262144,
                                                   fc_b + l * 512, t1, 512, 512, 0);
    ln_add<<<5440, 256, 0, stream>>>(seq, t1, ln1_g + l * 512, ln1_b + l * 512, seq_bf);
    gemm_bf16<<<dim3(16, 43), 256, 0, stream>>>(seq_bf, w1t + (size_t)l * 1048576,
                                                b1 + l * 2048, th_bf, 2048, 512, 1, 1);
    gemm_bf16_t64<<<dim3(8, 86), 256, 0, stream>>>(th_bf, w2t + (size_t)l * 1048576,
                                                   b2 + l * 512, t1, 512, 2048, 0);
    ln_add<<<5440, 256, 0, stream>>>(seq, t1, ln2_g + l * 512, ln2_b + l * 512, seq_bf);
  }
  gather_out<<<4096, 512, 0, stream>>>(seq, (float*)d_out);
}

// Round 6
// 698.286 us; speedup vs baseline: 1.0583x; 1.0583x over previous
//
#include <hip/hip_runtime.h>
#include <hip/hip_bf16.h>
#include <math.h>

// ---------------------------------------------------------------------------
// B=4, L_IN=1024, D=512, H=8, DK=64, DFF=2048, NL=4, WINDOW=[4,4,4], INNER=5.
// all_size=[1024,256,64,16], L_tot=1360, rows M=5440 padded to M_PAD=5504.
// ---------------------------------------------------------------------------

typedef __attribute__((ext_vector_type(8))) short short8;
typedef __attribute__((ext_vector_type(4))) float f32x4;

__device__ inline ushort f2bf(float x) {
  union { __hip_bfloat16 h; ushort u; } cv; cv.h = __float2bfloat16(x); return cv.u;
}
__device__ inline float bf2f(ushort u) {
  union { unsigned int i; float f; } cv; cv.i = (unsigned)u << 16; return cv.f;
}
__device__ inline float lo16(unsigned u) { union { unsigned i; float f; } c; c.i = u << 16; return c.f; }
__device__ inline float hi16(unsigned u) { union { unsigned i; float f; } c; c.i = u & 0xffff0000u; return c.f; }

// tanh-form GELU (max |err| vs exact erf-GELU ~3e-3; well within budget)
__device__ inline float gelu_f(float x) {
  float y = 0.7978845608028654f * (x + 0.044715f * x * x * x);
  float t = __expf(-2.0f * y);
  float th = (1.0f - t) / (1.0f + t);
  return 0.5f * x * (1.0f + th);
}

#define GLD16(gp, lp)                                                        \
  __builtin_amdgcn_global_load_lds(                                          \
      (const __attribute__((address_space(1))) void*)(gp),                   \
      (__attribute__((address_space(3))) void*)(lp), 16, 0, 0)

// ---------------- embed: circular conv3 + posenc + mark projection ---------
__global__ __launch_bounds__(512) void embed_kernel(
    const float* __restrict__ x_enc, const float* __restrict__ x_mark,
    const float* __restrict__ conv_w, const float* __restrict__ conv_b,
    const float* __restrict__ temp_w, const float* __restrict__ temp_b,
    float* __restrict__ e) {
  int bl = blockIdx.x;
  int b = bl >> 10, l = bl & 1023;
  int d = threadIdx.x;
  int lm1 = (l + 1023) & 1023;
  int lp1 = (l + 1) & 1023;
  const float* w  = conv_w + d * 21;
  const float* x0 = x_enc + (size_t)(b * 1024 + lm1) * 7;
  const float* x1 = x_enc + (size_t)(b * 1024 + l)   * 7;
  const float* x2 = x_enc + (size_t)(b * 1024 + lp1) * 7;
  float acc = conv_b[d];
#pragma unroll
  for (int ci = 0; ci < 7; ci++) {
    acc = fmaf(x0[ci], w[ci * 3 + 0], acc);
    acc = fmaf(x1[ci], w[ci * 3 + 1], acc);
    acc = fmaf(x2[ci], w[ci * 3 + 2], acc);
  }
  int j = d >> 1;
  float dv = expf((float)(2 * j) * (-9.210340371976184f / 512.0f));
  float ang = (float)l * dv;
  float pe = (d & 1) ? cosf(ang) : sinf(ang);
  const float* xm = x_mark + (size_t)(b * 1024 + l) * 4;
  float mk = temp_b[d];
  mk = fmaf(xm[0], temp_w[d],        mk);
  mk = fmaf(xm[1], temp_w[512 + d],  mk);
  mk = fmaf(xm[2], temp_w[1024 + d], mk);
  mk = fmaf(xm[3], temp_w[1536 + d], mk);
  e[(size_t)bl * 512 + d] = acc + pe + mk;
}

// ---------------- weight cast+transpose: f32 [K][N] -> bf16 [N][K] ---------
__global__ __launch_bounds__(256) void transpose_cast(
    const float* __restrict__ src, ushort* __restrict__ dst,
    int K, int N, size_t src_lstride, size_t dst_lstride) {
  src += (size_t)blockIdx.z * src_lstride;
  dst += (size_t)blockIdx.z * dst_lstride;
  __shared__ float t[32][33];
  int k0 = blockIdx.y * 32, n0 = blockIdx.x * 32;
  int tx = threadIdx.x, ty = threadIdx.y;  // (32,8)
#pragma unroll
  for (int i = 0; i < 4; i++)
    t[ty + i * 8][tx] = src[(size_t)(k0 + ty + i * 8) * N + n0 + tx];
  __syncthreads();
#pragma unroll
  for (int i = 0; i < 4; i++)
    dst[(size_t)(n0 + ty + i * 8) * K + k0 + tx] = f2bf(t[tx][ty + i * 8]);
}

// ---------------- bf16 MFMA GEMM, 64x128 tile (M x N), dbuf + LDS swizzle --
// A: [M_pad][K] bf16.  Bt: [N][K] bf16 (pre-transposed).  act 1 = GELU.
// 4 waves, wave = 32x64 quadrant (acc[2][4]). 16B chunk swizzle: LDS[row][c]
// holds global chunk c ^ ((row>>1)&3) (pre-swizzled global source, linear
// LDS dest for global_load_lds); ds_read applies same XOR -> 2-way banks.
// Grid (N/128, M_pad/64).
__global__ __launch_bounds__(256) void gemm_bf16(
    const ushort* __restrict__ A, const ushort* __restrict__ Bt,
    const float* __restrict__ bias, void* __restrict__ C,
    int N, int K, int act, int out_bf16) {
  __shared__ short As[2][2048];   // 64 rows x 32
  __shared__ short Bs[2][4096];   // 128 rows x 32
  int tid = threadIdx.x;
  int w = tid >> 6, lane = tid & 63;
  int bm = blockIdx.y << 6, bn = blockIdx.x << 7;
  int gch = (tid & 3) ^ ((tid >> 3) & 3);          // swizzled source chunk
  const short* Ab = (const short*)A + (size_t)(bm + (tid >> 2)) * K + gch * 8;
  const short* Bb = (const short*)Bt + (size_t)(bn + (tid >> 2)) * K + gch * 8;
  int ldsw = (tid & 192) * 8;                      // wave-uniform: w*512 shorts
  int wr = (w >> 1) << 5, wc = (w & 1) << 6;
  int lr = lane & 15, kg = lane >> 4;
  int csw = (kg ^ ((lr >> 1) & 3)) * 8;            // swizzled read chunk (shorts)
  f32x4 acc[2][4] = {};
  GLD16(Ab,                  &As[0][ldsw]);
  GLD16(Bb,                  &Bs[0][ldsw]);
  GLD16(Bb + (size_t)64 * K, &Bs[0][2048 + ldsw]);
  __syncthreads();
  int nt = K >> 5;
  for (int t = 0; t < nt; t++) {
    int cur = t & 1;
    if (t + 1 < nt) {
      int kt = (t + 1) << 5;
      GLD16(Ab + kt,                  &As[cur ^ 1][ldsw]);
      GLD16(Bb + kt,                  &Bs[cur ^ 1][ldsw]);
      GLD16(Bb + kt + (size_t)64 * K, &Bs[cur ^ 1][2048 + ldsw]);
    }
    short8 a_[2], b_[4];
#pragma unroll
    for (int m = 0; m < 2; m++)
      a_[m] = *(const short8*)&As[cur][(wr + m * 16 + lr) * 32 + csw];
#pragma unroll
    for (int n = 0; n < 4; n++)
      b_[n] = *(const short8*)&Bs[cur][(wc + n * 16 + lr) * 32 + csw];
#pragma unroll
    for (int m = 0; m < 2; m++)
#pragma unroll
      for (int n = 0; n < 4; n++)
        acc[m][n] = __builtin_amdgcn_mfma_f32_16x16x32_bf16(a_[m], b_[n], acc[m][n], 0, 0, 0);
    __syncthreads();
  }
  int r0 = bm + wr + kg * 4;
  int c0 = bn + wc + lr;
#pragma unroll
  for (int m = 0; m < 2; m++) {
#pragma unroll
    for (int n = 0; n < 4; n++) {
      int col = c0 + n * 16;
      float bv = bias ? bias[col] : 0.0f;
#pragma unroll
      for (int j = 0; j < 4; j++) {
        int row = r0 + m * 16 + j;
        float v = acc[m][n][j] + bv;
        if (act == 1) v = gelu_f(v);
        if (out_bf16) ((ushort*)C)[(size_t)row * N + col] = f2bf(v);
        else          ((float*)C)[(size_t)row * N + col] = v;
      }
    }
  }
}

// ---------------- bf16 MFMA GEMM, 64x64 tile, dbuf + LDS swizzle -----------
__global__ __launch_bounds__(256) void gemm_bf16_t64(
    const ushort* __restrict__ A, const ushort* __restrict__ Bt,
    const float* __restrict__ bias, void* __restrict__ C,
    int N, int K, int out_bf16) {
  __shared__ short As[2][2048];   // 64 x 32
  __shared__ short Bs[2][2048];
  int tid = threadIdx.x;
  int w = tid >> 6, lane = tid & 63;
  int bm = blockIdx.y << 6, bn = blockIdx.x << 6;
  int gch = (tid & 3) ^ ((tid >> 3) & 3);
  const short* Ab = (const short*)A + (size_t)(bm + (tid >> 2)) * K + gch * 8;
  const short* Bb = (const short*)Bt + (size_t)(bn + (tid >> 2)) * K + gch * 8;
  int ldsw = (tid & 192) * 8;          // wave-uniform base (shorts)
  int wr = (w >> 1) << 5, wc = (w & 1) << 5;
  int lr = lane & 15, kg = lane >> 4;
  int csw = (kg ^ ((lr >> 1) & 3)) * 8;
  f32x4 acc[2][2] = {};
  GLD16(Ab, &As[0][ldsw]);
  GLD16(Bb, &Bs[0][ldsw]);
  __syncthreads();
  int nt = K >> 5;
  for (int t = 0; t < nt; t++) {
    int cur = t & 1;
    if (t + 1 < nt) {
      int kt = (t + 1) << 5;
      GLD16(Ab + kt, &As[cur ^ 1][ldsw]);
      GLD16(Bb + kt, &Bs[cur ^ 1][ldsw]);
    }
    short8 a_[2], b_[2];
#pragma unroll
    for (int m = 0; m < 2; m++)
      a_[m] = *(const short8*)&As[cur][(wr + m * 16 + lr) * 32 + csw];
#pragma unroll
    for (int n = 0; n < 2; n++)
      b_[n] = *(const short8*)&Bs[cur][(wc + n * 16 + lr) * 32 + csw];
#pragma unroll
    for (int m = 0; m < 2; m++)
#pragma unroll
      for (int n = 0; n < 2; n++)
        acc[m][n] = __builtin_amdgcn_mfma_f32_16x16x32_bf16(a_[m], b_[n], acc[m][n], 0, 0, 0);
    __syncthreads();
  }
  int r0 = bm + wr + kg * 4;
  int c0 = bn + wc + lr;
#pragma unroll
  for (int m = 0; m < 2; m++) {
#pragma unroll
    for (int n = 0; n < 2; n++) {
      int col = c0 + n * 16;
      float bv = bias ? bias[col] : 0.0f;
#pragma unroll
      for (int j = 0; j < 4; j++) {
        int row = r0 + m * 16 + j;
        float v = acc[m][n][j] + bv;
        if (out_bf16) ((ushort*)C)[(size_t)row * N + col] = f2bf(v);
        else          ((float*)C)[(size_t)row * N + col] = v;
      }
    }
  }
}

// ---------------- small f32 GEMM (down / up projections) -------------------
__global__ __launch_bounds__(256) void gemm_f32(
    const float* __restrict__ A, const float* __restrict__ B,
    const float* __restrict__ bias, float* __restrict__ C,
    int M, int N, int K) {
  __shared__ float As[16][68];
  __shared__ float Bs[16][64];
  int tid = threadIdx.x;
  int tx = tid & 15, ty = tid >> 4;
  int bm = blockIdx.y << 6, bn = blockIdx.x << 6;
  const float* Ab = A + (size_t)bm * K;
  const float* Bb = B + bn;
  float acc[4][4] = {};
  for (int kt = 0; kt < K; kt += 16) {
#pragma unroll
    for (int r = 0; r < 4; r++) {
      int e2 = r * 256 + tid;
      As[e2 & 15][e2 >> 4] = Ab[(size_t)(e2 >> 4) * K + kt + (e2 & 15)];
    }
#pragma unroll
    for (int r = 0; r < 4; r++) {
      int e2 = r * 256 + tid;
      Bs[e2 >> 6][e2 & 63] = Bb[(size_t)(kt + (e2 >> 6)) * N + (e2 & 63)];
    }
    __syncthreads();
#pragma unroll
    for (int kk = 0; kk < 16; kk++) {
      float a0 = As[kk][(ty << 2) + 0], a1 = As[kk][(ty << 2) + 1];
      float a2 = As[kk][(ty << 2) + 2], a3 = As[kk][(ty << 2) + 3];
      float b0 = Bs[kk][(tx << 2) + 0], b1 = Bs[kk][(tx << 2) + 1];
      float b2 = Bs[kk][(tx << 2) + 2], b3 = Bs[kk][(tx << 2) + 3];
      acc[0][0] = fmaf(a0, b0, acc[0][0]); acc[0][1] = fmaf(a0, b1, acc[0][1]);
      acc[0][2] = fmaf(a0, b2, acc[0][2]); acc[0][3] = fmaf(a0, b3, acc[0][3]);
      acc[1][0] = fmaf(a1, b0, acc[1][0]); acc[1][1] = fmaf(a1, b1, acc[1][1]);
      acc[1][2] = fmaf(a1, b2, acc[1][2]); acc[1][3] = fmaf(a1, b3, acc[1][3]);
      acc[2][0] = fmaf(a2, b0, acc[2][0]); acc[2][1] = fmaf(a2, b1, acc[2][1]);
      acc[2][2] = fmaf(a2, b2, acc[2][2]); acc[2][3] = fmaf(a2, b3, acc[2][3]);
      acc[3][0] = fmaf(a3, b0, acc[3][0]); acc[3][1] = fmaf(a3, b1, acc[3][1]);
      acc[3][2] = fmaf(a3, b2, acc[3][2]); acc[3][3] = fmaf(a3, b3, acc[3][3]);
    }
    __syncthreads();
  }
#pragma unroll
  for (int i2 = 0; i2 < 4; i2++) {
    int row = bm + (ty << 2) + i2;
#pragma unroll
    for (int j2 = 0; j2 < 4; j2++) {
      int col = bn + (tx << 2) + j2;
      C[(size_t)row * N + col] = acc[i2][j2] + (bias ? bias[col] : 0.0f);
    }
  }
}

// ---------------- pyramid conv level ---------------------------------------
__global__ __launch_bounds__(64) void pyr_conv(
    const float* __restrict__ in, int in_base, int in_bstr,
    float* __restrict__ out, int out_base, int out_bstr, int out_len,
    const float* __restrict__ w, const float* __restrict__ bias,
    const float* __restrict__ bng, const float* __restrict__ bnb) {
  int blk = blockIdx.x;
  int b = blk / out_len, to = blk - b * out_len;
  int co = threadIdx.x;
  __shared__ float xin[4][64];
  const float* src = in + (size_t)(b * in_bstr + in_base + 4 * to) * 64;
#pragma unroll
  for (int r2 = 0; r2 < 4; r2++) xin[r2][co] = src[r2 * 64 + co];
  __syncthreads();
  const float* wr = w + (size_t)co * 256;
  float acc = bias[co];
#pragma unroll 16
  for (int ci = 0; ci < 64; ci++) {
    acc = fmaf(xin[0][ci], wr[ci * 4 + 0], acc);
    acc = fmaf(xin[1][ci], wr[ci * 4 + 1], acc);
    acc = fmaf(xin[2][ci], wr[ci * 4 + 2], acc);
    acc = fmaf(xin[3][ci], wr[ci * 4 + 3], acc);
  }
  float y = fmaf(bng[co], acc, bnb[co]);
  y = y > 0.0f ? y : expm1f(y);
  out[(size_t)(b * out_bstr + out_base + to) * 64 + co] = y;
}

// ---------------- LayerNorm over concat([embed, pyr_up]); dual output ------
__global__ __launch_bounds__(256) void ln_concat(
    const float* __restrict__ e, const float* __restrict__ pyru,
    const float* __restrict__ g, const float* __restrict__ bta,
    float* __restrict__ seq, ushort* __restrict__ seq_bf) {
  int r = blockIdx.x;
  int b = r / 1360, i = r - b * 1360;
  int tid = threadIdx.x;
  const float* src = (i < 1024)
      ? (e    + (size_t)(b * 1024 + i) * 512)
      : (pyru + (size_t)(b * 336 + (i - 1024)) * 512);
  float v0 = src[tid], v1 = src[tid + 256];
  __shared__ float red[256];
  red[tid] = v0 + v1;
  __syncthreads();
  for (int st = 128; st > 0; st >>= 1) { if (tid < st) red[tid] += red[tid + st]; __syncthreads(); }
  float mu = red[0] * (1.0f / 512.0f);
  __syncthreads();
  float d0 = v0 - mu, d1 = v1 - mu;
  red[tid] = d0 * d0 + d1 * d1;
  __syncthreads();
  for (int st = 128; st > 0; st >>= 1) { if (tid < st) red[tid] += red[tid + st]; __syncthreads(); }
  float inv = rsqrtf(red[0] * (1.0f / 512.0f) + 1e-5f);
  float o0 = d0 * inv * g[tid]       + bta[tid];
  float o1 = d1 * inv * g[tid + 256] + bta[tid + 256];
  float* dst = seq + (size_t)r * 512;
  dst[tid] = o0; dst[tid + 256] = o1;
  ushort* dbf = seq_bf + (size_t)r * 512;
  dbf[tid] = f2bf(o0); dbf[tid + 256] = f2bf(o1);
}

// ---------------- residual add + LayerNorm (in-place), dual output ---------
__global__ __launch_bounds__(256) void ln_add(
    float* __restrict__ seq, const float* __restrict__ t1,
    const float* __restrict__ g, const float* __restrict__ bta,
    ushort* __restrict__ seq_bf) {
  int r = blockIdx.x;
  int tid = threadIdx.x;
  float* row = seq + (size_t)r * 512;
  const float* trow = t1 + (size_t)r * 512;
  float v0 = row[tid] + trow[tid];
  float v1 = row[tid + 256] + trow[tid + 256];
  __shared__ float red[256];
  red[tid] = v0 + v1;
  __syncthreads();
  for (int st = 128; st > 0; st >>= 1) { if (tid < st) red[tid] += red[tid + st]; __syncthreads(); }
  float mu = red[0] * (1.0f / 512.0f);
  __syncthreads();
  float d0 = v0 - mu, d1 = v1 - mu;
  red[tid] = d0 * d0 + d1 * d1;
  __syncthreads();
  for (int st = 128; st > 0; st >>= 1) { if (tid < st) red[tid] += red[tid + st]; __syncthreads(); }
  float inv = rsqrtf(red[0] * (1.0f / 512.0f) + 1e-5f);
  float o0 = d0 * inv * g[tid]       + bta[tid];
  float o1 = d1 * inv * g[tid + 256] + bta[tid + 256];
  row[tid] = o0; row[tid + 256] = o1;
  ushort* dbf = seq_bf + (size_t)r * 512;
  dbf[tid] = f2bf(o0); dbf[tid + 256] = f2bf(o1);
}

// ---------------- sparse pyramidal attention (wave-per-head, no LDS) -------
// Query i attends to nk<=10 keys (exact: masked terms are exact softmax 0s).
// Wave = one (row, head). QK: lane=(j2=lane>>2, c=lane&3): 16-dim partial dot
// + shfl_xor reduce. Softmax/PV: scores & keys broadcast via __shfl.
__global__ __launch_bounds__(512) void attn_sparse(
    const ushort* __restrict__ qkv, ushort* __restrict__ o) {
  int r = blockIdx.x;
  int b = r / 1360, i = r - b * 1360;
  int h = threadIdx.x >> 6, lane = threadIdx.x & 63;
  // per-thread algebraic key set (no arrays, rule #20)
  int S, sz, li;
  if (i < 1024)      { li = 0; S = 0;    sz = 1024; }
  else if (i < 1280) { li = 1; S = 1024; sz = 256; }
  else if (i < 1344) { li = 2; S = 1280; sz = 64; }
  else               { li = 3; S = 1344; sz = 16; }
  int p = i - S;
  int lo = p - 2; if (lo < 0) lo = 0;
  int hi = p + 2; if (hi > sz - 1) hi = sz - 1;
  int cnt = hi - lo + 1;
  int nk = cnt + (li > 0 ? 4 : 0) + (li < 3 ? 1 : 0);
  int Sprev = (li == 1) ? 0 : (li == 2) ? 1024 : 1280;
  int Snext = (li == 0) ? 1024 : (li == 1) ? 1280 : 1344;
  int j2 = lane >> 2, c = lane & 3;
  // key for this lane's j2 (unconditional; fallback self for idle lanes)
  int key;
  if (j2 < cnt)                      key = S + lo + j2;
  else if (li > 0 && j2 - cnt < 4)   key = Sprev + 4 * p + (j2 - cnt);
  else if (li < 3)                   key = Snext + (p >> 2);
  else                               key = S + p;
  // QK partial dot over dims [c*16, c*16+16)
  float partial = 0.0f;
  {
    const uint4* qv = (const uint4*)(qkv + (size_t)r * 1536 + h * 64 + c * 16);
    const uint4* kv = (const uint4*)(qkv + (size_t)(b * 1360 + key) * 1536 + 512 + h * 64 + c * 16);
#pragma unroll
    for (int cc = 0; cc < 2; cc++) {
      uint4 a = qv[cc], k4 = kv[cc];
      partial = fmaf(lo16(a.x), lo16(k4.x), partial); partial = fmaf(hi16(a.x), hi16(k4.x), partial);
      partial = fmaf(lo16(a.y), lo16(k4.y), partial); partial = fmaf(hi16(a.y), hi16(k4.y), partial);
      partial = fmaf(lo16(a.z), lo16(k4.z), partial); partial = fmaf(hi16(a.z), hi16(k4.z), partial);
      partial = fmaf(lo16(a.w), lo16(k4.w), partial); partial = fmaf(hi16(a.w), hi16(k4.w), partial);
    }
  }
  partial += __shfl_xor(partial, 1);
  partial += __shfl_xor(partial, 2);
  float s = partial * 0.125f;       // score for key j2, on all 4 lanes of group
  // softmax over nk scores (broadcast via shfl; redundant on all lanes)
  float m = -1e30f;
  for (int j = 0; j < nk; j++) m = fmaxf(m, __shfl(s, 4 * j));
  float denom = 0.0f;
  for (int j = 0; j < nk; j++) denom += __expf(__shfl(s, 4 * j) - m);
  float inv = 1.0f / denom;
  // PV: lane = output dim d
  float acc = 0.0f;
  for (int j = 0; j < nk; j++) {
    float pj = __expf(__shfl(s, 4 * j) - m) * inv;
    int kj = __shfl(key, 4 * j);
    float vv = bf2f(qkv[(size_t)(b * 1360 + kj) * 1536 + 1024 + h * 64 + lane]);
    acc = fmaf(pj, vv, acc);
  }
  o[(size_t)r * 512 + h * 64 + lane] = f2bf(acc);
}

// ---------------- output gather --------------------------------------------
__global__ __launch_bounds__(512) void gather_out(
    const float* __restrict__ seq, float* __restrict__ out) {
  int bl = blockIdx.x;
  int b = bl >> 10, i = bl & 1023;
  int d = threadIdx.x;
  size_t ob = (size_t)bl * 2048 + d;
  size_t base = (size_t)b * 1360;
  out[ob]        = seq[(base + i) * 512 + d];
  out[ob + 512]  = seq[(base + 1024 + (i >> 2)) * 512 + d];
  out[ob + 1024] = seq[(base + 1280 + (i >> 4)) * 512 + d];
  out[ob + 1536] = seq[(base + 1344 + (i >> 6)) * 512 + d];
}

// ---------------------------------------------------------------------------
extern "C" void kernel_launch(void* const* d_in, const int* in_sizes, int n_in,
                              void* d_out, int out_size, void* d_ws, size_t ws_size,
                              hipStream_t stream) {
  const float* x_enc   = (const float*)d_in[0];
  const float* x_mark  = (const float*)d_in[1];
  const float* conv_w  = (const float*)d_in[2];
  const float* conv_b  = (const float*)d_in[3];
  const float* temp_w  = (const float*)d_in[4];
  const float* temp_b  = (const float*)d_in[5];
  const float* down_w  = (const float*)d_in[6];
  const float* down_b  = (const float*)d_in[7];
  const float* pyr_w   = (const float*)d_in[8];
  const float* pyr_b   = (const float*)d_in[9];
  const float* bn_g    = (const float*)d_in[10];
  const float* bn_b    = (const float*)d_in[11];
  const float* up_w    = (const float*)d_in[12];
  const float* up_b    = (const float*)d_in[13];
  const float* norm_g  = (const float*)d_in[14];
  const float* norm_b  = (const float*)d_in[15];
  const float* wq      = (const float*)d_in[16];
  const float* wk      = (const float*)d_in[17];
  const float* wv      = (const float*)d_in[18];
  const float* fc_w    = (const float*)d_in[19];
  const float* fc_b    = (const float*)d_in[20];
  const float* ln1_g   = (const float*)d_in[21];
  const float* ln1_b   = (const float*)d_in[22];
  const float* w1      = (const float*)d_in[23];
  const float* b1      = (const float*)d_in[24];
  const float* w2      = (const float*)d_in[25];
  const float* b2      = (const float*)d_in[26];
  const float* ln2_g   = (const float*)d_in[27];
  const float* ln2_b   = (const float*)d_in[28];

  // ---- workspace layout (f32-word offsets); total 18,972,672 words = 72.4MB
  float* ws = (float*)d_ws;
  float*  e      = ws;                         // 2,097,152 w
  float*  tmp0   = ws + 2097152;               //   262,144 w
  float*  pyrf   = ws + 2359296;               //    86,016 w
  float*  pyru   = ws + 2445312;               //   688,128 w
  ushort* qkv_bf = (ushort*)ws;                // [5504][1536] bf16
  ushort* o_bf   = (ushort*)(ws + 4227072);    // [5504][512] bf16
  ushort* th_bf  = (ushort*)ws;                // [5504][2048] bf16
  float*  t1     = ws + 5636096;               // [5504][512] f32
  float*  seq    = ws + 8454144;               // [5504][512] f32
  ushort* seq_bf = (ushort*)(ws + 11272192);   // [5504][512] bf16
  ushort* qkvw   = (ushort*)(ws + 12681216);   // 4 x [1536][512] bf16
  ushort* fcw    = (ushort*)(ws + 14254080);   // 4 x [512][512] bf16
  ushort* w1t    = (ushort*)(ws + 14778368);   // 4 x [2048][512] bf16
  ushort* w2t    = (ushort*)(ws + 16875520);   // 4 x [512][2048] bf16

  // ---- weight cast+transpose (once per call) ----
  dim3 tb(32, 8);
  transpose_cast<<<dim3(16, 16, 4), tb, 0, stream>>>(wq, qkvw,          512, 512,  262144, 786432);
  transpose_cast<<<dim3(16, 16, 4), tb, 0, stream>>>(wk, qkvw + 262144, 512, 512,  262144, 786432);
  transpose_cast<<<dim3(16, 16, 4), tb, 0, stream>>>(wv, qkvw + 524288, 512, 512,  262144, 786432);
  transpose_cast<<<dim3(16, 16, 4), tb, 0, stream>>>(fc_w, fcw,         512, 512,  262144, 262144);
  transpose_cast<<<dim3(64, 16, 4), tb, 0, stream>>>(w1, w1t,           512, 2048, 1048576, 1048576);
  transpose_cast<<<dim3(16, 64, 4), tb, 0, stream>>>(w2, w2t,           2048, 512, 1048576, 1048576);

  // ---- prologue ----
  embed_kernel<<<4096, 512, 0, stream>>>(x_enc, x_mark, conv_w, conv_b,
                                         temp_w, temp_b, e);
  gemm_f32<<<dim3(1, 64), 256, 0, stream>>>(e, down_w, down_b, tmp0, 4096, 64, 512);
  pyr_conv<<<4 * 256, 64, 0, stream>>>(tmp0, 0, 1024, pyrf, 0, 336, 256,
                                       pyr_w, pyr_b, bn_g, bn_b);
  pyr_conv<<<4 * 64, 64, 0, stream>>>(pyrf, 0, 336, pyrf, 256, 336, 64,
                                      pyr_w + 16384, pyr_b + 64, bn_g + 64, bn_b + 64);
  pyr_conv<<<4 * 16, 64, 0, stream>>>(pyrf, 256, 336, pyrf, 320, 336, 16,
                                      pyr_w + 32768, pyr_b + 128, bn_g + 128, bn_b + 128);
  gemm_f32<<<dim3(8, 21), 256, 0, stream>>>(pyrf, up_w, up_b, pyru, 1344, 512, 64);
  ln_concat<<<5440, 256, 0, stream>>>(e, pyru, norm_g, norm_b, seq, seq_bf);

  // ---- layers ----
  for (int l = 0; l < 4; l++) {
    gemm_bf16<<<dim3(12, 86), 256, 0, stream>>>(seq_bf, qkvw + (size_t)l * 786432,
                                                nullptr, qkv_bf, 1536, 512, 0, 1);
    attn_sparse<<<5440, 512, 0, stream>>>(qkv_bf, o_bf);
    gemm_bf16_t64<<<dim3(8, 86), 256, 0, stream>>>(o_bf, fcw + (size_t)l * 262144,
                                                   fc_b + l * 512, t1, 512, 512, 0);
    ln_add<<<5440, 256, 0, stream>>>(seq, t1, ln1_g + l * 512, ln1_b + l * 512, seq_bf);
    gemm_bf16<<<dim3(16, 86), 256, 0, stream>>>(seq_bf, w1t + (size_t)l * 1048576,
                                                b1 + l * 2048, th_bf, 2048, 512, 1, 1);
    gemm_bf16_t64<<<dim3(8, 86), 256, 0, stream>>>(th_bf, w2t + (size_t)l * 1048576,
                                                   b2 + l * 512, t1, 512, 2048, 0);
    ln_add<<<5440, 256, 0, stream>>>(seq, t1, ln2_g + l * 512, ln2_b + l * 512, seq_bf);
  }
  gather_out<<<4096, 512, 0, stream>>>(seq, (float*)d_out);
}

// Round 7
// 662.282 us; speedup vs baseline: 1.1158x; 1.0544x over previous
//
#include <hip/hip_runtime.h>
#include <hip/hip_bf16.h>
#include <math.h>

// ---------------------------------------------------------------------------
// B=4, L_IN=1024, D=512, H=8, DK=64, DFF=2048, NL=4, WINDOW=[4,4,4], INNER=5.
// all_size=[1024,256,64,16], L_tot=1360, rows M=5440 padded to M_PAD=5504.
// ---------------------------------------------------------------------------

typedef __attribute__((ext_vector_type(8))) short short8;
typedef __attribute__((ext_vector_type(4))) float f32x4;

__device__ inline ushort f2bf(float x) {
  union { __hip_bfloat16 h; ushort u; } cv; cv.h = __float2bfloat16(x); return cv.u;
}
__device__ inline float bf2f(ushort u) {
  union { unsigned int i; float f; } cv; cv.i = (unsigned)u << 16; return cv.f;
}
__device__ inline float lo16(unsigned u) { union { unsigned i; float f; } c; c.i = u << 16; return c.f; }
__device__ inline float hi16(unsigned u) { union { unsigned i; float f; } c; c.i = u & 0xffff0000u; return c.f; }

// tanh-form GELU (max |err| vs exact erf-GELU ~3e-3; well within budget)
__device__ inline float gelu_f(float x) {
  float y = 0.7978845608028654f * (x + 0.044715f * x * x * x);
  float t = __expf(-2.0f * y);
  float th = (1.0f - t) / (1.0f + t);
  return 0.5f * x * (1.0f + th);
}

// bijective XCD-chunk swizzle (m204): round-robin id -> contiguous chunk/XCD
__device__ inline int xcd_chunk(int orig, int nwg) {
  int q = nwg >> 3, r = nwg & 7;
  int xcd = orig & 7, idx = orig >> 3;
  int base = (xcd < r) ? xcd * (q + 1) : r * (q + 1) + (xcd - r) * q;
  return base + idx;
}

#define GLD16(gp, lp)                                                        \
  __builtin_amdgcn_global_load_lds(                                          \
      (const __attribute__((address_space(1))) void*)(gp),                   \
      (__attribute__((address_space(3))) void*)(lp), 16, 0, 0)

// ---------------- embed: circular conv3 + posenc + mark projection ---------
__global__ __launch_bounds__(512) void embed_kernel(
    const float* __restrict__ x_enc, const float* __restrict__ x_mark,
    const float* __restrict__ conv_w, const float* __restrict__ conv_b,
    const float* __restrict__ temp_w, const float* __restrict__ temp_b,
    float* __restrict__ e) {
  int bl = blockIdx.x;
  int b = bl >> 10, l = bl & 1023;
  int d = threadIdx.x;
  int lm1 = (l + 1023) & 1023;
  int lp1 = (l + 1) & 1023;
  const float* w  = conv_w + d * 21;
  const float* x0 = x_enc + (size_t)(b * 1024 + lm1) * 7;
  const float* x1 = x_enc + (size_t)(b * 1024 + l)   * 7;
  const float* x2 = x_enc + (size_t)(b * 1024 + lp1) * 7;
  float acc = conv_b[d];
#pragma unroll
  for (int ci = 0; ci < 7; ci++) {
    acc = fmaf(x0[ci], w[ci * 3 + 0], acc);
    acc = fmaf(x1[ci], w[ci * 3 + 1], acc);
    acc = fmaf(x2[ci], w[ci * 3 + 2], acc);
  }
  int j = d >> 1;
  float dv = expf((float)(2 * j) * (-9.210340371976184f / 512.0f));
  float ang = (float)l * dv;
  float pe = (d & 1) ? cosf(ang) : sinf(ang);
  const float* xm = x_mark + (size_t)(b * 1024 + l) * 4;
  float mk = temp_b[d];
  mk = fmaf(xm[0], temp_w[d],        mk);
  mk = fmaf(xm[1], temp_w[512 + d],  mk);
  mk = fmaf(xm[2], temp_w[1024 + d], mk);
  mk = fmaf(xm[3], temp_w[1536 + d], mk);
  e[(size_t)bl * 512 + d] = acc + pe + mk;
}

// ---------------- weight cast+transpose: f32 [K][N] -> bf16 [N][K] ---------
__global__ __launch_bounds__(256) void transpose_cast(
    const float* __restrict__ src, ushort* __restrict__ dst,
    int K, int N, size_t src_lstride, size_t dst_lstride) {
  src += (size_t)blockIdx.z * src_lstride;
  dst += (size_t)blockIdx.z * dst_lstride;
  __shared__ float t[32][33];
  int k0 = blockIdx.y * 32, n0 = blockIdx.x * 32;
  int tx = threadIdx.x, ty = threadIdx.y;  // (32,8)
#pragma unroll
  for (int i = 0; i < 4; i++)
    t[ty + i * 8][tx] = src[(size_t)(k0 + ty + i * 8) * N + n0 + tx];
  __syncthreads();
#pragma unroll
  for (int i = 0; i < 4; i++)
    dst[(size_t)(n0 + ty + i * 8) * K + k0 + tx] = f2bf(t[tx][ty + i * 8]);
}

// ---------------- bf16 MFMA GEMM, 64x128 tile, dbuf + swizzles -------------
// A: [M_pad][K] bf16.  Bt: [N][K] bf16 (pre-transposed).  act 1 = GELU.
// 1D grid = (N/128)*(M/64), XCD-chunk swizzled (x-fast within chunk ->
// per-XCD L2 footprint = B_full + few A row-blocks). LDS 16B-chunk XOR
// swizzle (pre-swizzled global source + swizzled ds_read) -> 0 conflicts.
__global__ __launch_bounds__(256) void gemm_bf16(
    const ushort* __restrict__ A, const ushort* __restrict__ Bt,
    const float* __restrict__ bias, void* __restrict__ C,
    int N, int K, int act, int out_bf16) {
  __shared__ short As[2][2048];   // 64 rows x 32
  __shared__ short Bs[2][4096];   // 128 rows x 32
  int nbx = N >> 7;
  int wgid = xcd_chunk(blockIdx.x, gridDim.x);
  int bx = wgid % nbx, by = wgid / nbx;
  int tid = threadIdx.x;
  int w = tid >> 6, lane = tid & 63;
  int bm = by << 6, bn = bx << 7;
  int gch = (tid & 3) ^ ((tid >> 3) & 3);          // swizzled source chunk
  const short* Ab = (const short*)A + (size_t)(bm + (tid >> 2)) * K + gch * 8;
  const short* Bb = (const short*)Bt + (size_t)(bn + (tid >> 2)) * K + gch * 8;
  int ldsw = (tid & 192) * 8;                      // wave-uniform: w*512 shorts
  int wr = (w >> 1) << 5, wc = (w & 1) << 6;
  int lr = lane & 15, kg = lane >> 4;
  int csw = (kg ^ ((lr >> 1) & 3)) * 8;            // swizzled read chunk (shorts)
  f32x4 acc[2][4] = {};
  GLD16(Ab,                  &As[0][ldsw]);
  GLD16(Bb,                  &Bs[0][ldsw]);
  GLD16(Bb + (size_t)64 * K, &Bs[0][2048 + ldsw]);
  __syncthreads();
  int nt = K >> 5;
  for (int t = 0; t < nt; t++) {
    int cur = t & 1;
    if (t + 1 < nt) {
      int kt = (t + 1) << 5;
      GLD16(Ab + kt,                  &As[cur ^ 1][ldsw]);
      GLD16(Bb + kt,                  &Bs[cur ^ 1][ldsw]);
      GLD16(Bb + kt + (size_t)64 * K, &Bs[cur ^ 1][2048 + ldsw]);
    }
    short8 a_[2], b_[4];
#pragma unroll
    for (int m = 0; m < 2; m++)
      a_[m] = *(const short8*)&As[cur][(wr + m * 16 + lr) * 32 + csw];
#pragma unroll
    for (int n = 0; n < 4; n++)
      b_[n] = *(const short8*)&Bs[cur][(wc + n * 16 + lr) * 32 + csw];
#pragma unroll
    for (int m = 0; m < 2; m++)
#pragma unroll
      for (int n = 0; n < 4; n++)
        acc[m][n] = __builtin_amdgcn_mfma_f32_16x16x32_bf16(a_[m], b_[n], acc[m][n], 0, 0, 0);
    __syncthreads();
  }
  int r0 = bm + wr + kg * 4;
  int c0 = bn + wc + lr;
#pragma unroll
  for (int m = 0; m < 2; m++) {
#pragma unroll
    for (int n = 0; n < 4; n++) {
      int col = c0 + n * 16;
      float bv = bias ? bias[col] : 0.0f;
#pragma unroll
      for (int j = 0; j < 4; j++) {
        int row = r0 + m * 16 + j;
        float v = acc[m][n][j] + bv;
        if (act == 1) v = gelu_f(v);
        if (out_bf16) ((ushort*)C)[(size_t)row * N + col] = f2bf(v);
        else          ((float*)C)[(size_t)row * N + col] = v;
      }
    }
  }
}

// ---------------- bf16 MFMA GEMM, 64x64 tile, dbuf + swizzles --------------
__global__ __launch_bounds__(256) void gemm_bf16_t64(
    const ushort* __restrict__ A, const ushort* __restrict__ Bt,
    const float* __restrict__ bias, void* __restrict__ C,
    int N, int K, int out_bf16) {
  __shared__ short As[2][2048];   // 64 x 32
  __shared__ short Bs[2][2048];
  int nbx = N >> 6;
  int wgid = xcd_chunk(blockIdx.x, gridDim.x);
  int bx = wgid % nbx, by = wgid / nbx;
  int tid = threadIdx.x;
  int w = tid >> 6, lane = tid & 63;
  int bm = by << 6, bn = bx << 6;
  int gch = (tid & 3) ^ ((tid >> 3) & 3);
  const short* Ab = (const short*)A + (size_t)(bm + (tid >> 2)) * K + gch * 8;
  const short* Bb = (const short*)Bt + (size_t)(bn + (tid >> 2)) * K + gch * 8;
  int ldsw = (tid & 192) * 8;          // wave-uniform base (shorts)
  int wr = (w >> 1) << 5, wc = (w & 1) << 5;
  int lr = lane & 15, kg = lane >> 4;
  int csw = (kg ^ ((lr >> 1) & 3)) * 8;
  f32x4 acc[2][2] = {};
  GLD16(Ab, &As[0][ldsw]);
  GLD16(Bb, &Bs[0][ldsw]);
  __syncthreads();
  int nt = K >> 5;
  for (int t = 0; t < nt; t++) {
    int cur = t & 1;
    if (t + 1 < nt) {
      int kt = (t + 1) << 5;
      GLD16(Ab + kt, &As[cur ^ 1][ldsw]);
      GLD16(Bb + kt, &Bs[cur ^ 1][ldsw]);
    }
    short8 a_[2], b_[2];
#pragma unroll
    for (int m = 0; m < 2; m++)
      a_[m] = *(const short8*)&As[cur][(wr + m * 16 + lr) * 32 + csw];
#pragma unroll
    for (int n = 0; n < 2; n++)
      b_[n] = *(const short8*)&Bs[cur][(wc + n * 16 + lr) * 32 + csw];
#pragma unroll
    for (int m = 0; m < 2; m++)
#pragma unroll
      for (int n = 0; n < 2; n++)
        acc[m][n] = __builtin_amdgcn_mfma_f32_16x16x32_bf16(a_[m], b_[n], acc[m][n], 0, 0, 0);
    __syncthreads();
  }
  int r0 = bm + wr + kg * 4;
  int c0 = bn + wc + lr;
#pragma unroll
  for (int m = 0; m < 2; m++) {
#pragma unroll
    for (int n = 0; n < 2; n++) {
      int col = c0 + n * 16;
      float bv = bias ? bias[col] : 0.0f;
#pragma unroll
      for (int j = 0; j < 4; j++) {
        int row = r0 + m * 16 + j;
        float v = acc[m][n][j] + bv;
        if (out_bf16) ((ushort*)C)[(size_t)row * N + col] = f2bf(v);
        else          ((float*)C)[(size_t)row * N + col] = v;
      }
    }
  }
}

// ---------------- down-projection GEMM: [4096][512] @ [512][64] ------------
// 16-row tiles -> 256 blocks (vs 64 at 64-tile). 4 outputs/thread; LDS
// broadcast reads for A, stride-1 for B. XCD-chunk swizzle for L2 locality.
__global__ __launch_bounds__(256) void down_gemm(
    const float* __restrict__ A, const float* __restrict__ B,
    const float* __restrict__ bias, float* __restrict__ C) {
  int wgid = xcd_chunk(blockIdx.x, gridDim.x);
  int r0 = wgid << 4;
  int tid = threadIdx.x;
  int col = tid & 63, rq = tid >> 6;
  __shared__ float As[16][32];
  __shared__ float Bs[32][64];
  float acc0 = 0, acc1 = 0, acc2 = 0, acc3 = 0;
  for (int kt = 0; kt < 512; kt += 32) {
    {
      int e = tid * 2;
      int ar = e >> 5, ak = e & 31;
      *(float2*)&As[ar][ak] = *(const float2*)&A[(size_t)(r0 + ar) * 512 + kt + ak];
    }
    {
      int e = tid * 8;
      int br = e >> 6, bc = e & 63;
      *(float4*)&Bs[br][bc]     = *(const float4*)&B[(size_t)(kt + br) * 64 + bc];
      *(float4*)&Bs[br][bc + 4] = *(const float4*)&B[(size_t)(kt + br) * 64 + bc + 4];
    }
    __syncthreads();
#pragma unroll
    for (int kk = 0; kk < 32; kk++) {
      float bv = Bs[kk][col];
      acc0 = fmaf(As[rq][kk],      bv, acc0);
      acc1 = fmaf(As[rq + 4][kk],  bv, acc1);
      acc2 = fmaf(As[rq + 8][kk],  bv, acc2);
      acc3 = fmaf(As[rq + 12][kk], bv, acc3);
    }
    __syncthreads();
  }
  float bv = bias[col];
  C[(size_t)(r0 + rq) * 64 + col]      = acc0 + bv;
  C[(size_t)(r0 + rq + 4) * 64 + col]  = acc1 + bv;
  C[(size_t)(r0 + rq + 8) * 64 + col]  = acc2 + bv;
  C[(size_t)(r0 + rq + 12) * 64 + col] = acc3 + bv;
}

// ---------------- small f32 GEMM (up projection) ---------------------------
__global__ __launch_bounds__(256) void gemm_f32(
    const float* __restrict__ A, const float* __restrict__ B,
    const float* __restrict__ bias, float* __restrict__ C,
    int M, int N, int K) {
  __shared__ float As[16][68];
  __shared__ float Bs[16][64];
  int tid = threadIdx.x;
  int tx = tid & 15, ty = tid >> 4;
  int bm = blockIdx.y << 6, bn = blockIdx.x << 6;
  const float* Ab = A + (size_t)bm * K;
  const float* Bb = B + bn;
  float acc[4][4] = {};
  for (int kt = 0; kt < K; kt += 16) {
#pragma unroll
    for (int r = 0; r < 4; r++) {
      int e2 = r * 256 + tid;
      As[e2 & 15][e2 >> 4] = Ab[(size_t)(e2 >> 4) * K + kt + (e2 & 15)];
    }
#pragma unroll
    for (int r = 0; r < 4; r++) {
      int e2 = r * 256 + tid;
      Bs[e2 >> 6][e2 & 63] = Bb[(size_t)(kt + (e2 >> 6)) * N + (e2 & 63)];
    }
    __syncthreads();
#pragma unroll
    for (int kk = 0; kk < 16; kk++) {
      float a0 = As[kk][(ty << 2) + 0], a1 = As[kk][(ty << 2) + 1];
      float a2 = As[kk][(ty << 2) + 2], a3 = As[kk][(ty << 2) + 3];
      float b0 = Bs[kk][(tx << 2) + 0], b1 = Bs[kk][(tx << 2) + 1];
      float b2 = Bs[kk][(tx << 2) + 2], b3 = Bs[kk][(tx << 2) + 3];
      acc[0][0] = fmaf(a0, b0, acc[0][0]); acc[0][1] = fmaf(a0, b1, acc[0][1]);
      acc[0][2] = fmaf(a0, b2, acc[0][2]); acc[0][3] = fmaf(a0, b3, acc[0][3]);
      acc[1][0] = fmaf(a1, b0, acc[1][0]); acc[1][1] = fmaf(a1, b1, acc[1][1]);
      acc[1][2] = fmaf(a1, b2, acc[1][2]); acc[1][3] = fmaf(a1, b3, acc[1][3]);
      acc[2][0] = fmaf(a2, b0, acc[2][0]); acc[2][1] = fmaf(a2, b1, acc[2][1]);
      acc[2][2] = fmaf(a2, b2, acc[2][2]); acc[2][3] = fmaf(a2, b3, acc[2][3]);
      acc[3][0] = fmaf(a3, b0, acc[3][0]); acc[3][1] = fmaf(a3, b1, acc[3][1]);
      acc[3][2] = fmaf(a3, b2, acc[3][2]); acc[3][3] = fmaf(a3, b3, acc[3][3]);
    }
    __syncthreads();
  }
#pragma unroll
  for (int i2 = 0; i2 < 4; i2++) {
    int row = bm + (ty << 2) + i2;
#pragma unroll
    for (int j2 = 0; j2 < 4; j2++) {
      int col = bn + (tx << 2) + j2;
      C[(size_t)row * N + col] = acc[i2][j2] + (bias ? bias[col] : 0.0f);
    }
  }
}

// ---------------- pyramid conv level ---------------------------------------
__global__ __launch_bounds__(64) void pyr_conv(
    const float* __restrict__ in, int in_base, int in_bstr,
    float* __restrict__ out, int out_base, int out_bstr, int out_len,
    const float* __restrict__ w, const float* __restrict__ bias,
    const float* __restrict__ bng, const float* __restrict__ bnb) {
  int blk = blockIdx.x;
  int b = blk / out_len, to = blk - b * out_len;
  int co = threadIdx.x;
  __shared__ float xin[4][64];
  const float* src = in + (size_t)(b * in_bstr + in_base + 4 * to) * 64;
#pragma unroll
  for (int r2 = 0; r2 < 4; r2++) xin[r2][co] = src[r2 * 64 + co];
  __syncthreads();
  const float* wr = w + (size_t)co * 256;
  float acc = bias[co];
#pragma unroll 16
  for (int ci = 0; ci < 64; ci++) {
    acc = fmaf(xin[0][ci], wr[ci * 4 + 0], acc);
    acc = fmaf(xin[1][ci], wr[ci * 4 + 1], acc);
    acc = fmaf(xin[2][ci], wr[ci * 4 + 2], acc);
    acc = fmaf(xin[3][ci], wr[ci * 4 + 3], acc);
  }
  float y = fmaf(bng[co], acc, bnb[co]);
  y = y > 0.0f ? y : expm1f(y);
  out[(size_t)(b * out_bstr + out_base + to) * 64 + co] = y;
}

// ---------------- LayerNorm over concat([embed, pyr_up]); dual output ------
__global__ __launch_bounds__(256) void ln_concat(
    const float* __restrict__ e, const float* __restrict__ pyru,
    const float* __restrict__ g, const float* __restrict__ bta,
    float* __restrict__ seq, ushort* __restrict__ seq_bf) {
  int r = blockIdx.x;
  int b = r / 1360, i = r - b * 1360;
  int tid = threadIdx.x;
  const float* src = (i < 1024)
      ? (e    + (size_t)(b * 1024 + i) * 512)
      : (pyru + (size_t)(b * 336 + (i - 1024)) * 512);
  float v0 = src[tid], v1 = src[tid + 256];
  __shared__ float red[256];
  red[tid] = v0 + v1;
  __syncthreads();
  for (int st = 128; st > 0; st >>= 1) { if (tid < st) red[tid] += red[tid + st]; __syncthreads(); }
  float mu = red[0] * (1.0f / 512.0f);
  __syncthreads();
  float d0 = v0 - mu, d1 = v1 - mu;
  red[tid] = d0 * d0 + d1 * d1;
  __syncthreads();
  for (int st = 128; st > 0; st >>= 1) { if (tid < st) red[tid] += red[tid + st]; __syncthreads(); }
  float inv = rsqrtf(red[0] * (1.0f / 512.0f) + 1e-5f);
  float o0 = d0 * inv * g[tid]       + bta[tid];
  float o1 = d1 * inv * g[tid + 256] + bta[tid + 256];
  float* dst = seq + (size_t)r * 512;
  dst[tid] = o0; dst[tid + 256] = o1;
  ushort* dbf = seq_bf + (size_t)r * 512;
  dbf[tid] = f2bf(o0); dbf[tid + 256] = f2bf(o1);
}

// ---------------- residual add + LayerNorm (in-place), dual output ---------
__global__ __launch_bounds__(256) void ln_add(
    float* __restrict__ seq, const float* __restrict__ t1,
    const float* __restrict__ g, const float* __restrict__ bta,
    ushort* __restrict__ seq_bf) {
  int r = blockIdx.x;
  int tid = threadIdx.x;
  float* row = seq + (size_t)r * 512;
  const float* trow = t1 + (size_t)r * 512;
  float v0 = row[tid] + trow[tid];
  float v1 = row[tid + 256] + trow[tid + 256];
  __shared__ float red[256];
  red[tid] = v0 + v1;
  __syncthreads();
  for (int st = 128; st > 0; st >>= 1) { if (tid < st) red[tid] += red[tid + st]; __syncthreads(); }
  float mu = red[0] * (1.0f / 512.0f);
  __syncthreads();
  float d0 = v0 - mu, d1 = v1 - mu;
  red[tid] = d0 * d0 + d1 * d1;
  __syncthreads();
  for (int st = 128; st > 0; st >>= 1) { if (tid < st) red[tid] += red[tid + st]; __syncthreads(); }
  float inv = rsqrtf(red[0] * (1.0f / 512.0f) + 1e-5f);
  float o0 = d0 * inv * g[tid]       + bta[tid];
  float o1 = d1 * inv * g[tid + 256] + bta[tid + 256];
  row[tid] = o0; row[tid + 256] = o1;
  ushort* dbf = seq_bf + (size_t)r * 512;
  dbf[tid] = f2bf(o0); dbf[tid + 256] = f2bf(o1);
}

// ---------------- sparse pyramidal attention (wave-per-head, no LDS) -------
__global__ __launch_bounds__(512) void attn_sparse(
    const ushort* __restrict__ qkv, ushort* __restrict__ o) {
  int r = blockIdx.x;
  int b = r / 1360, i = r - b * 1360;
  int h = threadIdx.x >> 6, lane = threadIdx.x & 63;
  int S, sz, li;
  if (i < 1024)      { li = 0; S = 0;    sz = 1024; }
  else if (i < 1280) { li = 1; S = 1024; sz = 256; }
  else if (i < 1344) { li = 2; S = 1280; sz = 64; }
  else               { li = 3; S = 1344; sz = 16; }
  int p = i - S;
  int lo = p - 2; if (lo < 0) lo = 0;
  int hi = p + 2; if (hi > sz - 1) hi = sz - 1;
  int cnt = hi - lo + 1;
  int nk = cnt + (li > 0 ? 4 : 0) + (li < 3 ? 1 : 0);
  int Sprev = (li == 1) ? 0 : (li == 2) ? 1024 : 1280;
  int Snext = (li == 0) ? 1024 : (li == 1) ? 1280 : 1344;
  int j2 = lane >> 2, c = lane & 3;
  int key;
  if (j2 < cnt)                      key = S + lo + j2;
  else if (li > 0 && j2 - cnt < 4)   key = Sprev + 4 * p + (j2 - cnt);
  else if (li < 3)                   key = Snext + (p >> 2);
  else                               key = S + p;
  float partial = 0.0f;
  {
    const uint4* qv = (const uint4*)(qkv + (size_t)r * 1536 + h * 64 + c * 16);
    const uint4* kv = (const uint4*)(qkv + (size_t)(b * 1360 + key) * 1536 + 512 + h * 64 + c * 16);
#pragma unroll
    for (int cc = 0; cc < 2; cc++) {
      uint4 a = qv[cc], k4 = kv[cc];
      partial = fmaf(lo16(a.x), lo16(k4.x), partial); partial = fmaf(hi16(a.x), hi16(k4.x), partial);
      partial = fmaf(lo16(a.y), lo16(k4.y), partial); partial = fmaf(hi16(a.y), hi16(k4.y), partial);
      partial = fmaf(lo16(a.z), lo16(k4.z), partial); partial = fmaf(hi16(a.z), hi16(k4.z), partial);
      partial = fmaf(lo16(a.w), lo16(k4.w), partial); partial = fmaf(hi16(a.w), hi16(k4.w), partial);
    }
  }
  partial += __shfl_xor(partial, 1);
  partial += __shfl_xor(partial, 2);
  float s = partial * 0.125f;
  float m = -1e30f;
  for (int j = 0; j < nk; j++) m = fmaxf(m, __shfl(s, 4 * j));
  float denom = 0.0f;
  for (int j = 0; j < nk; j++) denom += __expf(__shfl(s, 4 * j) - m);
  float inv = 1.0f / denom;
  float acc = 0.0f;
  for (int j = 0; j < nk; j++) {
    float pj = __expf(__shfl(s, 4 * j) - m) * inv;
    int kj = __shfl(key, 4 * j);
    float vv = bf2f(qkv[(size_t)(b * 1360 + kj) * 1536 + 1024 + h * 64 + lane]);
    acc = fmaf(pj, vv, acc);
  }
  o[(size_t)r * 512 + h * 64 + lane] = f2bf(acc);
}

// ---------------- output gather --------------------------------------------
__global__ __launch_bounds__(512) void gather_out(
    const float* __restrict__ seq, float* __restrict__ out) {
  int bl = blockIdx.x;
  int b = bl >> 10, i = bl & 1023;
  int d = threadIdx.x;
  size_t ob = (size_t)bl * 2048 + d;
  size_t base = (size_t)b * 1360;
  out[ob]        = seq[(base + i) * 512 + d];
  out[ob + 512]  = seq[(base + 1024 + (i >> 2)) * 512 + d];
  out[ob + 1024] = seq[(base + 1280 + (i >> 4)) * 512 + d];
  out[ob + 1536] = seq[(base + 1344 + (i >> 6)) * 512 + d];
}

// ---------------------------------------------------------------------------
extern "C" void kernel_launch(void* const* d_in, const int* in_sizes, int n_in,
                              void* d_out, int out_size, void* d_ws, size_t ws_size,
                              hipStream_t stream) {
  const float* x_enc   = (const float*)d_in[0];
  const float* x_mark  = (const float*)d_in[1];
  const float* conv_w  = (const float*)d_in[2];
  const float* conv_b  = (const float*)d_in[3];
  const float* temp_w  = (const float*)d_in[4];
  const float* temp_b  = (const float*)d_in[5];
  const float* down_w  = (const float*)d_in[6];
  const float* down_b  = (const float*)d_in[7];
  const float* pyr_w   = (const float*)d_in[8];
  const float* pyr_b   = (const float*)d_in[9];
  const float* bn_g    = (const float*)d_in[10];
  const float* bn_b    = (const float*)d_in[11];
  const float* up_w    = (const float*)d_in[12];
  const float* up_b    = (const float*)d_in[13];
  const float* norm_g  = (const float*)d_in[14];
  const float* norm_b  = (const float*)d_in[15];
  const float* wq      = (const float*)d_in[16];
  const float* wk      = (const float*)d_in[17];
  const float* wv      = (const float*)d_in[18];
  const float* fc_w    = (const float*)d_in[19];
  const float* fc_b    = (const float*)d_in[20];
  const float* ln1_g   = (const float*)d_in[21];
  const float* ln1_b   = (const float*)d_in[22];
  const float* w1      = (const float*)d_in[23];
  const float* b1      = (const float*)d_in[24];
  const float* w2      = (const float*)d_in[25];
  const float* b2      = (const float*)d_in[26];
  const float* ln2_g   = (const float*)d_in[27];
  const float* ln2_b   = (const float*)d_in[28];

  // ---- workspace layout (f32-word offsets); total 18,972,672 words = 72.4MB
  float* ws = (float*)d_ws;
  float*  e      = ws;                         // 2,097,152 w
  float*  tmp0   = ws + 2097152;               //   262,144 w
  float*  pyrf   = ws + 2359296;               //    86,016 w
  float*  pyru   = ws + 2445312;               //   688,128 w
  ushort* qkv_bf = (ushort*)ws;                // [5504][1536] bf16
  ushort* o_bf   = (ushort*)(ws + 4227072);    // [5504][512] bf16
  ushort* th_bf  = (ushort*)ws;                // [5504][2048] bf16
  float*  t1     = ws + 5636096;               // [5504][512] f32
  float*  seq    = ws + 8454144;               // [5504][512] f32
  ushort* seq_bf = (ushort*)(ws + 11272192);   // [5504][512] bf16
  ushort* qkvw   = (ushort*)(ws + 12681216);   // 4 x [1536][512] bf16
  ushort* fcw    = (ushort*)(ws + 14254080);   // 4 x [512][512] bf16
  ushort* w1t    = (ushort*)(ws + 14778368);   // 4 x [2048][512] bf16
  ushort* w2t    = (ushort*)(ws + 16875520);   // 4 x [512][2048] bf16

  // ---- weight cast+transpose (once per call) ----
  dim3 tb(32, 8);
  transpose_cast<<<dim3(16, 16, 4), tb, 0, stream>>>(wq, qkvw,          512, 512,  262144, 786432);
  transpose_cast<<<dim3(16, 16, 4), tb, 0, stream>>>(wk, qkvw + 262144, 512, 512,  262144, 786432);
  transpose_cast<<<dim3(16, 16, 4), tb, 0, stream>>>(wv, qkvw + 524288, 512, 512,  262144, 786432);
  transpose_cast<<<dim3(16, 16, 4), tb, 0, stream>>>(fc_w, fcw,         512, 512,  262144, 262144);
  transpose_cast<<<dim3(64, 16, 4), tb, 0, stream>>>(w1, w1t,           512, 2048, 1048576, 1048576);
  transpose_cast<<<dim3(16, 64, 4), tb, 0, stream>>>(w2, w2t,           2048, 512, 1048576, 1048576);

  // ---- prologue ----
  embed_kernel<<<4096, 512, 0, stream>>>(x_enc, x_mark, conv_w, conv_b,
                                         temp_w, temp_b, e);
  down_gemm<<<256, 256, 0, stream>>>(e, down_w, down_b, tmp0);
  pyr_conv<<<4 * 256, 64, 0, stream>>>(tmp0, 0, 1024, pyrf, 0, 336, 256,
                                       pyr_w, pyr_b, bn_g, bn_b);
  pyr_conv<<<4 * 64, 64, 0, stream>>>(pyrf, 0, 336, pyrf, 256, 336, 64,
                                      pyr_w + 16384, pyr_b + 64, bn_g + 64, bn_b + 64);
  pyr_conv<<<4 * 16, 64, 0, stream>>>(pyrf, 256, 336, pyrf, 320, 336, 16,
                                      pyr_w + 32768, pyr_b + 128, bn_g + 128, bn_b + 128);
  gemm_f32<<<dim3(8, 21), 256, 0, stream>>>(pyrf, up_w, up_b, pyru, 1344, 512, 64);
  ln_concat<<<5440, 256, 0, stream>>>(e, pyru, norm_g, norm_b, seq, seq_bf);

  // ---- layers ----
  for (int l = 0; l < 4; l++) {
    gemm_bf16<<<12 * 86, 256, 0, stream>>>(seq_bf, qkvw + (size_t)l * 786432,
                                           nullptr, qkv_bf, 1536, 512, 0, 1);
    attn_sparse<<<5440, 512, 0, stream>>>(qkv_bf, o_bf);
    gemm_bf16_t64<<<8 * 86, 256, 0, stream>>>(o_bf, fcw + (size_t)l * 262144,
                                              fc_b + l * 512, t1, 512, 512, 0);
    ln_add<<<5440, 256, 0, stream>>>(seq, t1, ln1_g + l * 512, ln1_b + l * 512, seq_bf);
    gemm_bf16<<<16 * 86, 256, 0, stream>>>(seq_bf, w1t + (size_t)l * 1048576,
                                           b1 + l * 2048, th_bf, 2048, 512, 1, 1);
    gemm_bf16_t64<<<8 * 86, 256, 0, stream>>>(th_bf, w2t + (size_t)l * 1048576,
                                              b2 + l * 512, t1, 512, 2048, 0);
    ln_add<<<5440, 256, 0, stream>>>(seq, t1, ln2_g + l * 512, ln2_b + l * 512, seq_bf);
  }
  gather_out<<<4096, 512, 0, stream>>>(seq, (float*)d_out);
}

// Round 8
// 619.582 us; speedup vs baseline: 1.1927x; 1.0689x over previous
//
#include <hip/hip_runtime.h>
#include <hip/hip_bf16.h>
#include <math.h>

// ---------------------------------------------------------------------------
// B=4, L_IN=1024, D=512, H=8, DK=64, DFF=2048, NL=4, WINDOW=[4,4,4], INNER=5.
// all_size=[1024,256,64,16], L_tot=1360, rows M=5440 padded to M_PAD=5504.
// ---------------------------------------------------------------------------

typedef __attribute__((ext_vector_type(8))) short short8;
typedef __attribute__((ext_vector_type(4))) float f32x4;

__device__ inline ushort f2bf(float x) {
  union { __hip_bfloat16 h; ushort u; } cv; cv.h = __float2bfloat16(x); return cv.u;
}
__device__ inline float bf2f(ushort u) {
  union { unsigned int i; float f; } cv; cv.i = (unsigned)u << 16; return cv.f;
}
__device__ inline float lo16(unsigned u) { union { unsigned i; float f; } c; c.i = u << 16; return c.f; }
__device__ inline float hi16(unsigned u) { union { unsigned i; float f; } c; c.i = u & 0xffff0000u; return c.f; }

// tanh-form GELU (max |err| vs exact erf-GELU ~3e-3; well within budget)
__device__ inline float gelu_f(float x) {
  float y = 0.7978845608028654f * (x + 0.044715f * x * x * x);
  float t = __expf(-2.0f * y);
  float th = (1.0f - t) / (1.0f + t);
  return 0.5f * x * (1.0f + th);
}

// bijective XCD-chunk swizzle (m204): round-robin id -> contiguous chunk/XCD
__device__ inline int xcd_chunk(int orig, int nwg) {
  int q = nwg >> 3, r = nwg & 7;
  int xcd = orig & 7, idx = orig >> 3;
  int base = (xcd < r) ? xcd * (q + 1) : r * (q + 1) + (xcd - r) * q;
  return base + idx;
}

#define GLD16(gp, lp)                                                        \
  __builtin_amdgcn_global_load_lds(                                          \
      (const __attribute__((address_space(1))) void*)(gp),                   \
      (__attribute__((address_space(3))) void*)(lp), 16, 0, 0)

// ---------------- embed: circular conv3 + posenc + mark projection ---------
__global__ __launch_bounds__(512) void embed_kernel(
    const float* __restrict__ x_enc, const float* __restrict__ x_mark,
    const float* __restrict__ conv_w, const float* __restrict__ conv_b,
    const float* __restrict__ temp_w, const float* __restrict__ temp_b,
    float* __restrict__ e) {
  int bl = blockIdx.x;
  int b = bl >> 10, l = bl & 1023;
  int d = threadIdx.x;
  int lm1 = (l + 1023) & 1023;
  int lp1 = (l + 1) & 1023;
  const float* w  = conv_w + d * 21;
  const float* x0 = x_enc + (size_t)(b * 1024 + lm1) * 7;
  const float* x1 = x_enc + (size_t)(b * 1024 + l)   * 7;
  const float* x2 = x_enc + (size_t)(b * 1024 + lp1) * 7;
  float acc = conv_b[d];
#pragma unroll
  for (int ci = 0; ci < 7; ci++) {
    acc = fmaf(x0[ci], w[ci * 3 + 0], acc);
    acc = fmaf(x1[ci], w[ci * 3 + 1], acc);
    acc = fmaf(x2[ci], w[ci * 3 + 2], acc);
  }
  int j = d >> 1;
  float dv = expf((float)(2 * j) * (-9.210340371976184f / 512.0f));
  float ang = (float)l * dv;
  float pe = (d & 1) ? cosf(ang) : sinf(ang);
  const float* xm = x_mark + (size_t)(b * 1024 + l) * 4;
  float mk = temp_b[d];
  mk = fmaf(xm[0], temp_w[d],        mk);
  mk = fmaf(xm[1], temp_w[512 + d],  mk);
  mk = fmaf(xm[2], temp_w[1024 + d], mk);
  mk = fmaf(xm[3], temp_w[1536 + d], mk);
  e[(size_t)bl * 512 + d] = acc + pe + mk;
}

// ---------------- weight cast+transpose: f32 [K][N] -> bf16 [N][K] ---------
__global__ __launch_bounds__(256) void transpose_cast(
    const float* __restrict__ src, ushort* __restrict__ dst,
    int K, int N, size_t src_lstride, size_t dst_lstride) {
  src += (size_t)blockIdx.z * src_lstride;
  dst += (size_t)blockIdx.z * dst_lstride;
  __shared__ float t[32][33];
  int k0 = blockIdx.y * 32, n0 = blockIdx.x * 32;
  int tx = threadIdx.x, ty = threadIdx.y;  // (32,8)
#pragma unroll
  for (int i = 0; i < 4; i++)
    t[ty + i * 8][tx] = src[(size_t)(k0 + ty + i * 8) * N + n0 + tx];
  __syncthreads();
#pragma unroll
  for (int i = 0; i < 4; i++)
    dst[(size_t)(n0 + ty + i * 8) * K + k0 + tx] = f2bf(t[tx][ty + i * 8]);
}

// ---------------- bf16 MFMA GEMM, 64x128 tile, BK=64, dbuf + swizzles ------
// A: [M_pad][K] bf16.  Bt: [N][K] bf16 (pre-transposed).  act 1 = GELU.
// LDS tile rows hold 64 k-elems (8 x 16B chunks); chunk XOR-swizzled by
// (row&7) via pre-swizzled global source + swizzled ds_read (2-way = free).
// 1D grid (N/128)*(M/64), XCD-chunk swizzled. 8 K-steps at K=512.
__global__ __launch_bounds__(256) void gemm_bf16(
    const ushort* __restrict__ A, const ushort* __restrict__ Bt,
    const float* __restrict__ bias, void* __restrict__ C,
    int N, int K, int act, int out_bf16) {
  __shared__ short As[2][4096];   // 64 rows x 64 k
  __shared__ short Bs[2][8192];   // 128 rows x 64 k
  int nbx = N >> 7;
  int wgid = xcd_chunk(blockIdx.x, gridDim.x);
  int bx = wgid % nbx, by = wgid / nbx;
  int tid = threadIdx.x;
  int w = tid >> 6, lane = tid & 63;
  int bm = by << 6, bn = bx << 7;
  // staging: thread covers (row = 32q + tid>>3, chunk = tid&7); global chunk
  // pre-swizzled so LDS slot (r,c) holds global chunk c^(r&7).
  int gch = (tid & 7) ^ ((tid >> 3) & 7);
  const short* Ab = (const short*)A + (size_t)(bm + (tid >> 3)) * K + gch * 8;
  const short* Bb = (const short*)Bt + (size_t)(bn + (tid >> 3)) * K + gch * 8;
  int ldst = (tid & 192) * 8;                      // wave-uniform: w*512 shorts
  int wr = (w >> 1) << 5, wc = (w & 1) << 6;
  int lr = lane & 15, kg = lane >> 4;
  int cs0 = ((kg)     ^ (lane & 7)) * 8;           // read chunk, k-sub 0
  int cs1 = ((4 + kg) ^ (lane & 7)) * 8;           // read chunk, k-sub 1
  f32x4 acc[2][4] = {};
#define STG(buf, kt)  do {                                                   \
    GLD16(Ab + (kt),                      &As[buf][ldst]);                   \
    GLD16(Ab + (kt) + (size_t)32 * K,     &As[buf][2048 + ldst]);            \
    GLD16(Bb + (kt),                      &Bs[buf][ldst]);                   \
    GLD16(Bb + (kt) + (size_t)32 * K,     &Bs[buf][2048 + ldst]);            \
    GLD16(Bb + (kt) + (size_t)64 * K,     &Bs[buf][4096 + ldst]);            \
    GLD16(Bb + (kt) + (size_t)96 * K,     &Bs[buf][6144 + ldst]); } while (0)
  STG(0, 0);
  __syncthreads();
  int nt = K >> 6;
  for (int t = 0; t < nt; t++) {
    int cur = t & 1;
    if (t + 1 < nt) STG(cur ^ 1, (t + 1) << 6);
    short8 a_[2][2], b_[4][2];
#pragma unroll
    for (int m = 0; m < 2; m++) {
      int rb = (wr + m * 16 + lr) * 64;
      a_[m][0] = *(const short8*)&As[cur][rb + cs0];
      a_[m][1] = *(const short8*)&As[cur][rb + cs1];
    }
#pragma unroll
    for (int n = 0; n < 4; n++) {
      int rb = (wc + n * 16 + lr) * 64;
      b_[n][0] = *(const short8*)&Bs[cur][rb + cs0];
      b_[n][1] = *(const short8*)&Bs[cur][rb + cs1];
    }
#pragma unroll
    for (int ks = 0; ks < 2; ks++)
#pragma unroll
      for (int m = 0; m < 2; m++)
#pragma unroll
        for (int n = 0; n < 4; n++)
          acc[m][n] = __builtin_amdgcn_mfma_f32_16x16x32_bf16(a_[m][ks], b_[n][ks], acc[m][n], 0, 0, 0);
    __syncthreads();
  }
#undef STG
  int r0 = bm + wr + kg * 4;
  int c0 = bn + wc + lr;
#pragma unroll
  for (int m = 0; m < 2; m++) {
#pragma unroll
    for (int n = 0; n < 4; n++) {
      int col = c0 + n * 16;
      float bv = bias ? bias[col] : 0.0f;
#pragma unroll
      for (int j = 0; j < 4; j++) {
        int row = r0 + m * 16 + j;
        float v = acc[m][n][j] + bv;
        if (act == 1) v = gelu_f(v);
        if (out_bf16) ((ushort*)C)[(size_t)row * N + col] = f2bf(v);
        else          ((float*)C)[(size_t)row * N + col] = v;
      }
    }
  }
}

// ---------------- bf16 MFMA GEMM, 64x64 tile, BK=64, dbuf + swizzles -------
__global__ __launch_bounds__(256) void gemm_bf16_t64(
    const ushort* __restrict__ A, const ushort* __restrict__ Bt,
    const float* __restrict__ bias, void* __restrict__ C,
    int N, int K, int out_bf16) {
  __shared__ short As[2][4096];   // 64 rows x 64 k
  __shared__ short Bs[2][4096];
  int nbx = N >> 6;
  int wgid = xcd_chunk(blockIdx.x, gridDim.x);
  int bx = wgid % nbx, by = wgid / nbx;
  int tid = threadIdx.x;
  int w = tid >> 6, lane = tid & 63;
  int bm = by << 6, bn = bx << 6;
  int gch = (tid & 7) ^ ((tid >> 3) & 7);
  const short* Ab = (const short*)A + (size_t)(bm + (tid >> 3)) * K + gch * 8;
  const short* Bb = (const short*)Bt + (size_t)(bn + (tid >> 3)) * K + gch * 8;
  int ldst = (tid & 192) * 8;          // wave-uniform base (shorts)
  int wr = (w >> 1) << 5, wc = (w & 1) << 5;
  int lr = lane & 15, kg = lane >> 4;
  int cs0 = ((kg)     ^ (lane & 7)) * 8;
  int cs1 = ((4 + kg) ^ (lane & 7)) * 8;
  f32x4 acc[2][2] = {};
#define STG64(buf, kt) do {                                                  \
    GLD16(Ab + (kt),                  &As[buf][ldst]);                       \
    GLD16(Ab + (kt) + (size_t)32 * K, &As[buf][2048 + ldst]);                \
    GLD16(Bb + (kt),                  &Bs[buf][ldst]);                       \
    GLD16(Bb + (kt) + (size_t)32 * K, &Bs[buf][2048 + ldst]); } while (0)
  STG64(0, 0);
  __syncthreads();
  int nt = K >> 6;
  for (int t = 0; t < nt; t++) {
    int cur = t & 1;
    if (t + 1 < nt) STG64(cur ^ 1, (t + 1) << 6);
    short8 a_[2][2], b_[2][2];
#pragma unroll
    for (int m = 0; m < 2; m++) {
      int rb = (wr + m * 16 + lr) * 64;
      a_[m][0] = *(const short8*)&As[cur][rb + cs0];
      a_[m][1] = *(const short8*)&As[cur][rb + cs1];
    }
#pragma unroll
    for (int n = 0; n < 2; n++) {
      int rb = (wc + n * 16 + lr) * 64;
      b_[n][0] = *(const short8*)&Bs[cur][rb + cs0];
      b_[n][1] = *(const short8*)&Bs[cur][rb + cs1];
    }
#pragma unroll
    for (int ks = 0; ks < 2; ks++)
#pragma unroll
      for (int m = 0; m < 2; m++)
#pragma unroll
        for (int n = 0; n < 2; n++)
          acc[m][n] = __builtin_amdgcn_mfma_f32_16x16x32_bf16(a_[m][ks], b_[n][ks], acc[m][n], 0, 0, 0);
    __syncthreads();
  }
#undef STG64
  int r0 = bm + wr + kg * 4;
  int c0 = bn + wc + lr;
#pragma unroll
  for (int m = 0; m < 2; m++) {
#pragma unroll
    for (int n = 0; n < 2; n++) {
      int col = c0 + n * 16;
      float bv = bias ? bias[col] : 0.0f;
#pragma unroll
      for (int j = 0; j < 4; j++) {
        int row = r0 + m * 16 + j;
        float v = acc[m][n][j] + bv;
        if (out_bf16) ((ushort*)C)[(size_t)row * N + col] = f2bf(v);
        else          ((float*)C)[(size_t)row * N + col] = v;
      }
    }
  }
}

// ---------------- down-projection GEMM: [4096][512] @ [512][64] ------------
__global__ __launch_bounds__(256) void down_gemm(
    const float* __restrict__ A, const float* __restrict__ B,
    const float* __restrict__ bias, float* __restrict__ C) {
  int wgid = xcd_chunk(blockIdx.x, gridDim.x);
  int r0 = wgid << 4;
  int tid = threadIdx.x;
  int col = tid & 63, rq = tid >> 6;
  __shared__ float As[16][32];
  __shared__ float Bs[32][64];
  float acc0 = 0, acc1 = 0, acc2 = 0, acc3 = 0;
  for (int kt = 0; kt < 512; kt += 32) {
    {
      int e = tid * 2;
      int ar = e >> 5, ak = e & 31;
      *(float2*)&As[ar][ak] = *(const float2*)&A[(size_t)(r0 + ar) * 512 + kt + ak];
    }
    {
      int e = tid * 8;
      int br = e >> 6, bc = e & 63;
      *(float4*)&Bs[br][bc]     = *(const float4*)&B[(size_t)(kt + br) * 64 + bc];
      *(float4*)&Bs[br][bc + 4] = *(const float4*)&B[(size_t)(kt + br) * 64 + bc + 4];
    }
    __syncthreads();
#pragma unroll
    for (int kk = 0; kk < 32; kk++) {
      float bv = Bs[kk][col];
      acc0 = fmaf(As[rq][kk],      bv, acc0);
      acc1 = fmaf(As[rq + 4][kk],  bv, acc1);
      acc2 = fmaf(As[rq + 8][kk],  bv, acc2);
      acc3 = fmaf(As[rq + 12][kk], bv, acc3);
    }
    __syncthreads();
  }
  float bv = bias[col];
  C[(size_t)(r0 + rq) * 64 + col]      = acc0 + bv;
  C[(size_t)(r0 + rq + 4) * 64 + col]  = acc1 + bv;
  C[(size_t)(r0 + rq + 8) * 64 + col]  = acc2 + bv;
  C[(size_t)(r0 + rq + 12) * 64 + col] = acc3 + bv;
}

// ---------------- small f32 GEMM (up projection) ---------------------------
__global__ __launch_bounds__(256) void gemm_f32(
    const float* __restrict__ A, const float* __restrict__ B,
    const float* __restrict__ bias, float* __restrict__ C,
    int M, int N, int K) {
  __shared__ float As[16][68];
  __shared__ float Bs[16][64];
  int tid = threadIdx.x;
  int tx = tid & 15, ty = tid >> 4;
  int bm = blockIdx.y << 6, bn = blockIdx.x << 6;
  const float* Ab = A + (size_t)bm * K;
  const float* Bb = B + bn;
  float acc[4][4] = {};
  for (int kt = 0; kt < K; kt += 16) {
#pragma unroll
    for (int r = 0; r < 4; r++) {
      int e2 = r * 256 + tid;
      As[e2 & 15][e2 >> 4] = Ab[(size_t)(e2 >> 4) * K + kt + (e2 & 15)];
    }
#pragma unroll
    for (int r = 0; r < 4; r++) {
      int e2 = r * 256 + tid;
      Bs[e2 >> 6][e2 & 63] = Bb[(size_t)(kt + (e2 >> 6)) * N + (e2 & 63)];
    }
    __syncthreads();
#pragma unroll
    for (int kk = 0; kk < 16; kk++) {
      float a0 = As[kk][(ty << 2) + 0], a1 = As[kk][(ty << 2) + 1];
      float a2 = As[kk][(ty << 2) + 2], a3 = As[kk][(ty << 2) + 3];
      float b0 = Bs[kk][(tx << 2) + 0], b1 = Bs[kk][(tx << 2) + 1];
      float b2 = Bs[kk][(tx << 2) + 2], b3 = Bs[kk][(tx << 2) + 3];
      acc[0][0] = fmaf(a0, b0, acc[0][0]); acc[0][1] = fmaf(a0, b1, acc[0][1]);
      acc[0][2] = fmaf(a0, b2, acc[0][2]); acc[0][3] = fmaf(a0, b3, acc[0][3]);
      acc[1][0] = fmaf(a1, b0, acc[1][0]); acc[1][1] = fmaf(a1, b1, acc[1][1]);
      acc[1][2] = fmaf(a1, b2, acc[1][2]); acc[1][3] = fmaf(a1, b3, acc[1][3]);
      acc[2][0] = fmaf(a2, b0, acc[2][0]); acc[2][1] = fmaf(a2, b1, acc[2][1]);
      acc[2][2] = fmaf(a2, b2, acc[2][2]); acc[2][3] = fmaf(a2, b3, acc[2][3]);
      acc[3][0] = fmaf(a3, b0, acc[3][0]); acc[3][1] = fmaf(a3, b1, acc[3][1]);
      acc[3][2] = fmaf(a3, b2, acc[3][2]); acc[3][3] = fmaf(a3, b3, acc[3][3]);
    }
    __syncthreads();
  }
#pragma unroll
  for (int i2 = 0; i2 < 4; i2++) {
    int row = bm + (ty << 2) + i2;
#pragma unroll
    for (int j2 = 0; j2 < 4; j2++) {
      int col = bn + (tx << 2) + j2;
      C[(size_t)row * N + col] = acc[i2][j2] + (bias ? bias[col] : 0.0f);
    }
  }
}

// ---------------- pyramid conv level ---------------------------------------
__global__ __launch_bounds__(64) void pyr_conv(
    const float* __restrict__ in, int in_base, int in_bstr,
    float* __restrict__ out, int out_base, int out_bstr, int out_len,
    const float* __restrict__ w, const float* __restrict__ bias,
    const float* __restrict__ bng, const float* __restrict__ bnb) {
  int blk = blockIdx.x;
  int b = blk / out_len, to = blk - b * out_len;
  int co = threadIdx.x;
  __shared__ float xin[4][64];
  const float* src = in + (size_t)(b * in_bstr + in_base + 4 * to) * 64;
#pragma unroll
  for (int r2 = 0; r2 < 4; r2++) xin[r2][co] = src[r2 * 64 + co];
  __syncthreads();
  const float* wr = w + (size_t)co * 256;
  float acc = bias[co];
#pragma unroll 16
  for (int ci = 0; ci < 64; ci++) {
    acc = fmaf(xin[0][ci], wr[ci * 4 + 0], acc);
    acc = fmaf(xin[1][ci], wr[ci * 4 + 1], acc);
    acc = fmaf(xin[2][ci], wr[ci * 4 + 2], acc);
    acc = fmaf(xin[3][ci], wr[ci * 4 + 3], acc);
  }
  float y = fmaf(bng[co], acc, bnb[co]);
  y = y > 0.0f ? y : expm1f(y);
  out[(size_t)(b * out_bstr + out_base + to) * 64 + co] = y;
}

// ---------------- LayerNorm over concat([embed, pyr_up]); dual output ------
__global__ __launch_bounds__(256) void ln_concat(
    const float* __restrict__ e, const float* __restrict__ pyru,
    const float* __restrict__ g, const float* __restrict__ bta,
    float* __restrict__ seq, ushort* __restrict__ seq_bf) {
  int r = blockIdx.x;
  int b = r / 1360, i = r - b * 1360;
  int tid = threadIdx.x;
  const float* src = (i < 1024)
      ? (e    + (size_t)(b * 1024 + i) * 512)
      : (pyru + (size_t)(b * 336 + (i - 1024)) * 512);
  float v0 = src[tid], v1 = src[tid + 256];
  __shared__ float red[256];
  red[tid] = v0 + v1;
  __syncthreads();
  for (int st = 128; st > 0; st >>= 1) { if (tid < st) red[tid] += red[tid + st]; __syncthreads(); }
  float mu = red[0] * (1.0f / 512.0f);
  __syncthreads();
  float d0 = v0 - mu, d1 = v1 - mu;
  red[tid] = d0 * d0 + d1 * d1;
  __syncthreads();
  for (int st = 128; st > 0; st >>= 1) { if (tid < st) red[tid] += red[tid + st]; __syncthreads(); }
  float inv = rsqrtf(red[0] * (1.0f / 512.0f) + 1e-5f);
  float o0 = d0 * inv * g[tid]       + bta[tid];
  float o1 = d1 * inv * g[tid + 256] + bta[tid + 256];
  float* dst = seq + (size_t)r * 512;
  dst[tid] = o0; dst[tid + 256] = o1;
  ushort* dbf = seq_bf + (size_t)r * 512;
  dbf[tid] = f2bf(o0); dbf[tid + 256] = f2bf(o1);
}

// ---------------- residual add + LayerNorm (bf16 t1), dual output ----------
__global__ __launch_bounds__(256) void ln_add(
    float* __restrict__ seq, const ushort* __restrict__ t1,
    const float* __restrict__ g, const float* __restrict__ bta,
    ushort* __restrict__ seq_bf) {
  int r = blockIdx.x;
  int tid = threadIdx.x;
  float* row = seq + (size_t)r * 512;
  const ushort* trow = t1 + (size_t)r * 512;
  float v0 = row[tid] + bf2f(trow[tid]);
  float v1 = row[tid + 256] + bf2f(trow[tid + 256]);
  __shared__ float red[256];
  red[tid] = v0 + v1;
  __syncthreads();
  for (int st = 128; st > 0; st >>= 1) { if (tid < st) red[tid] += red[tid + st]; __syncthreads(); }
  float mu = red[0] * (1.0f / 512.0f);
  __syncthreads();
  float d0 = v0 - mu, d1 = v1 - mu;
  red[tid] = d0 * d0 + d1 * d1;
  __syncthreads();
  for (int st = 128; st > 0; st >>= 1) { if (tid < st) red[tid] += red[tid + st]; __syncthreads(); }
  float inv = rsqrtf(red[0] * (1.0f / 512.0f) + 1e-5f);
  float o0 = d0 * inv * g[tid]       + bta[tid];
  float o1 = d1 * inv * g[tid + 256] + bta[tid + 256];
  row[tid] = o0; row[tid + 256] = o1;
  ushort* dbf = seq_bf + (size_t)r * 512;
  dbf[tid] = f2bf(o0); dbf[tid + 256] = f2bf(o1);
}

// ---------------- sparse pyramidal attention (wave-per-head, no LDS) -------
__global__ __launch_bounds__(512) void attn_sparse(
    const ushort* __restrict__ qkv, ushort* __restrict__ o) {
  int r = blockIdx.x;
  int b = r / 1360, i = r - b * 1360;
  int h = threadIdx.x >> 6, lane = threadIdx.x & 63;
  int S, sz, li;
  if (i < 1024)      { li = 0; S = 0;    sz = 1024; }
  else if (i < 1280) { li = 1; S = 1024; sz = 256; }
  else if (i < 1344) { li = 2; S = 1280; sz = 64; }
  else               { li = 3; S = 1344; sz = 16; }
  int p = i - S;
  int lo = p - 2; if (lo < 0) lo = 0;
  int hi = p + 2; if (hi > sz - 1) hi = sz - 1;
  int cnt = hi - lo + 1;
  int nk = cnt + (li > 0 ? 4 : 0) + (li < 3 ? 1 : 0);
  int Sprev = (li == 1) ? 0 : (li == 2) ? 1024 : 1280;
  int Snext = (li == 0) ? 1024 : (li == 1) ? 1280 : 1344;
  int j2 = lane >> 2, c = lane & 3;
  int key;
  if (j2 < cnt)                      key = S + lo + j2;
  else if (li > 0 && j2 - cnt < 4)   key = Sprev + 4 * p + (j2 - cnt);
  else if (li < 3)                   key = Snext + (p >> 2);
  else                               key = S + p;
  float partial = 0.0f;
  {
    const uint4* qv = (const uint4*)(qkv + (size_t)r * 1536 + h * 64 + c * 16);
    const uint4* kv = (const uint4*)(qkv + (size_t)(b * 1360 + key) * 1536 + 512 + h * 64 + c * 16);
#pragma unroll
    for (int cc = 0; cc < 2; cc++) {
      uint4 a = qv[cc], k4 = kv[cc];
      partial = fmaf(lo16(a.x), lo16(k4.x), partial); partial = fmaf(hi16(a.x), hi16(k4.x), partial);
      partial = fmaf(lo16(a.y), lo16(k4.y), partial); partial = fmaf(hi16(a.y), hi16(k4.y), partial);
      partial = fmaf(lo16(a.z), lo16(k4.z), partial); partial = fmaf(hi16(a.z), hi16(k4.z), partial);
      partial = fmaf(lo16(a.w), lo16(k4.w), partial); partial = fmaf(hi16(a.w), hi16(k4.w), partial);
    }
  }
  partial += __shfl_xor(partial, 1);
  partial += __shfl_xor(partial, 2);
  float s = partial * 0.125f;
  float m = -1e30f;
  for (int j = 0; j < nk; j++) m = fmaxf(m, __shfl(s, 4 * j));
  float denom = 0.0f;
  for (int j = 0; j < nk; j++) denom += __expf(__shfl(s, 4 * j) - m);
  float inv = 1.0f / denom;
  float acc = 0.0f;
  for (int j = 0; j < nk; j++) {
    float pj = __expf(__shfl(s, 4 * j) - m) * inv;
    int kj = __shfl(key, 4 * j);
    float vv = bf2f(qkv[(size_t)(b * 1360 + kj) * 1536 + 1024 + h * 64 + lane]);
    acc = fmaf(pj, vv, acc);
  }
  o[(size_t)r * 512 + h * 64 + lane] = f2bf(acc);
}

// ---------------- output gather --------------------------------------------
__global__ __launch_bounds__(512) void gather_out(
    const float* __restrict__ seq, float* __restrict__ out) {
  int bl = blockIdx.x;
  int b = bl >> 10, i = bl & 1023;
  int d = threadIdx.x;
  size_t ob = (size_t)bl * 2048 + d;
  size_t base = (size_t)b * 1360;
  out[ob]        = seq[(base + i) * 512 + d];
  out[ob + 512]  = seq[(base + 1024 + (i >> 2)) * 512 + d];
  out[ob + 1024] = seq[(base + 1280 + (i >> 4)) * 512 + d];
  out[ob + 1536] = seq[(base + 1344 + (i >> 6)) * 512 + d];
}

// ---------------------------------------------------------------------------
extern "C" void kernel_launch(void* const* d_in, const int* in_sizes, int n_in,
                              void* d_out, int out_size, void* d_ws, size_t ws_size,
                              hipStream_t stream) {
  const float* x_enc   = (const float*)d_in[0];
  const float* x_mark  = (const float*)d_in[1];
  const float* conv_w  = (const float*)d_in[2];
  const float* conv_b  = (const float*)d_in[3];
  const float* temp_w  = (const float*)d_in[4];
  const float* temp_b  = (const float*)d_in[5];
  const float* down_w  = (const float*)d_in[6];
  const float* down_b  = (const float*)d_in[7];
  const float* pyr_w   = (const float*)d_in[8];
  const float* pyr_b   = (const float*)d_in[9];
  const float* bn_g    = (const float*)d_in[10];
  const float* bn_b    = (const float*)d_in[11];
  const float* up_w    = (const float*)d_in[12];
  const float* up_b    = (const float*)d_in[13];
  const float* norm_g  = (const float*)d_in[14];
  const float* norm_b  = (const float*)d_in[15];
  const float* wq      = (const float*)d_in[16];
  const float* wk      = (const float*)d_in[17];
  const float* wv      = (const float*)d_in[18];
  const float* fc_w    = (const float*)d_in[19];
  const float* fc_b    = (const float*)d_in[20];
  const float* ln1_g   = (const float*)d_in[21];
  const float* ln1_b   = (const float*)d_in[22];
  const float* w1      = (const float*)d_in[23];
  const float* b1      = (const float*)d_in[24];
  const float* w2      = (const float*)d_in[25];
  const float* b2      = (const float*)d_in[26];
  const float* ln2_g   = (const float*)d_in[27];
  const float* ln2_b   = (const float*)d_in[28];

  // ---- workspace layout (f32-word offsets); total 18,972,672 words = 72.4MB
  float* ws = (float*)d_ws;
  float*  e      = ws;                         // 2,097,152 w
  float*  tmp0   = ws + 2097152;               //   262,144 w
  float*  pyrf   = ws + 2359296;               //    86,016 w
  float*  pyru   = ws + 2445312;               //   688,128 w
  ushort* qkv_bf = (ushort*)ws;                // [5504][1536] bf16
  ushort* o_bf   = (ushort*)(ws + 4227072);    // [5504][512] bf16
  ushort* th_bf  = (ushort*)ws;                // [5504][2048] bf16
  ushort* t1     = (ushort*)(ws + 5636096);    // [5504][512] bf16 (in t1 region)
  float*  seq    = ws + 8454144;               // [5504][512] f32
  ushort* seq_bf = (ushort*)(ws + 11272192);   // [5504][512] bf16
  ushort* qkvw   = (ushort*)(ws + 12681216);   // 4 x [1536][512] bf16
  ushort* fcw    = (ushort*)(ws + 14254080);   // 4 x [512][512] bf16
  ushort* w1t    = (ushort*)(ws + 14778368);   // 4 x [2048][512] bf16
  ushort* w2t    = (ushort*)(ws + 16875520);   // 4 x [512][2048] bf16

  // ---- weight cast+transpose (once per call) ----
  dim3 tb(32, 8);
  transpose_cast<<<dim3(16, 16, 4), tb, 0, stream>>>(wq, qkvw,          512, 512,  262144, 786432);
  transpose_cast<<<dim3(16, 16, 4), tb, 0, stream>>>(wk, qkvw + 262144, 512, 512,  262144, 786432);
  transpose_cast<<<dim3(16, 16, 4), tb, 0, stream>>>(wv, qkvw + 524288, 512, 512,  262144, 786432);
  transpose_cast<<<dim3(16, 16, 4), tb, 0, stream>>>(fc_w, fcw,         512, 512,  262144, 262144);
  transpose_cast<<<dim3(64, 16, 4), tb, 0, stream>>>(w1, w1t,           512, 2048, 1048576, 1048576);
  transpose_cast<<<dim3(16, 64, 4), tb, 0, stream>>>(w2, w2t,           2048, 512, 1048576, 1048576);

  // ---- prologue ----
  embed_kernel<<<4096, 512, 0, stream>>>(x_enc, x_mark, conv_w, conv_b,
                                         temp_w, temp_b, e);
  down_gemm<<<256, 256, 0, stream>>>(e, down_w, down_b, tmp0);
  pyr_conv<<<4 * 256, 64, 0, stream>>>(tmp0, 0, 1024, pyrf, 0, 336, 256,
                                       pyr_w, pyr_b, bn_g, bn_b);
  pyr_conv<<<4 * 64, 64, 0, stream>>>(pyrf, 0, 336, pyrf, 256, 336, 64,
                                      pyr_w + 16384, pyr_b + 64, bn_g + 64, bn_b + 64);
  pyr_conv<<<4 * 16, 64, 0, stream>>>(pyrf, 256, 336, pyrf, 320, 336, 16,
                                      pyr_w + 32768, pyr_b + 128, bn_g + 128, bn_b + 128);
  gemm_f32<<<dim3(8, 21), 256, 0, stream>>>(pyrf, up_w, up_b, pyru, 1344, 512, 64);
  ln_concat<<<5440, 256, 0, stream>>>(e, pyru, norm_g, norm_b, seq, seq_bf);

  // ---- layers ----
  for (int l = 0; l < 4; l++) {
    gemm_bf16<<<12 * 86, 256, 0, stream>>>(seq_bf, qkvw + (size_t)l * 786432,
                                           nullptr, qkv_bf, 1536, 512, 0, 1);
    attn_sparse<<<5440, 512, 0, stream>>>(qkv_bf, o_bf);
    gemm_bf16_t64<<<8 * 86, 256, 0, stream>>>(o_bf, fcw + (size_t)l * 262144,
                                              fc_b + l * 512, t1, 512, 512, 1);
    ln_add<<<5440, 256, 0, stream>>>(seq, t1, ln1_g + l * 512, ln1_b + l * 512, seq_bf);
    gemm_bf16<<<16 * 86, 256, 0, stream>>>(seq_bf, w1t + (size_t)l * 1048576,
                                           b1 + l * 2048, th_bf, 2048, 512, 1, 1);
    gemm_bf16_t64<<<8 * 86, 256, 0, stream>>>(th_bf, w2t + (size_t)l * 1048576,
                                              b2 + l * 512, t1, 512, 2048, 1);
    ln_add<<<5440, 256, 0, stream>>>(seq, t1, ln2_g + l * 512, ln2_b + l * 512, seq_bf);
  }
  gather_out<<<4096, 512, 0, stream>>>(seq, (float*)d_out);
}

// Round 9
// 609.232 us; speedup vs baseline: 1.2130x; 1.0170x over previous
//
#include <hip/hip_runtime.h>
#include <hip/hip_bf16.h>
#include <math.h>

// ---------------------------------------------------------------------------
// B=4, L_IN=1024, D=512, H=8, DK=64, DFF=2048, NL=4, WINDOW=[4,4,4], INNER=5.
// all_size=[1024,256,64,16], L_tot=1360, rows M=5440 padded to M_PAD=5504.
// ---------------------------------------------------------------------------

typedef __attribute__((ext_vector_type(8))) short short8;
typedef __attribute__((ext_vector_type(4))) float f32x4;

__device__ inline ushort f2bf(float x) {
  union { __hip_bfloat16 h; ushort u; } cv; cv.h = __float2bfloat16(x); return cv.u;
}
__device__ inline float bf2f(ushort u) {
  union { unsigned int i; float f; } cv; cv.i = (unsigned)u << 16; return cv.f;
}
__device__ inline float lo16(unsigned u) { union { unsigned i; float f; } c; c.i = u << 16; return c.f; }
__device__ inline float hi16(unsigned u) { union { unsigned i; float f; } c; c.i = u & 0xffff0000u; return c.f; }
__device__ inline unsigned pack2(float a, float b) {
  return (unsigned)f2bf(a) | ((unsigned)f2bf(b) << 16);
}

// tanh-form GELU (max |err| vs exact erf-GELU ~3e-3; well within budget)
__device__ inline float gelu_f(float x) {
  float y = 0.7978845608028654f * (x + 0.044715f * x * x * x);
  float t = __expf(-2.0f * y);
  float th = (1.0f - t) / (1.0f + t);
  return 0.5f * x * (1.0f + th);
}

// bijective XCD-chunk swizzle (m204): round-robin id -> contiguous chunk/XCD
__device__ inline int xcd_chunk(int orig, int nwg) {
  int q = nwg >> 3, r = nwg & 7;
  int xcd = orig & 7, idx = orig >> 3;
  int base = (xcd < r) ? xcd * (q + 1) : r * (q + 1) + (xcd - r) * q;
  return base + idx;
}

#define GLD16(gp, lp)                                                        \
  __builtin_amdgcn_global_load_lds(                                          \
      (const __attribute__((address_space(1))) void*)(gp),                   \
      (__attribute__((address_space(3))) void*)(lp), 16, 0, 0)

// ---------------- embed: circular conv3 + posenc + mark projection ---------
__global__ __launch_bounds__(512) void embed_kernel(
    const float* __restrict__ x_enc, const float* __restrict__ x_mark,
    const float* __restrict__ conv_w, const float* __restrict__ conv_b,
    const float* __restrict__ temp_w, const float* __restrict__ temp_b,
    float* __restrict__ e) {
  int bl = blockIdx.x;
  int b = bl >> 10, l = bl & 1023;
  int d = threadIdx.x;
  int lm1 = (l + 1023) & 1023;
  int lp1 = (l + 1) & 1023;
  const float* w  = conv_w + d * 21;
  const float* x0 = x_enc + (size_t)(b * 1024 + lm1) * 7;
  const float* x1 = x_enc + (size_t)(b * 1024 + l)   * 7;
  const float* x2 = x_enc + (size_t)(b * 1024 + lp1) * 7;
  float acc = conv_b[d];
#pragma unroll
  for (int ci = 0; ci < 7; ci++) {
    acc = fmaf(x0[ci], w[ci * 3 + 0], acc);
    acc = fmaf(x1[ci], w[ci * 3 + 1], acc);
    acc = fmaf(x2[ci], w[ci * 3 + 2], acc);
  }
  int j = d >> 1;
  float dv = expf((float)(2 * j) * (-9.210340371976184f / 512.0f));
  float ang = (float)l * dv;
  float pe = (d & 1) ? cosf(ang) : sinf(ang);
  const float* xm = x_mark + (size_t)(b * 1024 + l) * 4;
  float mk = temp_b[d];
  mk = fmaf(xm[0], temp_w[d],        mk);
  mk = fmaf(xm[1], temp_w[512 + d],  mk);
  mk = fmaf(xm[2], temp_w[1024 + d], mk);
  mk = fmaf(xm[3], temp_w[1536 + d], mk);
  e[(size_t)bl * 512 + d] = acc + pe + mk;
}

// ---------------- weight cast+transpose: f32 [K][N] -> bf16 [N][K] ---------
__global__ __launch_bounds__(256) void transpose_cast(
    const float* __restrict__ src, ushort* __restrict__ dst,
    int K, int N, size_t src_lstride, size_t dst_lstride) {
  src += (size_t)blockIdx.z * src_lstride;
  dst += (size_t)blockIdx.z * dst_lstride;
  __shared__ float t[32][33];
  int k0 = blockIdx.y * 32, n0 = blockIdx.x * 32;
  int tx = threadIdx.x, ty = threadIdx.y;  // (32,8)
#pragma unroll
  for (int i = 0; i < 4; i++)
    t[ty + i * 8][tx] = src[(size_t)(k0 + ty + i * 8) * N + n0 + tx];
  __syncthreads();
#pragma unroll
  for (int i = 0; i < 4; i++)
    dst[(size_t)(n0 + ty + i * 8) * K + k0 + tx] = f2bf(t[tx][ty + i * 8]);
}

// ---------------- bf16 MFMA GEMM, 64x128 tile, BK=64, dbuf + swizzles ------
// A: [M_pad][K] bf16.  Bt: [N][K] bf16 (pre-transposed).  act 1 = GELU.
// LDS rows hold 64 k (8 x 16B chunks), chunk XOR-swizzled by row&7 via
// pre-swizzled global source + swizzled ds_read. XCD-chunk 1D grid.
__global__ __launch_bounds__(256) void gemm_bf16(
    const ushort* __restrict__ A, const ushort* __restrict__ Bt,
    const float* __restrict__ bias, void* __restrict__ C,
    int N, int K, int act, int out_bf16) {
  __shared__ short As[2][4096];   // 64 rows x 64 k
  __shared__ short Bs[2][8192];   // 128 rows x 64 k
  int nbx = N >> 7;
  int wgid = xcd_chunk(blockIdx.x, gridDim.x);
  int bx = wgid % nbx, by = wgid / nbx;
  int tid = threadIdx.x;
  int w = tid >> 6, lane = tid & 63;
  int bm = by << 6, bn = bx << 7;
  int gch = (tid & 7) ^ ((tid >> 3) & 7);
  const short* Ab = (const short*)A + (size_t)(bm + (tid >> 3)) * K + gch * 8;
  const short* Bb = (const short*)Bt + (size_t)(bn + (tid >> 3)) * K + gch * 8;
  int ldst = (tid & 192) * 8;                      // wave-uniform: w*512 shorts
  int wr = (w >> 1) << 5, wc = (w & 1) << 6;
  int lr = lane & 15, kg = lane >> 4;
  int cs0 = ((kg)     ^ (lane & 7)) * 8;
  int cs1 = ((4 + kg) ^ (lane & 7)) * 8;
  f32x4 acc[2][4] = {};
#define STG(buf, kt)  do {                                                   \
    GLD16(Ab + (kt),                      &As[buf][ldst]);                   \
    GLD16(Ab + (kt) + (size_t)32 * K,     &As[buf][2048 + ldst]);            \
    GLD16(Bb + (kt),                      &Bs[buf][ldst]);                   \
    GLD16(Bb + (kt) + (size_t)32 * K,     &Bs[buf][2048 + ldst]);            \
    GLD16(Bb + (kt) + (size_t)64 * K,     &Bs[buf][4096 + ldst]);            \
    GLD16(Bb + (kt) + (size_t)96 * K,     &Bs[buf][6144 + ldst]); } while (0)
  STG(0, 0);
  __syncthreads();
  int nt = K >> 6;
  for (int t = 0; t < nt; t++) {
    int cur = t & 1;
    if (t + 1 < nt) STG(cur ^ 1, (t + 1) << 6);
    short8 a_[2][2], b_[4][2];
#pragma unroll
    for (int m = 0; m < 2; m++) {
      int rb = (wr + m * 16 + lr) * 64;
      a_[m][0] = *(const short8*)&As[cur][rb + cs0];
      a_[m][1] = *(const short8*)&As[cur][rb + cs1];
    }
#pragma unroll
    for (int n = 0; n < 4; n++) {
      int rb = (wc + n * 16 + lr) * 64;
      b_[n][0] = *(const short8*)&Bs[cur][rb + cs0];
      b_[n][1] = *(const short8*)&Bs[cur][rb + cs1];
    }
#pragma unroll
    for (int ks = 0; ks < 2; ks++)
#pragma unroll
      for (int m = 0; m < 2; m++)
#pragma unroll
        for (int n = 0; n < 4; n++)
          acc[m][n] = __builtin_amdgcn_mfma_f32_16x16x32_bf16(a_[m][ks], b_[n][ks], acc[m][n], 0, 0, 0);
    __syncthreads();
  }
#undef STG
  int r0 = bm + wr + kg * 4;
  int c0 = bn + wc + lr;
#pragma unroll
  for (int m = 0; m < 2; m++) {
#pragma unroll
    for (int n = 0; n < 4; n++) {
      int col = c0 + n * 16;
      float bv = bias ? bias[col] : 0.0f;
#pragma unroll
      for (int j = 0; j < 4; j++) {
        int row = r0 + m * 16 + j;
        float v = acc[m][n][j] + bv;
        if (act == 1) v = gelu_f(v);
        if (out_bf16) ((ushort*)C)[(size_t)row * N + col] = f2bf(v);
        else          ((float*)C)[(size_t)row * N + col] = v;
      }
    }
  }
}

// ---------------- bf16 MFMA GEMM, 32x64 tile, BK=64 (small-N, hi-occ) ------
// 4 waves, each 16x32 (acc[1][2]). LDS 24KB -> 6 blocks/CU; grid doubles vs
// 64x64: (N/64)*(M/32). Same chunk swizzles. For fc (K=512) and FFN2 (K=2048).
__global__ __launch_bounds__(256) void gemm_bf16_t32(
    const ushort* __restrict__ A, const ushort* __restrict__ Bt,
    const float* __restrict__ bias, ushort* __restrict__ C,
    int N, int K) {
  __shared__ short As[2][2048];   // 32 rows x 64 k
  __shared__ short Bs[2][4096];   // 64 rows x 64 k
  int nbx = N >> 6;
  int wgid = xcd_chunk(blockIdx.x, gridDim.x);
  int bx = wgid % nbx, by = wgid / nbx;
  int tid = threadIdx.x;
  int w = tid >> 6, lane = tid & 63;
  int bm = by << 5, bn = bx << 6;
  int gch = (tid & 7) ^ ((tid >> 3) & 7);
  const short* Ab = (const short*)A + (size_t)(bm + (tid >> 3)) * K + gch * 8;
  const short* Bb = (const short*)Bt + (size_t)(bn + (tid >> 3)) * K + gch * 8;
  int ldst = (tid & 192) * 8;          // wave-uniform: w*512 shorts
  int wr = (w >> 1) << 4, wc = (w & 1) << 5;
  int lr = lane & 15, kg = lane >> 4;
  int cs0 = ((kg)     ^ (lane & 7)) * 8;
  int cs1 = ((4 + kg) ^ (lane & 7)) * 8;
  f32x4 acc[2] = {};
#define STG32(buf, kt) do {                                                  \
    GLD16(Ab + (kt),                  &As[buf][ldst]);                       \
    GLD16(Bb + (kt),                  &Bs[buf][ldst]);                       \
    GLD16(Bb + (kt) + (size_t)32 * K, &Bs[buf][2048 + ldst]); } while (0)
  STG32(0, 0);
  __syncthreads();
  int nt = K >> 6;
  for (int t = 0; t < nt; t++) {
    int cur = t & 1;
    if (t + 1 < nt) STG32(cur ^ 1, (t + 1) << 6);
    short8 a_[2], b_[2][2];
    {
      int rb = (wr + lr) * 64;
      a_[0] = *(const short8*)&As[cur][rb + cs0];
      a_[1] = *(const short8*)&As[cur][rb + cs1];
    }
#pragma unroll
    for (int n = 0; n < 2; n++) {
      int rb = (wc + n * 16 + lr) * 64;
      b_[n][0] = *(const short8*)&Bs[cur][rb + cs0];
      b_[n][1] = *(const short8*)&Bs[cur][rb + cs1];
    }
#pragma unroll
    for (int ks = 0; ks < 2; ks++)
#pragma unroll
      for (int n = 0; n < 2; n++)
        acc[n] = __builtin_amdgcn_mfma_f32_16x16x32_bf16(a_[ks], b_[n][ks], acc[n], 0, 0, 0);
    __syncthreads();
  }
#undef STG32
  int r0 = bm + wr + kg * 4;
  int c0 = bn + wc + lr;
#pragma unroll
  for (int n = 0; n < 2; n++) {
    int col = c0 + n * 16;
    float bv = bias ? bias[col] : 0.0f;
#pragma unroll
    for (int j = 0; j < 4; j++) {
      int row = r0 + j;
      C[(size_t)row * N + col] = f2bf(acc[n][j] + bv);
    }
  }
}

// ---------------- down-projection GEMM: [4096][512] @ [512][64] ------------
__global__ __launch_bounds__(256) void down_gemm(
    const float* __restrict__ A, const float* __restrict__ B,
    const float* __restrict__ bias, float* __restrict__ C) {
  int wgid = xcd_chunk(blockIdx.x, gridDim.x);
  int r0 = wgid << 4;
  int tid = threadIdx.x;
  int col = tid & 63, rq = tid >> 6;
  __shared__ float As[16][32];
  __shared__ float Bs[32][64];
  float acc0 = 0, acc1 = 0, acc2 = 0, acc3 = 0;
  for (int kt = 0; kt < 512; kt += 32) {
    {
      int e = tid * 2;
      int ar = e >> 5, ak = e & 31;
      *(float2*)&As[ar][ak] = *(const float2*)&A[(size_t)(r0 + ar) * 512 + kt + ak];
    }
    {
      int e = tid * 8;
      int br = e >> 6, bc = e & 63;
      *(float4*)&Bs[br][bc]     = *(const float4*)&B[(size_t)(kt + br) * 64 + bc];
      *(float4*)&Bs[br][bc + 4] = *(const float4*)&B[(size_t)(kt + br) * 64 + bc + 4];
    }
    __syncthreads();
#pragma unroll
    for (int kk = 0; kk < 32; kk++) {
      float bv = Bs[kk][col];
      acc0 = fmaf(As[rq][kk],      bv, acc0);
      acc1 = fmaf(As[rq + 4][kk],  bv, acc1);
      acc2 = fmaf(As[rq + 8][kk],  bv, acc2);
      acc3 = fmaf(As[rq + 12][kk], bv, acc3);
    }
    __syncthreads();
  }
  float bv = bias[col];
  C[(size_t)(r0 + rq) * 64 + col]      = acc0 + bv;
  C[(size_t)(r0 + rq + 4) * 64 + col]  = acc1 + bv;
  C[(size_t)(r0 + rq + 8) * 64 + col]  = acc2 + bv;
  C[(size_t)(r0 + rq + 12) * 64 + col] = acc3 + bv;
}

// ---------------- small f32 GEMM (up projection) ---------------------------
__global__ __launch_bounds__(256) void gemm_f32(
    const float* __restrict__ A, const float* __restrict__ B,
    const float* __restrict__ bias, float* __restrict__ C,
    int M, int N, int K) {
  __shared__ float As[16][68];
  __shared__ float Bs[16][64];
  int tid = threadIdx.x;
  int tx = tid & 15, ty = tid >> 4;
  int bm = blockIdx.y << 6, bn = blockIdx.x << 6;
  const float* Ab = A + (size_t)bm * K;
  const float* Bb = B + bn;
  float acc[4][4] = {};
  for (int kt = 0; kt < K; kt += 16) {
#pragma unroll
    for (int r = 0; r < 4; r++) {
      int e2 = r * 256 + tid;
      As[e2 & 15][e2 >> 4] = Ab[(size_t)(e2 >> 4) * K + kt + (e2 & 15)];
    }
#pragma unroll
    for (int r = 0; r < 4; r++) {
      int e2 = r * 256 + tid;
      Bs[e2 >> 6][e2 & 63] = Bb[(size_t)(kt + (e2 >> 6)) * N + (e2 & 63)];
    }
    __syncthreads();
#pragma unroll
    for (int kk = 0; kk < 16; kk++) {
      float a0 = As[kk][(ty << 2) + 0], a1 = As[kk][(ty << 2) + 1];
      float a2 = As[kk][(ty << 2) + 2], a3 = As[kk][(ty << 2) + 3];
      float b0 = Bs[kk][(tx << 2) + 0], b1 = Bs[kk][(tx << 2) + 1];
      float b2 = Bs[kk][(tx << 2) + 2], b3 = Bs[kk][(tx << 2) + 3];
      acc[0][0] = fmaf(a0, b0, acc[0][0]); acc[0][1] = fmaf(a0, b1, acc[0][1]);
      acc[0][2] = fmaf(a0, b2, acc[0][2]); acc[0][3] = fmaf(a0, b3, acc[0][3]);
      acc[1][0] = fmaf(a1, b0, acc[1][0]); acc[1][1] = fmaf(a1, b1, acc[1][1]);
      acc[1][2] = fmaf(a1, b2, acc[1][2]); acc[1][3] = fmaf(a1, b3, acc[1][3]);
      acc[2][0] = fmaf(a2, b0, acc[2][0]); acc[2][1] = fmaf(a2, b1, acc[2][1]);
      acc[2][2] = fmaf(a2, b2, acc[2][2]); acc[2][3] = fmaf(a2, b3, acc[2][3]);
      acc[3][0] = fmaf(a3, b0, acc[3][0]); acc[3][1] = fmaf(a3, b1, acc[3][1]);
      acc[3][2] = fmaf(a3, b2, acc[3][2]); acc[3][3] = fmaf(a3, b3, acc[3][3]);
    }
    __syncthreads();
  }
#pragma unroll
  for (int i2 = 0; i2 < 4; i2++) {
    int row = bm + (ty << 2) + i2;
#pragma unroll
    for (int j2 = 0; j2 < 4; j2++) {
      int col = bn + (tx << 2) + j2;
      C[(size_t)row * N + col] = acc[i2][j2] + (bias ? bias[col] : 0.0f);
    }
  }
}

// ---------------- pyramid conv level ---------------------------------------
__global__ __launch_bounds__(64) void pyr_conv(
    const float* __restrict__ in, int in_base, int in_bstr,
    float* __restrict__ out, int out_base, int out_bstr, int out_len,
    const float* __restrict__ w, const float* __restrict__ bias,
    const float* __restrict__ bng, const float* __restrict__ bnb) {
  int blk = blockIdx.x;
  int b = blk / out_len, to = blk - b * out_len;
  int co = threadIdx.x;
  __shared__ float xin[4][64];
  const float* src = in + (size_t)(b * in_bstr + in_base + 4 * to) * 64;
#pragma unroll
  for (int r2 = 0; r2 < 4; r2++) xin[r2][co] = src[r2 * 64 + co];
  __syncthreads();
  const float* wr = w + (size_t)co * 256;
  float acc = bias[co];
#pragma unroll 16
  for (int ci = 0; ci < 64; ci++) {
    acc = fmaf(xin[0][ci], wr[ci * 4 + 0], acc);
    acc = fmaf(xin[1][ci], wr[ci * 4 + 1], acc);
    acc = fmaf(xin[2][ci], wr[ci * 4 + 2], acc);
    acc = fmaf(xin[3][ci], wr[ci * 4 + 3], acc);
  }
  float y = fmaf(bng[co], acc, bnb[co]);
  y = y > 0.0f ? y : expm1f(y);
  out[(size_t)(b * out_bstr + out_base + to) * 64 + co] = y;
}

// ---------------- LayerNorm concat, wave-per-row (no barriers) -------------
// Block = 256 thr = 4 waves, wave handles one row; lane owns 8 elems.
__global__ __launch_bounds__(256) void ln_concat(
    const float* __restrict__ e, const float* __restrict__ pyru,
    const float* __restrict__ g, const float* __restrict__ bta,
    float* __restrict__ seq, ushort* __restrict__ seq_bf) {
  int r = (blockIdx.x << 2) + (threadIdx.x >> 6);
  int lane = threadIdx.x & 63;
  int b = r / 1360, i = r - b * 1360;
  const float* src = (i < 1024)
      ? (e    + (size_t)(b * 1024 + i) * 512)
      : (pyru + (size_t)(b * 336 + (i - 1024)) * 512);
  int c = lane << 3;
  float4 v0 = *(const float4*)&src[c];
  float4 v1 = *(const float4*)&src[c + 4];
  float sum = v0.x + v0.y + v0.z + v0.w + v1.x + v1.y + v1.z + v1.w;
#pragma unroll
  for (int off = 1; off < 64; off <<= 1) sum += __shfl_xor(sum, off);
  float mu = sum * (1.0f / 512.0f);
  float d[8] = { v0.x - mu, v0.y - mu, v0.z - mu, v0.w - mu,
                 v1.x - mu, v1.y - mu, v1.z - mu, v1.w - mu };
  float sq = d[0]*d[0] + d[1]*d[1] + d[2]*d[2] + d[3]*d[3]
           + d[4]*d[4] + d[5]*d[5] + d[6]*d[6] + d[7]*d[7];
#pragma unroll
  for (int off = 1; off < 64; off <<= 1) sq += __shfl_xor(sq, off);
  float inv = rsqrtf(sq * (1.0f / 512.0f) + 1e-5f);
  float4 g0 = *(const float4*)&g[c],   g1 = *(const float4*)&g[c + 4];
  float4 b0 = *(const float4*)&bta[c], b1 = *(const float4*)&bta[c + 4];
  float o[8] = { d[0]*inv*g0.x + b0.x, d[1]*inv*g0.y + b0.y,
                 d[2]*inv*g0.z + b0.z, d[3]*inv*g0.w + b0.w,
                 d[4]*inv*g1.x + b1.x, d[5]*inv*g1.y + b1.y,
                 d[6]*inv*g1.z + b1.z, d[7]*inv*g1.w + b1.w };
  float* dst = seq + (size_t)r * 512 + c;
  *(float4*)&dst[0] = make_float4(o[0], o[1], o[2], o[3]);
  *(float4*)&dst[4] = make_float4(o[4], o[5], o[6], o[7]);
  uint4 pk;
  pk.x = pack2(o[0], o[1]); pk.y = pack2(o[2], o[3]);
  pk.z = pack2(o[4], o[5]); pk.w = pack2(o[6], o[7]);
  *(uint4*)(seq_bf + (size_t)r * 512 + c) = pk;
}

// ---------------- residual add + LayerNorm, wave-per-row (no barriers) -----
__global__ __launch_bounds__(256) void ln_add(
    float* __restrict__ seq, const ushort* __restrict__ t1,
    const float* __restrict__ g, const float* __restrict__ bta,
    ushort* __restrict__ seq_bf) {
  int r = (blockIdx.x << 2) + (threadIdx.x >> 6);
  int lane = threadIdx.x & 63;
  int c = lane << 3;
  float* row = seq + (size_t)r * 512 + c;
  float4 v0 = *(const float4*)&row[0];
  float4 v1 = *(const float4*)&row[4];
  uint4 tv = *(const uint4*)(t1 + (size_t)r * 512 + c);
  v0.x += lo16(tv.x); v0.y += hi16(tv.x);
  v0.z += lo16(tv.y); v0.w += hi16(tv.y);
  v1.x += lo16(tv.z); v1.y += hi16(tv.z);
  v1.z += lo16(tv.w); v1.w += hi16(tv.w);
  float sum = v0.x + v0.y + v0.z + v0.w + v1.x + v1.y + v1.z + v1.w;
#pragma unroll
  for (int off = 1; off < 64; off <<= 1) sum += __shfl_xor(sum, off);
  float mu = sum * (1.0f / 512.0f);
  float d[8] = { v0.x - mu, v0.y - mu, v0.z - mu, v0.w - mu,
                 v1.x - mu, v1.y - mu, v1.z - mu, v1.w - mu };
  float sq = d[0]*d[0] + d[1]*d[1] + d[2]*d[2] + d[3]*d[3]
           + d[4]*d[4] + d[5]*d[5] + d[6]*d[6] + d[7]*d[7];
#pragma unroll
  for (int off = 1; off < 64; off <<= 1) sq += __shfl_xor(sq, off);
  float inv = rsqrtf(sq * (1.0f / 512.0f) + 1e-5f);
  float4 g0 = *(const float4*)&g[c],   g1 = *(const float4*)&g[c + 4];
  float4 b0 = *(const float4*)&bta[c], b1 = *(const float4*)&bta[c + 4];
  float o[8] = { d[0]*inv*g0.x + b0.x, d[1]*inv*g0.y + b0.y,
                 d[2]*inv*g0.z + b0.z, d[3]*inv*g0.w + b0.w,
                 d[4]*inv*g1.x + b1.x, d[5]*inv*g1.y + b1.y,
                 d[6]*inv*g1.z + b1.z, d[7]*inv*g1.w + b1.w };
  *(float4*)&row[0] = make_float4(o[0], o[1], o[2], o[3]);
  *(float4*)&row[4] = make_float4(o[4], o[5], o[6], o[7]);
  uint4 pk;
  pk.x = pack2(o[0], o[1]); pk.y = pack2(o[2], o[3]);
  pk.z = pack2(o[4], o[5]); pk.w = pack2(o[6], o[7]);
  *(uint4*)(seq_bf + (size_t)r * 512 + c) = pk;
}

// ---------------- sparse pyramidal attention (wave-per-head, no LDS) -------
__global__ __launch_bounds__(512) void attn_sparse(
    const ushort* __restrict__ qkv, ushort* __restrict__ o) {
  int r = blockIdx.x;
  int b = r / 1360, i = r - b * 1360;
  int h = threadIdx.x >> 6, lane = threadIdx.x & 63;
  int S, sz, li;
  if (i < 1024)      { li = 0; S = 0;    sz = 1024; }
  else if (i < 1280) { li = 1; S = 1024; sz = 256; }
  else if (i < 1344) { li = 2; S = 1280; sz = 64; }
  else               { li = 3; S = 1344; sz = 16; }
  int p = i - S;
  int lo = p - 2; if (lo < 0) lo = 0;
  int hi = p + 2; if (hi > sz - 1) hi = sz - 1;
  int cnt = hi - lo + 1;
  int nk = cnt + (li > 0 ? 4 : 0) + (li < 3 ? 1 : 0);
  int Sprev = (li == 1) ? 0 : (li == 2) ? 1024 : 1280;
  int Snext = (li == 0) ? 1024 : (li == 1) ? 1280 : 1344;
  int j2 = lane >> 2, c = lane & 3;
  int key;
  if (j2 < cnt)                      key = S + lo + j2;
  else if (li > 0 && j2 - cnt < 4)   key = Sprev + 4 * p + (j2 - cnt);
  else if (li < 3)                   key = Snext + (p >> 2);
  else                               key = S + p;
  float partial = 0.0f;
  {
    const uint4* qv = (const uint4*)(qkv + (size_t)r * 1536 + h * 64 + c * 16);
    const uint4* kv = (const uint4*)(qkv + (size_t)(b * 1360 + key) * 1536 + 512 + h * 64 + c * 16);
#pragma unroll
    for (int cc = 0; cc < 2; cc++) {
      uint4 a = qv[cc], k4 = kv[cc];
      partial = fmaf(lo16(a.x), lo16(k4.x), partial); partial = fmaf(hi16(a.x), hi16(k4.x), partial);
      partial = fmaf(lo16(a.y), lo16(k4.y), partial); partial = fmaf(hi16(a.y), hi16(k4.y), partial);
      partial = fmaf(lo16(a.z), lo16(k4.z), partial); partial = fmaf(hi16(a.z), hi16(k4.z), partial);
      partial = fmaf(lo16(a.w), lo16(k4.w), partial); partial = fmaf(hi16(a.w), hi16(k4.w), partial);
    }
  }
  partial += __shfl_xor(partial, 1);
  partial += __shfl_xor(partial, 2);
  float s = partial * 0.125f;
  float m = -1e30f;
  for (int j = 0; j < nk; j++) m = fmaxf(m, __shfl(s, 4 * j));
  float denom = 0.0f;
  for (int j = 0; j < nk; j++) denom += __expf(__shfl(s, 4 * j) - m);
  float inv = 1.0f / denom;
  float acc = 0.0f;
  for (int j = 0; j < nk; j++) {
    float pj = __expf(__shfl(s, 4 * j) - m) * inv;
    int kj = __shfl(key, 4 * j);
    float vv = bf2f(qkv[(size_t)(b * 1360 + kj) * 1536 + 1024 + h * 64 + lane]);
    acc = fmaf(pj, vv, acc);
  }
  o[(size_t)r * 512 + h * 64 + lane] = f2bf(acc);
}

// ---------------- output gather --------------------------------------------
__global__ __launch_bounds__(512) void gather_out(
    const float* __restrict__ seq, float* __restrict__ out) {
  int bl = blockIdx.x;
  int b = bl >> 10, i = bl & 1023;
  int d = threadIdx.x;
  size_t ob = (size_t)bl * 2048 + d;
  size_t base = (size_t)b * 1360;
  out[ob]        = seq[(base + i) * 512 + d];
  out[ob + 512]  = seq[(base + 1024 + (i >> 2)) * 512 + d];
  out[ob + 1024] = seq[(base + 1280 + (i >> 4)) * 512 + d];
  out[ob + 1536] = seq[(base + 1344 + (i >> 6)) * 512 + d];
}

// ---------------------------------------------------------------------------
extern "C" void kernel_launch(void* const* d_in, const int* in_sizes, int n_in,
                              void* d_out, int out_size, void* d_ws, size_t ws_size,
                              hipStream_t stream) {
  const float* x_enc   = (const float*)d_in[0];
  const float* x_mark  = (const float*)d_in[1];
  const float* conv_w  = (const float*)d_in[2];
  const float* conv_b  = (const float*)d_in[3];
  const float* temp_w  = (const float*)d_in[4];
  const float* temp_b  = (const float*)d_in[5];
  const float* down_w  = (const float*)d_in[6];
  const float* down_b  = (const float*)d_in[7];
  const float* pyr_w   = (const float*)d_in[8];
  const float* pyr_b   = (const float*)d_in[9];
  const float* bn_g    = (const float*)d_in[10];
  const float* bn_b    = (const float*)d_in[11];
  const float* up_w    = (const float*)d_in[12];
  const float* up_b    = (const float*)d_in[13];
  const float* norm_g  = (const float*)d_in[14];
  const float* norm_b  = (const float*)d_in[15];
  const float* wq      = (const float*)d_in[16];
  const float* wk      = (const float*)d_in[17];
  const float* wv      = (const float*)d_in[18];
  const float* fc_w    = (const float*)d_in[19];
  const float* fc_b    = (const float*)d_in[20];
  const float* ln1_g   = (const float*)d_in[21];
  const float* ln1_b   = (const float*)d_in[22];
  const float* w1      = (const float*)d_in[23];
  const float* b1      = (const float*)d_in[24];
  const float* w2      = (const float*)d_in[25];
  const float* b2      = (const float*)d_in[26];
  const float* ln2_g   = (const float*)d_in[27];
  const float* ln2_b   = (const float*)d_in[28];

  // ---- workspace layout (f32-word offsets); total 18,972,672 words = 72.4MB
  float* ws = (float*)d_ws;
  float*  e      = ws;                         // 2,097,152 w
  float*  tmp0   = ws + 2097152;               //   262,144 w
  float*  pyrf   = ws + 2359296;               //    86,016 w
  float*  pyru   = ws + 2445312;               //   688,128 w
  ushort* qkv_bf = (ushort*)ws;                // [5504][1536] bf16
  ushort* o_bf   = (ushort*)(ws + 4227072);    // [5504][512] bf16
  ushort* th_bf  = (ushort*)ws;                // [5504][2048] bf16
  ushort* t1     = (ushort*)(ws + 5636096);    // [5504][512] bf16
  float*  seq    = ws + 8454144;               // [5504][512] f32
  ushort* seq_bf = (ushort*)(ws + 11272192);   // [5504][512] bf16
  ushort* qkvw   = (ushort*)(ws + 12681216);   // 4 x [1536][512] bf16
  ushort* fcw    = (ushort*)(ws + 14254080);   // 4 x [512][512] bf16
  ushort* w1t    = (ushort*)(ws + 14778368);   // 4 x [2048][512] bf16
  ushort* w2t    = (ushort*)(ws + 16875520);   // 4 x [512][2048] bf16

  // ---- weight cast+transpose (once per call) ----
  dim3 tb(32, 8);
  transpose_cast<<<dim3(16, 16, 4), tb, 0, stream>>>(wq, qkvw,          512, 512,  262144, 786432);
  transpose_cast<<<dim3(16, 16, 4), tb, 0, stream>>>(wk, qkvw + 262144, 512, 512,  262144, 786432);
  transpose_cast<<<dim3(16, 16, 4), tb, 0, stream>>>(wv, qkvw + 524288, 512, 512,  262144, 786432);
  transpose_cast<<<dim3(16, 16, 4), tb, 0, stream>>>(fc_w, fcw,         512, 512,  262144, 262144);
  transpose_cast<<<dim3(64, 16, 4), tb, 0, stream>>>(w1, w1t,           512, 2048, 1048576, 1048576);
  transpose_cast<<<dim3(16, 64, 4), tb, 0, stream>>>(w2, w2t,           2048, 512, 1048576, 1048576);

  // ---- prologue ----
  embed_kernel<<<4096, 512, 0, stream>>>(x_enc, x_mark, conv_w, conv_b,
                                         temp_w, temp_b, e);
  down_gemm<<<256, 256, 0, stream>>>(e, down_w, down_b, tmp0);
  pyr_conv<<<4 * 256, 64, 0, stream>>>(tmp0, 0, 1024, pyrf, 0, 336, 256,
                                       pyr_w, pyr_b, bn_g, bn_b);
  pyr_conv<<<4 * 64, 64, 0, stream>>>(pyrf, 0, 336, pyrf, 256, 336, 64,
                                      pyr_w + 16384, pyr_b + 64, bn_g + 64, bn_b + 64);
  pyr_conv<<<4 * 16, 64, 0, stream>>>(pyrf, 256, 336, pyrf, 320, 336, 16,
                                      pyr_w + 32768, pyr_b + 128, bn_g + 128, bn_b + 128);
  gemm_f32<<<dim3(8, 21), 256, 0, stream>>>(pyrf, up_w, up_b, pyru, 1344, 512, 64);
  ln_concat<<<1360, 256, 0, stream>>>(e, pyru, norm_g, norm_b, seq, seq_bf);

  // ---- layers ----
  for (int l = 0; l < 4; l++) {
    gemm_bf16<<<12 * 86, 256, 0, stream>>>(seq_bf, qkvw + (size_t)l * 786432,
                                           nullptr, qkv_bf, 1536, 512, 0, 1);
    attn_sparse<<<5440, 512, 0, stream>>>(qkv_bf, o_bf);
    gemm_bf16_t32<<<8 * 172, 256, 0, stream>>>(o_bf, fcw + (size_t)l * 262144,
                                               fc_b + l * 512, t1, 512, 512);
    ln_add<<<1360, 256, 0, stream>>>(seq, t1, ln1_g + l * 512, ln1_b + l * 512, seq_bf);
    gemm_bf16<<<16 * 86, 256, 0, stream>>>(seq_bf, w1t + (size_t)l * 1048576,
                                           b1 + l * 2048, th_bf, 2048, 512, 1, 1);
    gemm_bf16_t32<<<8 * 172, 256, 0, stream>>>(th_bf, w2t + (size_t)l * 1048576,
                                               b2 + l * 512, t1, 512, 2048);
    ln_add<<<1360, 256, 0, stream>>>(seq, t1, ln2_g + l * 512, ln2_b + l * 512, seq_bf);
  }
  gather_out<<<4096, 512, 0, stream>>>(seq, (float*)d_out);
}

// Round 10
// 566.921 us; speedup vs baseline: 1.3035x; 1.0746x over previous
//
#include <hip/hip_runtime.h>
#include <hip/hip_bf16.h>
#include <math.h>

// ---------------------------------------------------------------------------
// B=4, L_IN=1024, D=512, H=8, DK=64, DFF=2048, NL=4, WINDOW=[4,4,4], INNER=5.
// all_size=[1024,256,64,16], L_tot=1360, rows M=5440 padded to M_PAD=5504.
// ---------------------------------------------------------------------------

typedef __attribute__((ext_vector_type(8))) short short8;
typedef __attribute__((ext_vector_type(4))) float f32x4;

__device__ inline ushort f2bf(float x) {
  union { __hip_bfloat16 h; ushort u; } cv; cv.h = __float2bfloat16(x); return cv.u;
}
__device__ inline float bf2f(ushort u) {
  union { unsigned int i; float f; } cv; cv.i = (unsigned)u << 16; return cv.f;
}
__device__ inline float lo16(unsigned u) { union { unsigned i; float f; } c; c.i = u << 16; return c.f; }
__device__ inline float hi16(unsigned u) { union { unsigned i; float f; } c; c.i = u & 0xffff0000u; return c.f; }
__device__ inline unsigned pack2(float a, float b) {
  return (unsigned)f2bf(a) | ((unsigned)f2bf(b) << 16);
}

// tanh-form GELU (max |err| vs exact erf-GELU ~3e-3; well within budget)
__device__ inline float gelu_f(float x) {
  float y = 0.7978845608028654f * (x + 0.044715f * x * x * x);
  float t = __expf(-2.0f * y);
  float th = (1.0f - t) / (1.0f + t);
  return 0.5f * x * (1.0f + th);
}

// bijective XCD-chunk swizzle (m204): round-robin id -> contiguous chunk/XCD
__device__ inline int xcd_chunk(int orig, int nwg) {
  int q = nwg >> 3, r = nwg & 7;
  int xcd = orig & 7, idx = orig >> 3;
  int base = (xcd < r) ? xcd * (q + 1) : r * (q + 1) + (xcd - r) * q;
  return base + idx;
}

#define GLD16(gp, lp)                                                        \
  __builtin_amdgcn_global_load_lds(                                          \
      (const __attribute__((address_space(1))) void*)(gp),                   \
      (__attribute__((address_space(3))) void*)(lp), 16, 0, 0)

// ---------------- embed: circular conv3 + posenc + mark projection ---------
__global__ __launch_bounds__(512) void embed_kernel(
    const float* __restrict__ x_enc, const float* __restrict__ x_mark,
    const float* __restrict__ conv_w, const float* __restrict__ conv_b,
    const float* __restrict__ temp_w, const float* __restrict__ temp_b,
    float* __restrict__ e) {
  int bl = blockIdx.x;
  int b = bl >> 10, l = bl & 1023;
  int d = threadIdx.x;
  int lm1 = (l + 1023) & 1023;
  int lp1 = (l + 1) & 1023;
  const float* w  = conv_w + d * 21;
  const float* x0 = x_enc + (size_t)(b * 1024 + lm1) * 7;
  const float* x1 = x_enc + (size_t)(b * 1024 + l)   * 7;
  const float* x2 = x_enc + (size_t)(b * 1024 + lp1) * 7;
  float acc = conv_b[d];
#pragma unroll
  for (int ci = 0; ci < 7; ci++) {
    acc = fmaf(x0[ci], w[ci * 3 + 0], acc);
    acc = fmaf(x1[ci], w[ci * 3 + 1], acc);
    acc = fmaf(x2[ci], w[ci * 3 + 2], acc);
  }
  int j = d >> 1;
  float dv = expf((float)(2 * j) * (-9.210340371976184f / 512.0f));
  float ang = (float)l * dv;
  float pe = (d & 1) ? cosf(ang) : sinf(ang);
  const float* xm = x_mark + (size_t)(b * 1024 + l) * 4;
  float mk = temp_b[d];
  mk = fmaf(xm[0], temp_w[d],        mk);
  mk = fmaf(xm[1], temp_w[512 + d],  mk);
  mk = fmaf(xm[2], temp_w[1024 + d], mk);
  mk = fmaf(xm[3], temp_w[1536 + d], mk);
  e[(size_t)bl * 512 + d] = acc + pe + mk;
}

// ---------------- weight cast+transpose: f32 [K][N] -> bf16 [N][K] ---------
__global__ __launch_bounds__(256) void transpose_cast(
    const float* __restrict__ src, ushort* __restrict__ dst,
    int K, int N, size_t src_lstride, size_t dst_lstride) {
  src += (size_t)blockIdx.z * src_lstride;
  dst += (size_t)blockIdx.z * dst_lstride;
  __shared__ float t[32][33];
  int k0 = blockIdx.y * 32, n0 = blockIdx.x * 32;
  int tx = threadIdx.x, ty = threadIdx.y;  // (32,8)
#pragma unroll
  for (int i = 0; i < 4; i++)
    t[ty + i * 8][tx] = src[(size_t)(k0 + ty + i * 8) * N + n0 + tx];
  __syncthreads();
#pragma unroll
  for (int i = 0; i < 4; i++)
    dst[(size_t)(n0 + ty + i * 8) * K + k0 + tx] = f2bf(t[tx][ty + i * 8]);
}

// ---------------- bf16 MFMA GEMM, 64x64 tile, BK=64, dbuf + swizzles -------
// A: [M_pad][K] bf16.  Bt: [N][K] bf16 (pre-transposed).  act 1 = GELU.
// 32KB LDS -> 5 blocks/CU. Chunk XOR-swizzle by row&7 (pre-swizzled global
// source + swizzled ds_read). XCD-chunk 1D grid (N/64)*(M/64).
__global__ __launch_bounds__(256) void gemm_bf16_t64(
    const ushort* __restrict__ A, const ushort* __restrict__ Bt,
    const float* __restrict__ bias, ushort* __restrict__ C,
    int N, int K, int act) {
  __shared__ short As[2][4096];   // 64 rows x 64 k
  __shared__ short Bs[2][4096];
  int nbx = N >> 6;
  int wgid = xcd_chunk(blockIdx.x, gridDim.x);
  int bx = wgid % nbx, by = wgid / nbx;
  int tid = threadIdx.x;
  int w = tid >> 6, lane = tid & 63;
  int bm = by << 6, bn = bx << 6;
  int gch = (tid & 7) ^ ((tid >> 3) & 7);
  const short* Ab = (const short*)A + (size_t)(bm + (tid >> 3)) * K + gch * 8;
  const short* Bb = (const short*)Bt + (size_t)(bn + (tid >> 3)) * K + gch * 8;
  int ldst = (tid & 192) * 8;          // wave-uniform base (shorts)
  int wr = (w >> 1) << 5, wc = (w & 1) << 5;
  int lr = lane & 15, kg = lane >> 4;
  int cs0 = ((kg)     ^ (lane & 7)) * 8;
  int cs1 = ((4 + kg) ^ (lane & 7)) * 8;
  f32x4 acc[2][2] = {};
#define STG64(buf, kt) do {                                                  \
    GLD16(Ab + (kt),                  &As[buf][ldst]);                       \
    GLD16(Ab + (kt) + (size_t)32 * K, &As[buf][2048 + ldst]);                \
    GLD16(Bb + (kt),                  &Bs[buf][ldst]);                       \
    GLD16(Bb + (kt) + (size_t)32 * K, &Bs[buf][2048 + ldst]); } while (0)
  STG64(0, 0);
  __syncthreads();
  int nt = K >> 6;
  for (int t = 0; t < nt; t++) {
    int cur = t & 1;
    if (t + 1 < nt) STG64(cur ^ 1, (t + 1) << 6);
    short8 a_[2][2], b_[2][2];
#pragma unroll
    for (int m = 0; m < 2; m++) {
      int rb = (wr + m * 16 + lr) * 64;
      a_[m][0] = *(const short8*)&As[cur][rb + cs0];
      a_[m][1] = *(const short8*)&As[cur][rb + cs1];
    }
#pragma unroll
    for (int n = 0; n < 2; n++) {
      int rb = (wc + n * 16 + lr) * 64;
      b_[n][0] = *(const short8*)&Bs[cur][rb + cs0];
      b_[n][1] = *(const short8*)&Bs[cur][rb + cs1];
    }
#pragma unroll
    for (int ks = 0; ks < 2; ks++)
#pragma unroll
      for (int m = 0; m < 2; m++)
#pragma unroll
        for (int n = 0; n < 2; n++)
          acc[m][n] = __builtin_amdgcn_mfma_f32_16x16x32_bf16(a_[m][ks], b_[n][ks], acc[m][n], 0, 0, 0);
    __syncthreads();
  }
#undef STG64
  int r0 = bm + wr + kg * 4;
  int c0 = bn + wc + lr;
#pragma unroll
  for (int m = 0; m < 2; m++) {
#pragma unroll
    for (int n = 0; n < 2; n++) {
      int col = c0 + n * 16;
      float bv = bias ? bias[col] : 0.0f;
#pragma unroll
      for (int j = 0; j < 4; j++) {
        int row = r0 + m * 16 + j;
        float v = acc[m][n][j] + bv;
        if (act == 1) v = gelu_f(v);
        C[(size_t)row * N + col] = f2bf(v);
      }
    }
  }
}

// ---------------- bf16 MFMA GEMM, 32x64 tile, BK=64 (small-N, hi-occ) ------
__global__ __launch_bounds__(256) void gemm_bf16_t32(
    const ushort* __restrict__ A, const ushort* __restrict__ Bt,
    const float* __restrict__ bias, ushort* __restrict__ C,
    int N, int K) {
  __shared__ short As[2][2048];   // 32 rows x 64 k
  __shared__ short Bs[2][4096];   // 64 rows x 64 k
  int nbx = N >> 6;
  int wgid = xcd_chunk(blockIdx.x, gridDim.x);
  int bx = wgid % nbx, by = wgid / nbx;
  int tid = threadIdx.x;
  int w = tid >> 6, lane = tid & 63;
  int bm = by << 5, bn = bx << 6;
  int gch = (tid & 7) ^ ((tid >> 3) & 7);
  const short* Ab = (const short*)A + (size_t)(bm + (tid >> 3)) * K + gch * 8;
  const short* Bb = (const short*)Bt + (size_t)(bn + (tid >> 3)) * K + gch * 8;
  int ldst = (tid & 192) * 8;          // wave-uniform: w*512 shorts
  int wr = (w >> 1) << 4, wc = (w & 1) << 5;
  int lr = lane & 15, kg = lane >> 4;
  int cs0 = ((kg)     ^ (lane & 7)) * 8;
  int cs1 = ((4 + kg) ^ (lane & 7)) * 8;
  f32x4 acc[2] = {};
#define STG32(buf, kt) do {                                                  \
    GLD16(Ab + (kt),                  &As[buf][ldst]);                       \
    GLD16(Bb + (kt),                  &Bs[buf][ldst]);                       \
    GLD16(Bb + (kt) + (size_t)32 * K, &Bs[buf][2048 + ldst]); } while (0)
  STG32(0, 0);
  __syncthreads();
  int nt = K >> 6;
  for (int t = 0; t < nt; t++) {
    int cur = t & 1;
    if (t + 1 < nt) STG32(cur ^ 1, (t + 1) << 6);
    short8 a_[2], b_[2][2];
    {
      int rb = (wr + lr) * 64;
      a_[0] = *(const short8*)&As[cur][rb + cs0];
      a_[1] = *(const short8*)&As[cur][rb + cs1];
    }
#pragma unroll
    for (int n = 0; n < 2; n++) {
      int rb = (wc + n * 16 + lr) * 64;
      b_[n][0] = *(const short8*)&Bs[cur][rb + cs0];
      b_[n][1] = *(const short8*)&Bs[cur][rb + cs1];
    }
#pragma unroll
    for (int ks = 0; ks < 2; ks++)
#pragma unroll
      for (int n = 0; n < 2; n++)
        acc[n] = __builtin_amdgcn_mfma_f32_16x16x32_bf16(a_[ks], b_[n][ks], acc[n], 0, 0, 0);
    __syncthreads();
  }
#undef STG32
  int r0 = bm + wr + kg * 4;
  int c0 = bn + wc + lr;
#pragma unroll
  for (int n = 0; n < 2; n++) {
    int col = c0 + n * 16;
    float bv = bias ? bias[col] : 0.0f;
#pragma unroll
    for (int j = 0; j < 4; j++) {
      int row = r0 + j;
      C[(size_t)row * N + col] = f2bf(acc[n][j] + bv);
    }
  }
}

// ---------------- down-projection GEMM: [4096][512] @ [512][64] ------------
__global__ __launch_bounds__(256) void down_gemm(
    const float* __restrict__ A, const float* __restrict__ B,
    const float* __restrict__ bias, float* __restrict__ C) {
  int wgid = xcd_chunk(blockIdx.x, gridDim.x);
  int r0 = wgid << 4;
  int tid = threadIdx.x;
  int col = tid & 63, rq = tid >> 6;
  __shared__ float As[16][32];
  __shared__ float Bs[32][64];
  float acc0 = 0, acc1 = 0, acc2 = 0, acc3 = 0;
  for (int kt = 0; kt < 512; kt += 32) {
    {
      int e = tid * 2;
      int ar = e >> 5, ak = e & 31;
      *(float2*)&As[ar][ak] = *(const float2*)&A[(size_t)(r0 + ar) * 512 + kt + ak];
    }
    {
      int e = tid * 8;
      int br = e >> 6, bc = e & 63;
      *(float4*)&Bs[br][bc]     = *(const float4*)&B[(size_t)(kt + br) * 64 + bc];
      *(float4*)&Bs[br][bc + 4] = *(const float4*)&B[(size_t)(kt + br) * 64 + bc + 4];
    }
    __syncthreads();
#pragma unroll
    for (int kk = 0; kk < 32; kk++) {
      float bv = Bs[kk][col];
      acc0 = fmaf(As[rq][kk],      bv, acc0);
      acc1 = fmaf(As[rq + 4][kk],  bv, acc1);
      acc2 = fmaf(As[rq + 8][kk],  bv, acc2);
      acc3 = fmaf(As[rq + 12][kk], bv, acc3);
    }
    __syncthreads();
  }
  float bv = bias[col];
  C[(size_t)(r0 + rq) * 64 + col]      = acc0 + bv;
  C[(size_t)(r0 + rq + 4) * 64 + col]  = acc1 + bv;
  C[(size_t)(r0 + rq + 8) * 64 + col]  = acc2 + bv;
  C[(size_t)(r0 + rq + 12) * 64 + col] = acc3 + bv;
}

// ---------------- small f32 GEMM (up projection) ---------------------------
__global__ __launch_bounds__(256) void gemm_f32(
    const float* __restrict__ A, const float* __restrict__ B,
    const float* __restrict__ bias, float* __restrict__ C,
    int M, int N, int K) {
  __shared__ float As[16][68];
  __shared__ float Bs[16][64];
  int tid = threadIdx.x;
  int tx = tid & 15, ty = tid >> 4;
  int bm = blockIdx.y << 6, bn = blockIdx.x << 6;
  const float* Ab = A + (size_t)bm * K;
  const float* Bb = B + bn;
  float acc[4][4] = {};
  for (int kt = 0; kt < K; kt += 16) {
#pragma unroll
    for (int r = 0; r < 4; r++) {
      int e2 = r * 256 + tid;
      As[e2 & 15][e2 >> 4] = Ab[(size_t)(e2 >> 4) * K + kt + (e2 & 15)];
    }
#pragma unroll
    for (int r = 0; r < 4; r++) {
      int e2 = r * 256 + tid;
      Bs[e2 >> 6][e2 & 63] = Bb[(size_t)(kt + (e2 >> 6)) * N + (e2 & 63)];
    }
    __syncthreads();
#pragma unroll
    for (int kk = 0; kk < 16; kk++) {
      float a0 = As[kk][(ty << 2) + 0], a1 = As[kk][(ty << 2) + 1];
      float a2 = As[kk][(ty << 2) + 2], a3 = As[kk][(ty << 2) + 3];
      float b0 = Bs[kk][(tx << 2) + 0], b1 = Bs[kk][(tx << 2) + 1];
      float b2 = Bs[kk][(tx << 2) + 2], b3 = Bs[kk][(tx << 2) + 3];
      acc[0][0] = fmaf(a0, b0, acc[0][0]); acc[0][1] = fmaf(a0, b1, acc[0][1]);
      acc[0][2] = fmaf(a0, b2, acc[0][2]); acc[0][3] = fmaf(a0, b3, acc[0][3]);
      acc[1][0] = fmaf(a1, b0, acc[1][0]); acc[1][1] = fmaf(a1, b1, acc[1][1]);
      acc[1][2] = fmaf(a1, b2, acc[1][2]); acc[1][3] = fmaf(a1, b3, acc[1][3]);
      acc[2][0] = fmaf(a2, b0, acc[2][0]); acc[2][1] = fmaf(a2, b1, acc[2][1]);
      acc[2][2] = fmaf(a2, b2, acc[2][2]); acc[2][3] = fmaf(a2, b3, acc[2][3]);
      acc[3][0] = fmaf(a3, b0, acc[3][0]); acc[3][1] = fmaf(a3, b1, acc[3][1]);
      acc[3][2] = fmaf(a3, b2, acc[3][2]); acc[3][3] = fmaf(a3, b3, acc[3][3]);
    }
    __syncthreads();
  }
#pragma unroll
  for (int i2 = 0; i2 < 4; i2++) {
    int row = bm + (ty << 2) + i2;
#pragma unroll
    for (int j2 = 0; j2 < 4; j2++) {
      int col = bn + (tx << 2) + j2;
      C[(size_t)row * N + col] = acc[i2][j2] + (bias ? bias[col] : 0.0f);
    }
  }
}

// ---------------- pyramid conv level ---------------------------------------
__global__ __launch_bounds__(64) void pyr_conv(
    const float* __restrict__ in, int in_base, int in_bstr,
    float* __restrict__ out, int out_base, int out_bstr, int out_len,
    const float* __restrict__ w, const float* __restrict__ bias,
    const float* __restrict__ bng, const float* __restrict__ bnb) {
  int blk = blockIdx.x;
  int b = blk / out_len, to = blk - b * out_len;
  int co = threadIdx.x;
  __shared__ float xin[4][64];
  const float* src = in + (size_t)(b * in_bstr + in_base + 4 * to) * 64;
#pragma unroll
  for (int r2 = 0; r2 < 4; r2++) xin[r2][co] = src[r2 * 64 + co];
  __syncthreads();
  const float* wr = w + (size_t)co * 256;
  float acc = bias[co];
#pragma unroll 16
  for (int ci = 0; ci < 64; ci++) {
    acc = fmaf(xin[0][ci], wr[ci * 4 + 0], acc);
    acc = fmaf(xin[1][ci], wr[ci * 4 + 1], acc);
    acc = fmaf(xin[2][ci], wr[ci * 4 + 2], acc);
    acc = fmaf(xin[3][ci], wr[ci * 4 + 3], acc);
  }
  float y = fmaf(bng[co], acc, bnb[co]);
  y = y > 0.0f ? y : expm1f(y);
  out[(size_t)(b * out_bstr + out_base + to) * 64 + co] = y;
}

// ---------------- LayerNorm concat, wave-per-row -> bf16 stream ------------
__global__ __launch_bounds__(256) void ln_concat(
    const float* __restrict__ e, const float* __restrict__ pyru,
    const float* __restrict__ g, const float* __restrict__ bta,
    ushort* __restrict__ seq_bf) {
  int r = (blockIdx.x << 2) + (threadIdx.x >> 6);
  int lane = threadIdx.x & 63;
  int b = r / 1360, i = r - b * 1360;
  const float* src = (i < 1024)
      ? (e    + (size_t)(b * 1024 + i) * 512)
      : (pyru + (size_t)(b * 336 + (i - 1024)) * 512);
  int c = lane << 3;
  float4 v0 = *(const float4*)&src[c];
  float4 v1 = *(const float4*)&src[c + 4];
  float sum = v0.x + v0.y + v0.z + v0.w + v1.x + v1.y + v1.z + v1.w;
#pragma unroll
  for (int off = 1; off < 64; off <<= 1) sum += __shfl_xor(sum, off);
  float mu = sum * (1.0f / 512.0f);
  float d[8] = { v0.x - mu, v0.y - mu, v0.z - mu, v0.w - mu,
                 v1.x - mu, v1.y - mu, v1.z - mu, v1.w - mu };
  float sq = d[0]*d[0] + d[1]*d[1] + d[2]*d[2] + d[3]*d[3]
           + d[4]*d[4] + d[5]*d[5] + d[6]*d[6] + d[7]*d[7];
#pragma unroll
  for (int off = 1; off < 64; off <<= 1) sq += __shfl_xor(sq, off);
  float inv = rsqrtf(sq * (1.0f / 512.0f) + 1e-5f);
  float4 g0 = *(const float4*)&g[c],   g1 = *(const float4*)&g[c + 4];
  float4 b0 = *(const float4*)&bta[c], b1 = *(const float4*)&bta[c + 4];
  uint4 pk;
  pk.x = pack2(d[0]*inv*g0.x + b0.x, d[1]*inv*g0.y + b0.y);
  pk.y = pack2(d[2]*inv*g0.z + b0.z, d[3]*inv*g0.w + b0.w);
  pk.z = pack2(d[4]*inv*g1.x + b1.x, d[5]*inv*g1.y + b1.y);
  pk.w = pack2(d[6]*inv*g1.z + b1.z, d[7]*inv*g1.w + b1.w);
  *(uint4*)(seq_bf + (size_t)r * 512 + c) = pk;
}

// ---------------- residual add + LayerNorm on bf16 stream ------------------
__global__ __launch_bounds__(256) void ln_add(
    ushort* __restrict__ seq_bf, const ushort* __restrict__ t1,
    const float* __restrict__ g, const float* __restrict__ bta) {
  int r = (blockIdx.x << 2) + (threadIdx.x >> 6);
  int lane = threadIdx.x & 63;
  int c = lane << 3;
  ushort* row = seq_bf + (size_t)r * 512 + c;
  uint4 sv = *(const uint4*)row;
  uint4 tv = *(const uint4*)(t1 + (size_t)r * 512 + c);
  float v[8] = {
    lo16(sv.x) + lo16(tv.x), hi16(sv.x) + hi16(tv.x),
    lo16(sv.y) + lo16(tv.y), hi16(sv.y) + hi16(tv.y),
    lo16(sv.z) + lo16(tv.z), hi16(sv.z) + hi16(tv.z),
    lo16(sv.w) + lo16(tv.w), hi16(sv.w) + hi16(tv.w) };
  float sum = v[0]+v[1]+v[2]+v[3]+v[4]+v[5]+v[6]+v[7];
#pragma unroll
  for (int off = 1; off < 64; off <<= 1) sum += __shfl_xor(sum, off);
  float mu = sum * (1.0f / 512.0f);
  float sq = 0.0f;
#pragma unroll
  for (int k = 0; k < 8; k++) { v[k] -= mu; sq += v[k] * v[k]; }
#pragma unroll
  for (int off = 1; off < 64; off <<= 1) sq += __shfl_xor(sq, off);
  float inv = rsqrtf(sq * (1.0f / 512.0f) + 1e-5f);
  float4 g0 = *(const float4*)&g[c],   g1 = *(const float4*)&g[c + 4];
  float4 b0 = *(const float4*)&bta[c], b1 = *(const float4*)&bta[c + 4];
  uint4 pk;
  pk.x = pack2(v[0]*inv*g0.x + b0.x, v[1]*inv*g0.y + b0.y);
  pk.y = pack2(v[2]*inv*g0.z + b0.z, v[3]*inv*g0.w + b0.w);
  pk.z = pack2(v[4]*inv*g1.x + b1.x, v[5]*inv*g1.y + b1.y);
  pk.w = pack2(v[6]*inv*g1.z + b1.z, v[7]*inv*g1.w + b1.w);
  *(uint4*)row = pk;
}

// ---------------- sparse pyramidal attention (wave-per-head, no LDS) -------
__global__ __launch_bounds__(512) void attn_sparse(
    const ushort* __restrict__ qkv, ushort* __restrict__ o) {
  int r = blockIdx.x;
  int b = r / 1360, i = r - b * 1360;
  int h = threadIdx.x >> 6, lane = threadIdx.x & 63;
  int S, sz, li;
  if (i < 1024)      { li = 0; S = 0;    sz = 1024; }
  else if (i < 1280) { li = 1; S = 1024; sz = 256; }
  else if (i < 1344) { li = 2; S = 1280; sz = 64; }
  else               { li = 3; S = 1344; sz = 16; }
  int p = i - S;
  int lo = p - 2; if (lo < 0) lo = 0;
  int hi = p + 2; if (hi > sz - 1) hi = sz - 1;
  int cnt = hi - lo + 1;
  int nk = cnt + (li > 0 ? 4 : 0) + (li < 3 ? 1 : 0);
  int Sprev = (li == 1) ? 0 : (li == 2) ? 1024 : 1280;
  int Snext = (li == 0) ? 1024 : (li == 1) ? 1280 : 1344;
  int j2 = lane >> 2, c = lane & 3;
  int key;
  if (j2 < cnt)                      key = S + lo + j2;
  else if (li > 0 && j2 - cnt < 4)   key = Sprev + 4 * p + (j2 - cnt);
  else if (li < 3)                   key = Snext + (p >> 2);
  else                               key = S + p;
  float partial = 0.0f;
  {
    const uint4* qv = (const uint4*)(qkv + (size_t)r * 1536 + h * 64 + c * 16);
    const uint4* kv = (const uint4*)(qkv + (size_t)(b * 1360 + key) * 1536 + 512 + h * 64 + c * 16);
#pragma unroll
    for (int cc = 0; cc < 2; cc++) {
      uint4 a = qv[cc], k4 = kv[cc];
      partial = fmaf(lo16(a.x), lo16(k4.x), partial); partial = fmaf(hi16(a.x), hi16(k4.x), partial);
      partial = fmaf(lo16(a.y), lo16(k4.y), partial); partial = fmaf(hi16(a.y), hi16(k4.y), partial);
      partial = fmaf(lo16(a.z), lo16(k4.z), partial); partial = fmaf(hi16(a.z), hi16(k4.z), partial);
      partial = fmaf(lo16(a.w), lo16(k4.w), partial); partial = fmaf(hi16(a.w), hi16(k4.w), partial);
    }
  }
  partial += __shfl_xor(partial, 1);
  partial += __shfl_xor(partial, 2);
  float s = partial * 0.125f;
  float m = -1e30f;
  for (int j = 0; j < nk; j++) m = fmaxf(m, __shfl(s, 4 * j));
  float denom = 0.0f;
  for (int j = 0; j < nk; j++) denom += __expf(__shfl(s, 4 * j) - m);
  float inv = 1.0f / denom;
  float acc = 0.0f;
  for (int j = 0; j < nk; j++) {
    float pj = __expf(__shfl(s, 4 * j) - m) * inv;
    int kj = __shfl(key, 4 * j);
    float vv = bf2f(qkv[(size_t)(b * 1360 + kj) * 1536 + 1024 + h * 64 + lane]);
    acc = fmaf(pj, vv, acc);
  }
  o[(size_t)r * 512 + h * 64 + lane] = f2bf(acc);
}

// ---------------- output gather (bf16 stream -> f32 out) -------------------
__global__ __launch_bounds__(512) void gather_out(
    const ushort* __restrict__ seq_bf, float* __restrict__ out) {
  int bl = blockIdx.x;
  int b = bl >> 10, i = bl & 1023;
  int d = threadIdx.x;
  size_t ob = (size_t)bl * 2048 + d;
  size_t base = (size_t)b * 1360;
  out[ob]        = bf2f(seq_bf[(base + i) * 512 + d]);
  out[ob + 512]  = bf2f(seq_bf[(base + 1024 + (i >> 2)) * 512 + d]);
  out[ob + 1024] = bf2f(seq_bf[(base + 1280 + (i >> 4)) * 512 + d]);
  out[ob + 1536] = bf2f(seq_bf[(base + 1344 + (i >> 6)) * 512 + d]);
}

// ---------------------------------------------------------------------------
extern "C" void kernel_launch(void* const* d_in, const int* in_sizes, int n_in,
                              void* d_out, int out_size, void* d_ws, size_t ws_size,
                              hipStream_t stream) {
  const float* x_enc   = (const float*)d_in[0];
  const float* x_mark  = (const float*)d_in[1];
  const float* conv_w  = (const float*)d_in[2];
  const float* conv_b  = (const float*)d_in[3];
  const float* temp_w  = (const float*)d_in[4];
  const float* temp_b  = (const float*)d_in[5];
  const float* down_w  = (const float*)d_in[6];
  const float* down_b  = (const float*)d_in[7];
  const float* pyr_w   = (const float*)d_in[8];
  const float* pyr_b   = (const float*)d_in[9];
  const float* bn_g    = (const float*)d_in[10];
  const float* bn_b    = (const float*)d_in[11];
  const float* up_w    = (const float*)d_in[12];
  const float* up_b    = (const float*)d_in[13];
  const float* norm_g  = (const float*)d_in[14];
  const float* norm_b  = (const float*)d_in[15];
  const float* wq      = (const float*)d_in[16];
  const float* wk      = (const float*)d_in[17];
  const float* wv      = (const float*)d_in[18];
  const float* fc_w    = (const float*)d_in[19];
  const float* fc_b    = (const float*)d_in[20];
  const float* ln1_g   = (const float*)d_in[21];
  const float* ln1_b   = (const float*)d_in[22];
  const float* w1      = (const float*)d_in[23];
  const float* b1      = (const float*)d_in[24];
  const float* w2      = (const float*)d_in[25];
  const float* b2      = (const float*)d_in[26];
  const float* ln2_g   = (const float*)d_in[27];
  const float* ln2_b   = (const float*)d_in[28];

  // ---- workspace layout (f32-word offsets); total 18,972,672 words = 72.4MB
  float* ws = (float*)d_ws;
  float*  e      = ws;                         // 2,097,152 w
  float*  tmp0   = ws + 2097152;               //   262,144 w
  float*  pyrf   = ws + 2359296;               //    86,016 w
  float*  pyru   = ws + 2445312;               //   688,128 w
  ushort* qkv_bf = (ushort*)ws;                // [5504][1536] bf16
  ushort* o_bf   = (ushort*)(ws + 4227072);    // [5504][512] bf16
  ushort* th_bf  = (ushort*)ws;                // [5504][2048] bf16
  ushort* t1     = (ushort*)(ws + 5636096);    // [5504][512] bf16
  ushort* seq_bf = (ushort*)(ws + 11272192);   // [5504][512] bf16
  ushort* qkvw   = (ushort*)(ws + 12681216);   // 4 x [1536][512] bf16
  ushort* fcw    = (ushort*)(ws + 14254080);   // 4 x [512][512] bf16
  ushort* w1t    = (ushort*)(ws + 14778368);   // 4 x [2048][512] bf16
  ushort* w2t    = (ushort*)(ws + 16875520);   // 4 x [512][2048] bf16

  // ---- weight cast+transpose (once per call) ----
  dim3 tb(32, 8);
  transpose_cast<<<dim3(16, 16, 4), tb, 0, stream>>>(wq, qkvw,          512, 512,  262144, 786432);
  transpose_cast<<<dim3(16, 16, 4), tb, 0, stream>>>(wk, qkvw + 262144, 512, 512,  262144, 786432);
  transpose_cast<<<dim3(16, 16, 4), tb, 0, stream>>>(wv, qkvw + 524288, 512, 512,  262144, 786432);
  transpose_cast<<<dim3(16, 16, 4), tb, 0, stream>>>(fc_w, fcw,         512, 512,  262144, 262144);
  transpose_cast<<<dim3(64, 16, 4), tb, 0, stream>>>(w1, w1t,           512, 2048, 1048576, 1048576);
  transpose_cast<<<dim3(16, 64, 4), tb, 0, stream>>>(w2, w2t,           2048, 512, 1048576, 1048576);

  // ---- prologue ----
  embed_kernel<<<4096, 512, 0, stream>>>(x_enc, x_mark, conv_w, conv_b,
                                         temp_w, temp_b, e);
  down_gemm<<<256, 256, 0, stream>>>(e, down_w, down_b, tmp0);
  pyr_conv<<<4 * 256, 64, 0, stream>>>(tmp0, 0, 1024, pyrf, 0, 336, 256,
                                       pyr_w, pyr_b, bn_g, bn_b);
  pyr_conv<<<4 * 64, 64, 0, stream>>>(pyrf, 0, 336, pyrf, 256, 336, 64,
                                      pyr_w + 16384, pyr_b + 64, bn_g + 64, bn_b + 64);
  pyr_conv<<<4 * 16, 64, 0, stream>>>(pyrf, 256, 336, pyrf, 320, 336, 16,
                                      pyr_w + 32768, pyr_b + 128, bn_g + 128, bn_b + 128);
  gemm_f32<<<dim3(8, 21), 256, 0, stream>>>(pyrf, up_w, up_b, pyru, 1344, 512, 64);
  ln_concat<<<1360, 256, 0, stream>>>(e, pyru, norm_g, norm_b, seq_bf);

  // ---- layers ----
  for (int l = 0; l < 4; l++) {
    gemm_bf16_t64<<<24 * 86, 256, 0, stream>>>(seq_bf, qkvw + (size_t)l * 786432,
                                               nullptr, qkv_bf, 1536, 512, 0);
    attn_sparse<<<5440, 512, 0, stream>>>(qkv_bf, o_bf);
    gemm_bf16_t32<<<8 * 172, 256, 0, stream>>>(o_bf, fcw + (size_t)l * 262144,
                                               fc_b + l * 512, t1, 512, 512);
    ln_add<<<1360, 256, 0, stream>>>(seq_bf, t1, ln1_g + l * 512, ln1_b + l * 512);
    gemm_bf16_t64<<<32 * 86, 256, 0, stream>>>(seq_bf, w1t + (size_t)l * 1048576,
                                               b1 + l * 2048, th_bf, 2048, 512, 1);
    gemm_bf16_t32<<<8 * 172, 256, 0, stream>>>(th_bf, w2t + (size_t)l * 1048576,
                                               b2 + l * 512, t1, 512, 2048);
    ln_add<<<1360, 256, 0, stream>>>(seq_bf, t1, ln2_g + l * 512, ln2_b + l * 512);
  }
  gather_out<<<4096, 512, 0, stream>>>(seq_bf, (float*)d_out);
}

// Round 11
// 541.774 us; speedup vs baseline: 1.3640x; 1.0464x over previous
//
#include <hip/hip_runtime.h>
#include <hip/hip_bf16.h>
#include <math.h>

// ---------------------------------------------------------------------------
// B=4, L_IN=1024, D=512, H=8, DK=64, DFF=2048, NL=4, WINDOW=[4,4,4], INNER=5.
// all_size=[1024,256,64,16], L_tot=1360, rows M=5440 padded to M_PAD=5504.
// ---------------------------------------------------------------------------

typedef __attribute__((ext_vector_type(8))) short short8;
typedef __attribute__((ext_vector_type(4))) float f32x4;

__device__ inline ushort f2bf(float x) {
  union { __hip_bfloat16 h; ushort u; } cv; cv.h = __float2bfloat16(x); return cv.u;
}
__device__ inline float bf2f(ushort u) {
  union { unsigned int i; float f; } cv; cv.i = (unsigned)u << 16; return cv.f;
}
__device__ inline float lo16(unsigned u) { union { unsigned i; float f; } c; c.i = u << 16; return c.f; }
__device__ inline float hi16(unsigned u) { union { unsigned i; float f; } c; c.i = u & 0xffff0000u; return c.f; }
__device__ inline unsigned pack2(float a, float b) {
  return (unsigned)f2bf(a) | ((unsigned)f2bf(b) << 16);
}

// tanh-form GELU (max |err| vs exact erf-GELU ~3e-3; well within budget)
__device__ inline float gelu_f(float x) {
  float y = 0.7978845608028654f * (x + 0.044715f * x * x * x);
  float t = __expf(-2.0f * y);
  float th = (1.0f - t) / (1.0f + t);
  return 0.5f * x * (1.0f + th);
}

// bijective XCD-chunk swizzle (m204): round-robin id -> contiguous chunk/XCD
__device__ inline int xcd_chunk(int orig, int nwg) {
  int q = nwg >> 3, r = nwg & 7;
  int xcd = orig & 7, idx = orig >> 3;
  int base = (xcd < r) ? xcd * (q + 1) : r * (q + 1) + (xcd - r) * q;
  return base + idx;
}

#define GLD16(gp, lp)                                                        \
  __builtin_amdgcn_global_load_lds(                                          \
      (const __attribute__((address_space(1))) void*)(gp),                   \
      (__attribute__((address_space(3))) void*)(lp), 16, 0, 0)

// ---------------- embed: circular conv3 + posenc + mark projection ---------
__global__ __launch_bounds__(512) void embed_kernel(
    const float* __restrict__ x_enc, const float* __restrict__ x_mark,
    const float* __restrict__ conv_w, const float* __restrict__ conv_b,
    const float* __restrict__ temp_w, const float* __restrict__ temp_b,
    float* __restrict__ e, ushort* __restrict__ e_bf) {
  int bl = blockIdx.x;
  int b = bl >> 10, l = bl & 1023;
  int d = threadIdx.x;
  int lm1 = (l + 1023) & 1023;
  int lp1 = (l + 1) & 1023;
  const float* w  = conv_w + d * 21;
  const float* x0 = x_enc + (size_t)(b * 1024 + lm1) * 7;
  const float* x1 = x_enc + (size_t)(b * 1024 + l)   * 7;
  const float* x2 = x_enc + (size_t)(b * 1024 + lp1) * 7;
  float acc = conv_b[d];
#pragma unroll
  for (int ci = 0; ci < 7; ci++) {
    acc = fmaf(x0[ci], w[ci * 3 + 0], acc);
    acc = fmaf(x1[ci], w[ci * 3 + 1], acc);
    acc = fmaf(x2[ci], w[ci * 3 + 2], acc);
  }
  int j = d >> 1;
  float dv = expf((float)(2 * j) * (-9.210340371976184f / 512.0f));
  float ang = (float)l * dv;
  float pe = (d & 1) ? cosf(ang) : sinf(ang);
  const float* xm = x_mark + (size_t)(b * 1024 + l) * 4;
  float mk = temp_b[d];
  mk = fmaf(xm[0], temp_w[d],        mk);
  mk = fmaf(xm[1], temp_w[512 + d],  mk);
  mk = fmaf(xm[2], temp_w[1024 + d], mk);
  mk = fmaf(xm[3], temp_w[1536 + d], mk);
  float v = acc + pe + mk;
  e[(size_t)bl * 512 + d] = v;
  e_bf[(size_t)bl * 512 + d] = f2bf(v);
}

// ---------------- weight cast+transpose: f32 [K][N] -> bf16 [N][K] ---------
__global__ __launch_bounds__(256) void transpose_cast(
    const float* __restrict__ src, ushort* __restrict__ dst,
    int K, int N, size_t src_lstride, size_t dst_lstride) {
  src += (size_t)blockIdx.z * src_lstride;
  dst += (size_t)blockIdx.z * dst_lstride;
  __shared__ float t[32][33];
  int k0 = blockIdx.y * 32, n0 = blockIdx.x * 32;
  int tx = threadIdx.x, ty = threadIdx.y;  // (32,8)
#pragma unroll
  for (int i = 0; i < 4; i++)
    t[ty + i * 8][tx] = src[(size_t)(k0 + ty + i * 8) * N + n0 + tx];
  __syncthreads();
#pragma unroll
  for (int i = 0; i < 4; i++)
    dst[(size_t)(n0 + ty + i * 8) * K + k0 + tx] = f2bf(t[tx][ty + i * 8]);
}

// ---------------- bf16 MFMA GEMM, 64x64 tile, BK=64, dbuf + swizzles -------
// A: [M_pad][K] bf16.  Bt: [N][K] bf16 (pre-transposed).  act 1 = GELU.
// 32KB LDS -> 5 blocks/CU. Chunk XOR-swizzle by row&7 (pre-swizzled global
// source + swizzled ds_read). XCD-chunk 1D grid (N/64)*(M/64).
__global__ __launch_bounds__(256) void gemm_bf16_t64(
    const ushort* __restrict__ A, const ushort* __restrict__ Bt,
    const float* __restrict__ bias, ushort* __restrict__ C,
    int N, int K, int act) {
  __shared__ short As[2][4096];   // 64 rows x 64 k
  __shared__ short Bs[2][4096];
  int nbx = N >> 6;
  int wgid = xcd_chunk(blockIdx.x, gridDim.x);
  int bx = wgid % nbx, by = wgid / nbx;
  int tid = threadIdx.x;
  int w = tid >> 6, lane = tid & 63;
  int bm = by << 6, bn = bx << 6;
  int gch = (tid & 7) ^ ((tid >> 3) & 7);
  const short* Ab = (const short*)A + (size_t)(bm + (tid >> 3)) * K + gch * 8;
  const short* Bb = (const short*)Bt + (size_t)(bn + (tid >> 3)) * K + gch * 8;
  int ldst = (tid & 192) * 8;          // wave-uniform base (shorts)
  int wr = (w >> 1) << 5, wc = (w & 1) << 5;
  int lr = lane & 15, kg = lane >> 4;
  int cs0 = ((kg)     ^ (lane & 7)) * 8;
  int cs1 = ((4 + kg) ^ (lane & 7)) * 8;
  f32x4 acc[2][2] = {};
#define STG64(buf, kt) do {                                                  \
    GLD16(Ab + (kt),                  &As[buf][ldst]);                       \
    GLD16(Ab + (kt) + (size_t)32 * K, &As[buf][2048 + ldst]);                \
    GLD16(Bb + (kt),                  &Bs[buf][ldst]);                       \
    GLD16(Bb + (kt) + (size_t)32 * K, &Bs[buf][2048 + ldst]); } while (0)
  STG64(0, 0);
  __syncthreads();
  int nt = K >> 6;
  for (int t = 0; t < nt; t++) {
    int cur = t & 1;
    if (t + 1 < nt) STG64(cur ^ 1, (t + 1) << 6);
    short8 a_[2][2], b_[2][2];
#pragma unroll
    for (int m = 0; m < 2; m++) {
      int rb = (wr + m * 16 + lr) * 64;
      a_[m][0] = *(const short8*)&As[cur][rb + cs0];
      a_[m][1] = *(const short8*)&As[cur][rb + cs1];
    }
#pragma unroll
    for (int n = 0; n < 2; n++) {
      int rb = (wc + n * 16 + lr) * 64;
      b_[n][0] = *(const short8*)&Bs[cur][rb + cs0];
      b_[n][1] = *(const short8*)&Bs[cur][rb + cs1];
    }
#pragma unroll
    for (int ks = 0; ks < 2; ks++)
#pragma unroll
      for (int m = 0; m < 2; m++)
#pragma unroll
        for (int n = 0; n < 2; n++)
          acc[m][n] = __builtin_amdgcn_mfma_f32_16x16x32_bf16(a_[m][ks], b_[n][ks], acc[m][n], 0, 0, 0);
    __syncthreads();
  }
#undef STG64
  int r0 = bm + wr + kg * 4;
  int c0 = bn + wc + lr;
#pragma unroll
  for (int m = 0; m < 2; m++) {
#pragma unroll
    for (int n = 0; n < 2; n++) {
      int col = c0 + n * 16;
      float bv = bias ? bias[col] : 0.0f;
#pragma unroll
      for (int j = 0; j < 4; j++) {
        int row = r0 + m * 16 + j;
        float v = acc[m][n][j] + bv;
        if (act == 1) v = gelu_f(v);
        C[(size_t)row * N + col] = f2bf(v);
      }
    }
  }
}

// ---------------- bf16 MFMA GEMM, 32x64 tile, BK=64 (small-N, hi-occ) ------
// Also used for down (N=64,K=512) and up (N=512,K=64) prologue projections.
__global__ __launch_bounds__(256) void gemm_bf16_t32(
    const ushort* __restrict__ A, const ushort* __restrict__ Bt,
    const float* __restrict__ bias, ushort* __restrict__ C,
    int N, int K) {
  __shared__ short As[2][2048];   // 32 rows x 64 k
  __shared__ short Bs[2][4096];   // 64 rows x 64 k
  int nbx = N >> 6;
  int wgid = xcd_chunk(blockIdx.x, gridDim.x);
  int bx = wgid % nbx, by = wgid / nbx;
  int tid = threadIdx.x;
  int w = tid >> 6, lane = tid & 63;
  int bm = by << 5, bn = bx << 6;
  int gch = (tid & 7) ^ ((tid >> 3) & 7);
  const short* Ab = (const short*)A + (size_t)(bm + (tid >> 3)) * K + gch * 8;
  const short* Bb = (const short*)Bt + (size_t)(bn + (tid >> 3)) * K + gch * 8;
  int ldst = (tid & 192) * 8;          // wave-uniform: w*512 shorts
  int wr = (w >> 1) << 4, wc = (w & 1) << 5;
  int lr = lane & 15, kg = lane >> 4;
  int cs0 = ((kg)     ^ (lane & 7)) * 8;
  int cs1 = ((4 + kg) ^ (lane & 7)) * 8;
  f32x4 acc[2] = {};
#define STG32(buf, kt) do {                                                  \
    GLD16(Ab + (kt),                  &As[buf][ldst]);                       \
    GLD16(Bb + (kt),                  &Bs[buf][ldst]);                       \
    GLD16(Bb + (kt) + (size_t)32 * K, &Bs[buf][2048 + ldst]); } while (0)
  STG32(0, 0);
  __syncthreads();
  int nt = K >> 6;
  for (int t = 0; t < nt; t++) {
    int cur = t & 1;
    if (t + 1 < nt) STG32(cur ^ 1, (t + 1) << 6);
    short8 a_[2], b_[2][2];
    {
      int rb = (wr + lr) * 64;
      a_[0] = *(const short8*)&As[cur][rb + cs0];
      a_[1] = *(const short8*)&As[cur][rb + cs1];
    }
#pragma unroll
    for (int n = 0; n < 2; n++) {
      int rb = (wc + n * 16 + lr) * 64;
      b_[n][0] = *(const short8*)&Bs[cur][rb + cs0];
      b_[n][1] = *(const short8*)&Bs[cur][rb + cs1];
    }
#pragma unroll
    for (int ks = 0; ks < 2; ks++)
#pragma unroll
      for (int n = 0; n < 2; n++)
        acc[n] = __builtin_amdgcn_mfma_f32_16x16x32_bf16(a_[ks], b_[n][ks], acc[n], 0, 0, 0);
    __syncthreads();
  }
#undef STG32
  int r0 = bm + wr + kg * 4;
  int c0 = bn + wc + lr;
#pragma unroll
  for (int n = 0; n < 2; n++) {
    int col = c0 + n * 16;
    float bv = bias ? bias[col] : 0.0f;
#pragma unroll
    for (int j = 0; j < 4; j++) {
      int row = r0 + j;
      C[(size_t)row * N + col] = f2bf(acc[n][j] + bv);
    }
  }
}

// ---------------- pyramid conv level (bf16 in/out, f32 accumulate) ---------
__global__ __launch_bounds__(64) void pyr_conv(
    const ushort* __restrict__ in, int in_base, int in_bstr,
    ushort* __restrict__ out, int out_base, int out_bstr, int out_len,
    const float* __restrict__ w, const float* __restrict__ bias,
    const float* __restrict__ bng, const float* __restrict__ bnb) {
  int blk = blockIdx.x;
  int b = blk / out_len, to = blk - b * out_len;
  int co = threadIdx.x;
  __shared__ float xin[4][64];
  const ushort* src = in + (size_t)(b * in_bstr + in_base + 4 * to) * 64;
#pragma unroll
  for (int r2 = 0; r2 < 4; r2++) xin[r2][co] = bf2f(src[r2 * 64 + co]);
  __syncthreads();
  const float* wr = w + (size_t)co * 256;
  float acc = bias[co];
#pragma unroll 16
  for (int ci = 0; ci < 64; ci++) {
    acc = fmaf(xin[0][ci], wr[ci * 4 + 0], acc);
    acc = fmaf(xin[1][ci], wr[ci * 4 + 1], acc);
    acc = fmaf(xin[2][ci], wr[ci * 4 + 2], acc);
    acc = fmaf(xin[3][ci], wr[ci * 4 + 3], acc);
  }
  float y = fmaf(bng[co], acc, bnb[co]);
  y = y > 0.0f ? y : expm1f(y);
  out[(size_t)(b * out_bstr + out_base + to) * 64 + co] = f2bf(y);
}

// ---------------- LayerNorm concat, wave-per-row -> bf16 stream ------------
__global__ __launch_bounds__(256) void ln_concat(
    const float* __restrict__ e, const ushort* __restrict__ pyru,
    const float* __restrict__ g, const float* __restrict__ bta,
    ushort* __restrict__ seq_bf) {
  int r = (blockIdx.x << 2) + (threadIdx.x >> 6);
  int lane = threadIdx.x & 63;
  int b = r / 1360, i = r - b * 1360;
  int c = lane << 3;
  float v[8];
  if (i < 1024) {
    const float* src = e + (size_t)(b * 1024 + i) * 512 + c;
    float4 v0 = *(const float4*)&src[0];
    float4 v1 = *(const float4*)&src[4];
    v[0] = v0.x; v[1] = v0.y; v[2] = v0.z; v[3] = v0.w;
    v[4] = v1.x; v[5] = v1.y; v[6] = v1.z; v[7] = v1.w;
  } else {
    uint4 sv = *(const uint4*)(pyru + (size_t)(b * 336 + (i - 1024)) * 512 + c);
    v[0] = lo16(sv.x); v[1] = hi16(sv.x); v[2] = lo16(sv.y); v[3] = hi16(sv.y);
    v[4] = lo16(sv.z); v[5] = hi16(sv.z); v[6] = lo16(sv.w); v[7] = hi16(sv.w);
  }
  float sum = v[0]+v[1]+v[2]+v[3]+v[4]+v[5]+v[6]+v[7];
#pragma unroll
  for (int off = 1; off < 64; off <<= 1) sum += __shfl_xor(sum, off);
  float mu = sum * (1.0f / 512.0f);
  float sq = 0.0f;
#pragma unroll
  for (int k = 0; k < 8; k++) { v[k] -= mu; sq += v[k] * v[k]; }
#pragma unroll
  for (int off = 1; off < 64; off <<= 1) sq += __shfl_xor(sq, off);
  float inv = rsqrtf(sq * (1.0f / 512.0f) + 1e-5f);
  float4 g0 = *(const float4*)&g[c],   g1 = *(const float4*)&g[c + 4];
  float4 b0 = *(const float4*)&bta[c], b1 = *(const float4*)&bta[c + 4];
  uint4 pk;
  pk.x = pack2(v[0]*inv*g0.x + b0.x, v[1]*inv*g0.y + b0.y);
  pk.y = pack2(v[2]*inv*g0.z + b0.z, v[3]*inv*g0.w + b0.w);
  pk.z = pack2(v[4]*inv*g1.x + b1.x, v[5]*inv*g1.y + b1.y);
  pk.w = pack2(v[6]*inv*g1.z + b1.z, v[7]*inv*g1.w + b1.w);
  *(uint4*)(seq_bf + (size_t)r * 512 + c) = pk;
}

// ---------------- residual add + LayerNorm on bf16 stream ------------------
__global__ __launch_bounds__(256) void ln_add(
    ushort* __restrict__ seq_bf, const ushort* __restrict__ t1,
    const float* __restrict__ g, const float* __restrict__ bta) {
  int r = (blockIdx.x << 2) + (threadIdx.x >> 6);
  int lane = threadIdx.x & 63;
  int c = lane << 3;
  ushort* row = seq_bf + (size_t)r * 512 + c;
  uint4 sv = *(const uint4*)row;
  uint4 tv = *(const uint4*)(t1 + (size_t)r * 512 + c);
  float v[8] = {
    lo16(sv.x) + lo16(tv.x), hi16(sv.x) + hi16(tv.x),
    lo16(sv.y) + lo16(tv.y), hi16(sv.y) + hi16(tv.y),
    lo16(sv.z) + lo16(tv.z), hi16(sv.z) + hi16(tv.z),
    lo16(sv.w) + lo16(tv.w), hi16(sv.w) + hi16(tv.w) };
  float sum = v[0]+v[1]+v[2]+v[3]+v[4]+v[5]+v[6]+v[7];
#pragma unroll
  for (int off = 1; off < 64; off <<= 1) sum += __shfl_xor(sum, off);
  float mu = sum * (1.0f / 512.0f);
  float sq = 0.0f;
#pragma unroll
  for (int k = 0; k < 8; k++) { v[k] -= mu; sq += v[k] * v[k]; }
#pragma unroll
  for (int off = 1; off < 64; off <<= 1) sq += __shfl_xor(sq, off);
  float inv = rsqrtf(sq * (1.0f / 512.0f) + 1e-5f);
  float4 g0 = *(const float4*)&g[c],   g1 = *(const float4*)&g[c + 4];
  float4 b0 = *(const float4*)&bta[c], b1 = *(const float4*)&bta[c + 4];
  uint4 pk;
  pk.x = pack2(v[0]*inv*g0.x + b0.x, v[1]*inv*g0.y + b0.y);
  pk.y = pack2(v[2]*inv*g0.z + b0.z, v[3]*inv*g0.w + b0.w);
  pk.z = pack2(v[4]*inv*g1.x + b1.x, v[5]*inv*g1.y + b1.y);
  pk.w = pack2(v[6]*inv*g1.z + b1.z, v[7]*inv*g1.w + b1.w);
  *(uint4*)row = pk;
}

// ---------------- sparse pyramidal attention (wave-per-head, no LDS) -------
__global__ __launch_bounds__(512) void attn_sparse(
    const ushort* __restrict__ qkv, ushort* __restrict__ o) {
  int r = blockIdx.x;
  int b = r / 1360, i = r - b * 1360;
  int h = threadIdx.x >> 6, lane = threadIdx.x & 63;
  int S, sz, li;
  if (i < 1024)      { li = 0; S = 0;    sz = 1024; }
  else if (i < 1280) { li = 1; S = 1024; sz = 256; }
  else if (i < 1344) { li = 2; S = 1280; sz = 64; }
  else               { li = 3; S = 1344; sz = 16; }
  int p = i - S;
  int lo = p - 2; if (lo < 0) lo = 0;
  int hi = p + 2; if (hi > sz - 1) hi = sz - 1;
  int cnt = hi - lo + 1;
  int nk = cnt + (li > 0 ? 4 : 0) + (li < 3 ? 1 : 0);
  int Sprev = (li == 1) ? 0 : (li == 2) ? 1024 : 1280;
  int Snext = (li == 0) ? 1024 : (li == 1) ? 1280 : 1344;
  int j2 = lane >> 2, c = lane & 3;
  int key;
  if (j2 < cnt)                      key = S + lo + j2;
  else if (li > 0 && j2 - cnt < 4)   key = Sprev + 4 * p + (j2 - cnt);
  else if (li < 3)                   key = Snext + (p >> 2);
  else                               key = S + p;
  float partial = 0.0f;
  {
    const uint4* qv = (const uint4*)(qkv + (size_t)r * 1536 + h * 64 + c * 16);
    const uint4* kv = (const uint4*)(qkv + (size_t)(b * 1360 + key) * 1536 + 512 + h * 64 + c * 16);
#pragma unroll
    for (int cc = 0; cc < 2; cc++) {
      uint4 a = qv[cc], k4 = kv[cc];
      partial = fmaf(lo16(a.x), lo16(k4.x), partial); partial = fmaf(hi16(a.x), hi16(k4.x), partial);
      partial = fmaf(lo16(a.y), lo16(k4.y), partial); partial = fmaf(hi16(a.y), hi16(k4.y), partial);
      partial = fmaf(lo16(a.z), lo16(k4.z), partial); partial = fmaf(hi16(a.z), hi16(k4.z), partial);
      partial = fmaf(lo16(a.w), lo16(k4.w), partial); partial = fmaf(hi16(a.w), hi16(k4.w), partial);
    }
  }
  partial += __shfl_xor(partial, 1);
  partial += __shfl_xor(partial, 2);
  float s = partial * 0.125f;
  float m = -1e30f;
  for (int j = 0; j < nk; j++) m = fmaxf(m, __shfl(s, 4 * j));
  float denom = 0.0f;
  for (int j = 0; j < nk; j++) denom += __expf(__shfl(s, 4 * j) - m);
  float inv = 1.0f / denom;
  float acc = 0.0f;
  for (int j = 0; j < nk; j++) {
    float pj = __expf(__shfl(s, 4 * j) - m) * inv;
    int kj = __shfl(key, 4 * j);
    float vv = bf2f(qkv[(size_t)(b * 1360 + kj) * 1536 + 1024 + h * 64 + lane]);
    acc = fmaf(pj, vv, acc);
  }
  o[(size_t)r * 512 + h * 64 + lane] = f2bf(acc);
}

// ---------------- output gather (bf16 stream -> f32 out) -------------------
__global__ __launch_bounds__(512) void gather_out(
    const ushort* __restrict__ seq_bf, float* __restrict__ out) {
  int bl = blockIdx.x;
  int b = bl >> 10, i = bl & 1023;
  int d = threadIdx.x;
  size_t ob = (size_t)bl * 2048 + d;
  size_t base = (size_t)b * 1360;
  out[ob]        = bf2f(seq_bf[(base + i) * 512 + d]);
  out[ob + 512]  = bf2f(seq_bf[(base + 1024 + (i >> 2)) * 512 + d]);
  out[ob + 1024] = bf2f(seq_bf[(base + 1280 + (i >> 4)) * 512 + d]);
  out[ob + 1536] = bf2f(seq_bf[(base + 1344 + (i >> 6)) * 512 + d]);
}

// ---------------------------------------------------------------------------
extern "C" void kernel_launch(void* const* d_in, const int* in_sizes, int n_in,
                              void* d_out, int out_size, void* d_ws, size_t ws_size,
                              hipStream_t stream) {
  const float* x_enc   = (const float*)d_in[0];
  const float* x_mark  = (const float*)d_in[1];
  const float* conv_w  = (const float*)d_in[2];
  const float* conv_b  = (const float*)d_in[3];
  const float* temp_w  = (const float*)d_in[4];
  const float* temp_b  = (const float*)d_in[5];
  const float* down_w  = (const float*)d_in[6];
  const float* down_b  = (const float*)d_in[7];
  const float* pyr_w   = (const float*)d_in[8];
  const float* pyr_b   = (const float*)d_in[9];
  const float* bn_g    = (const float*)d_in[10];
  const float* bn_b    = (const float*)d_in[11];
  const float* up_w    = (const float*)d_in[12];
  const float* up_b    = (const float*)d_in[13];
  const float* norm_g  = (const float*)d_in[14];
  const float* norm_b  = (const float*)d_in[15];
  const float* wq      = (const float*)d_in[16];
  const float* wk      = (const float*)d_in[17];
  const float* wv      = (const float*)d_in[18];
  const float* fc_w    = (const float*)d_in[19];
  const float* fc_b    = (const float*)d_in[20];
  const float* ln1_g   = (const float*)d_in[21];
  const float* ln1_b   = (const float*)d_in[22];
  const float* w1      = (const float*)d_in[23];
  const float* b1      = (const float*)d_in[24];
  const float* w2      = (const float*)d_in[25];
  const float* b2      = (const float*)d_in[26];
  const float* ln2_g   = (const float*)d_in[27];
  const float* ln2_b   = (const float*)d_in[28];

  // ---- workspace layout (f32-word offsets); total <= 18,972,672 words -----
  float* ws = (float*)d_ws;
  // prologue region (all dead before layer loop; aliased by qkv/o/th):
  float*  e       = ws;                        // [4096][512] f32  (2,097,152 w)
  ushort* e_bf    = (ushort*)(ws + 2097152);   // [4096][512] bf16 (1,048,576 w)
  ushort* tmp0_bf = (ushort*)(ws + 3145728);   // [4096][64] bf16  (  131,072 w)
  ushort* pyrf_bf = (ushort*)(ws + 3276800);   // [1344][64] bf16  (   43,008 w)
  ushort* pyru_bf = (ushort*)(ws + 3319808);   // [1344][512] bf16 (  344,064 w)
  // layer-loop aliases:
  ushort* qkv_bf = (ushort*)ws;                // [5504][1536] bf16 (4,227,072 w)
  ushort* o_bf   = (ushort*)(ws + 4227072);    // [5504][512] bf16
  ushort* th_bf  = (ushort*)ws;                // [5504][2048] bf16
  ushort* t1     = (ushort*)(ws + 5636096);    // [5504][512] bf16
  ushort* dwt    = (ushort*)(ws + 7045120);    // down_w^T [64][512]  (16,384 w)
  ushort* uwt    = (ushort*)(ws + 7061504);    // up_w^T  [512][64]   (16,384 w)
  ushort* seq_bf = (ushort*)(ws + 11272192);   // [5504][512] bf16
  ushort* qkvw   = (ushort*)(ws + 12681216);   // 4 x [1536][512] bf16
  ushort* fcw    = (ushort*)(ws + 14254080);   // 4 x [512][512] bf16
  ushort* w1t    = (ushort*)(ws + 14778368);   // 4 x [2048][512] bf16
  ushort* w2t    = (ushort*)(ws + 16875520);   // 4 x [512][2048] bf16

  // ---- weight cast+transpose (once per call) ----
  dim3 tb(32, 8);
  transpose_cast<<<dim3(16, 16, 4), tb, 0, stream>>>(wq, qkvw,          512, 512,  262144, 786432);
  transpose_cast<<<dim3(16, 16, 4), tb, 0, stream>>>(wk, qkvw + 262144, 512, 512,  262144, 786432);
  transpose_cast<<<dim3(16, 16, 4), tb, 0, stream>>>(wv, qkvw + 524288, 512, 512,  262144, 786432);
  transpose_cast<<<dim3(16, 16, 4), tb, 0, stream>>>(fc_w, fcw,         512, 512,  262144, 262144);
  transpose_cast<<<dim3(64, 16, 4), tb, 0, stream>>>(w1, w1t,           512, 2048, 1048576, 1048576);
  transpose_cast<<<dim3(16, 64, 4), tb, 0, stream>>>(w2, w2t,           2048, 512, 1048576, 1048576);
  transpose_cast<<<dim3(2, 16, 1), tb, 0, stream>>>(down_w, dwt,        512, 64,   0, 0);
  transpose_cast<<<dim3(16, 2, 1), tb, 0, stream>>>(up_w, uwt,          64, 512,   0, 0);

  // ---- prologue (all-bf16 MFMA path) ----
  embed_kernel<<<4096, 512, 0, stream>>>(x_enc, x_mark, conv_w, conv_b,
                                         temp_w, temp_b, e, e_bf);
  gemm_bf16_t32<<<128, 256, 0, stream>>>(e_bf, dwt, down_b, tmp0_bf, 64, 512);
  pyr_conv<<<4 * 256, 64, 0, stream>>>(tmp0_bf, 0, 1024, pyrf_bf, 0, 336, 256,
                                       pyr_w, pyr_b, bn_g, bn_b);
  pyr_conv<<<4 * 64, 64, 0, stream>>>(pyrf_bf, 0, 336, pyrf_bf, 256, 336, 64,
                                      pyr_w + 16384, pyr_b + 64, bn_g + 64, bn_b + 64);
  pyr_conv<<<4 * 16, 64, 0, stream>>>(pyrf_bf, 256, 336, pyrf_bf, 320, 336, 16,
                                      pyr_w + 32768, pyr_b + 128, bn_g + 128, bn_b + 128);
  gemm_bf16_t32<<<8 * 42, 256, 0, stream>>>(pyrf_bf, uwt, up_b, pyru_bf, 512, 64);
  ln_concat<<<1360, 256, 0, stream>>>(e, pyru_bf, norm_g, norm_b, seq_bf);

  // ---- layers ----
  for (int l = 0; l < 4; l++) {
    gemm_bf16_t64<<<24 * 86, 256, 0, stream>>>(seq_bf, qkvw + (size_t)l * 786432,
                                               nullptr, qkv_bf, 1536, 512, 0);
    attn_sparse<<<5440, 512, 0, stream>>>(qkv_bf, o_bf);
    gemm_bf16_t32<<<8 * 172, 256, 0, stream>>>(o_bf, fcw + (size_t)l * 262144,
                                               fc_b + l * 512, t1, 512, 512);
    ln_add<<<1360, 256, 0, stream>>>(seq_bf, t1, ln1_g + l * 512, ln1_b + l * 512);
    gemm_bf16_t64<<<32 * 86, 256, 0, stream>>>(seq_bf, w1t + (size_t)l * 1048576,
                                               b1 + l * 2048, th_bf, 2048, 512, 1);
    gemm_bf16_t32<<<8 * 172, 256, 0, stream>>>(th_bf, w2t + (size_t)l * 1048576,
                                               b2 + l * 512, t1, 512, 2048);
    ln_add<<<1360, 256, 0, stream>>>(seq_bf, t1, ln2_g + l * 512, ln2_b + l * 512);
  }
  gather_out<<<4096, 512, 0, stream>>>(seq_bf, (float*)d_out);
}

// Round 13
// 521.269 us; speedup vs baseline: 1.4177x; 1.0393x over previous
//
#include <hip/hip_runtime.h>
#include <hip/hip_bf16.h>
#include <math.h>

// ---------------------------------------------------------------------------
// B=4, L_IN=1024, D=512, H=8, DK=64, DFF=2048, NL=4, WINDOW=[4,4,4], INNER=5.
// all_size=[1024,256,64,16], L_tot=1360, rows M=5440 padded to M_PAD=5504.
// ---------------------------------------------------------------------------

typedef __attribute__((ext_vector_type(8))) short short8;
typedef __attribute__((ext_vector_type(4))) float f32x4;

__device__ inline ushort f2bf(float x) {
  union { __hip_bfloat16 h; ushort u; } cv; cv.h = __float2bfloat16(x); return cv.u;
}
__device__ inline float bf2f(ushort u) {
  union { unsigned int i; float f; } cv; cv.i = (unsigned)u << 16; return cv.f;
}
__device__ inline float lo16(unsigned u) { union { unsigned i; float f; } c; c.i = u << 16; return c.f; }
__device__ inline float hi16(unsigned u) { union { unsigned i; float f; } c; c.i = u & 0xffff0000u; return c.f; }
__device__ inline unsigned pack2(float a, float b) {
  return (unsigned)f2bf(a) | ((unsigned)f2bf(b) << 16);
}

// tanh-form GELU (max |err| vs exact erf-GELU ~3e-3; well within budget)
__device__ inline float gelu_f(float x) {
  float y = 0.7978845608028654f * (x + 0.044715f * x * x * x);
  float t = __expf(-2.0f * y);
  float th = (1.0f - t) / (1.0f + t);
  return 0.5f * x * (1.0f + th);
}

// bijective XCD-chunk swizzle (m204): round-robin id -> contiguous chunk/XCD
__device__ inline int xcd_chunk(int orig, int nwg) {
  int q = nwg >> 3, r = nwg & 7;
  int xcd = orig & 7, idx = orig >> 3;
  int base = (xcd < r) ? xcd * (q + 1) : r * (q + 1) + (xcd - r) * q;
  return base + idx;
}

#define GLD16(gp, lp)                                                        \
  __builtin_amdgcn_global_load_lds(                                          \
      (const __attribute__((address_space(1))) void*)(gp),                   \
      (__attribute__((address_space(3))) void*)(lp), 16, 0, 0)

// ---------------- embed: circular conv3 + posenc + mark projection ---------
__global__ __launch_bounds__(512) void embed_kernel(
    const float* __restrict__ x_enc, const float* __restrict__ x_mark,
    const float* __restrict__ conv_w, const float* __restrict__ conv_b,
    const float* __restrict__ temp_w, const float* __restrict__ temp_b,
    float* __restrict__ e, ushort* __restrict__ e_bf) {
  int bl = blockIdx.x;
  int b = bl >> 10, l = bl & 1023;
  int d = threadIdx.x;
  int lm1 = (l + 1023) & 1023;
  int lp1 = (l + 1) & 1023;
  const float* w  = conv_w + d * 21;
  const float* x0 = x_enc + (size_t)(b * 1024 + lm1) * 7;
  const float* x1 = x_enc + (size_t)(b * 1024 + l)   * 7;
  const float* x2 = x_enc + (size_t)(b * 1024 + lp1) * 7;
  float acc = conv_b[d];
#pragma unroll
  for (int ci = 0; ci < 7; ci++) {
    acc = fmaf(x0[ci], w[ci * 3 + 0], acc);
    acc = fmaf(x1[ci], w[ci * 3 + 1], acc);
    acc = fmaf(x2[ci], w[ci * 3 + 2], acc);
  }
  int j = d >> 1;
  float dv = __expf((float)(2 * j) * (-9.210340371976184f / 512.0f));
  float ang = (float)l * dv;
  float pe = (d & 1) ? __cosf(ang) : __sinf(ang);
  const float* xm = x_mark + (size_t)(b * 1024 + l) * 4;
  float mk = temp_b[d];
  mk = fmaf(xm[0], temp_w[d],        mk);
  mk = fmaf(xm[1], temp_w[512 + d],  mk);
  mk = fmaf(xm[2], temp_w[1024 + d], mk);
  mk = fmaf(xm[3], temp_w[1536 + d], mk);
  float v = acc + pe + mk;
  e[(size_t)bl * 512 + d] = v;
  e_bf[(size_t)bl * 512 + d] = f2bf(v);
}

// ---------------- weight cast+transpose: f32 [K][N] -> bf16 [N][K] ---------
__global__ __launch_bounds__(256) void transpose_cast(
    const float* __restrict__ src, ushort* __restrict__ dst,
    int K, int N, size_t src_lstride, size_t dst_lstride) {
  src += (size_t)blockIdx.z * src_lstride;
  dst += (size_t)blockIdx.z * dst_lstride;
  __shared__ float t[32][33];
  int k0 = blockIdx.y * 32, n0 = blockIdx.x * 32;
  int tx = threadIdx.x, ty = threadIdx.y;  // (32,8)
#pragma unroll
  for (int i = 0; i < 4; i++)
    t[ty + i * 8][tx] = src[(size_t)(k0 + ty + i * 8) * N + n0 + tx];
  __syncthreads();
#pragma unroll
  for (int i = 0; i < 4; i++)
    dst[(size_t)(n0 + ty + i * 8) * K + k0 + tx] = f2bf(t[tx][ty + i * 8]);
}

// ---------------- bf16 MFMA GEMM, 64x64 tile, 8 waves (512 thr), BK=64 -----
// 32KB LDS, 4 blocks/CU x 8 waves = 32 waves/CU (occupancy cap). Wave w owns
// a 16x32 sub-tile: wr=(w&3)*16, wc=(w>>2)*32. 1 GLD16/operand/thread.
// Chunk XOR-swizzle by row&7; XCD-chunk 1D grid (N/64)*(M/64).
__global__ __launch_bounds__(512, 8) void gemm_bf16_t64w8(
    const ushort* __restrict__ A, const ushort* __restrict__ Bt,
    const float* __restrict__ bias, ushort* __restrict__ C,
    int N, int K, int act) {
  __shared__ short As[2][4096];   // 64 rows x 64 k
  __shared__ short Bs[2][4096];
  int nbx = N >> 6;
  int wgid = xcd_chunk(blockIdx.x, gridDim.x);
  int bx = wgid % nbx, by = wgid / nbx;
  int tid = threadIdx.x;
  int w = tid >> 6, lane = tid & 63;
  int bm = by << 6, bn = bx << 6;
  int gch = (tid & 7) ^ ((tid >> 3) & 7);
  const short* Ab = (const short*)A + (size_t)(bm + (tid >> 3)) * K + gch * 8;
  const short* Bb = (const short*)Bt + (size_t)(bn + (tid >> 3)) * K + gch * 8;
  int ldst = (tid & 448) * 8;          // wave-uniform base: w*512 shorts
  int wr = (w & 3) << 4, wc = (w >> 2) << 5;
  int lr = lane & 15, kg = lane >> 4;
  int cs0 = ((kg)     ^ (lane & 7)) * 8;
  int cs1 = ((4 + kg) ^ (lane & 7)) * 8;
  f32x4 acc[2] = {};
#define STG(buf, kt) do {                                                    \
    GLD16(Ab + (kt), &As[buf][ldst]);                                        \
    GLD16(Bb + (kt), &Bs[buf][ldst]); } while (0)
  STG(0, 0);
  __syncthreads();
  int nt = K >> 6;
  for (int t = 0; t < nt; t++) {
    int cur = t & 1;
    if (t + 1 < nt) STG(cur ^ 1, (t + 1) << 6);
    short8 a_[2], b_[2][2];
    {
      int rb = (wr + lr) * 64;
      a_[0] = *(const short8*)&As[cur][rb + cs0];
      a_[1] = *(const short8*)&As[cur][rb + cs1];
    }
#pragma unroll
    for (int n = 0; n < 2; n++) {
      int rb = (wc + n * 16 + lr) * 64;
      b_[n][0] = *(const short8*)&Bs[cur][rb + cs0];
      b_[n][1] = *(const short8*)&Bs[cur][rb + cs1];
    }
#pragma unroll
    for (int ks = 0; ks < 2; ks++)
#pragma unroll
      for (int n = 0; n < 2; n++)
        acc[n] = __builtin_amdgcn_mfma_f32_16x16x32_bf16(a_[ks], b_[n][ks], acc[n], 0, 0, 0);
    __syncthreads();
  }
#undef STG
  int r0 = bm + wr + kg * 4;
  int c0 = bn + wc + lr;
#pragma unroll
  for (int n = 0; n < 2; n++) {
    int col = c0 + n * 16;
    float bv = bias ? bias[col] : 0.0f;
#pragma unroll
    for (int j = 0; j < 4; j++) {
      int row = r0 + j;
      float v = acc[n][j] + bv;
      if (act == 1) v = gelu_f(v);
      C[(size_t)row * N + col] = f2bf(v);
    }
  }
}

// ---------------- bf16 MFMA GEMM, 32x64 tile, BK=64 (small-N, hi-occ) ------
__global__ __launch_bounds__(256) void gemm_bf16_t32(
    const ushort* __restrict__ A, const ushort* __restrict__ Bt,
    const float* __restrict__ bias, ushort* __restrict__ C,
    int N, int K) {
  __shared__ short As[2][2048];   // 32 rows x 64 k
  __shared__ short Bs[2][4096];   // 64 rows x 64 k
  int nbx = N >> 6;
  int wgid = xcd_chunk(blockIdx.x, gridDim.x);
  int bx = wgid % nbx, by = wgid / nbx;
  int tid = threadIdx.x;
  int w = tid >> 6, lane = tid & 63;
  int bm = by << 5, bn = bx << 6;
  int gch = (tid & 7) ^ ((tid >> 3) & 7);
  const short* Ab = (const short*)A + (size_t)(bm + (tid >> 3)) * K + gch * 8;
  const short* Bb = (const short*)Bt + (size_t)(bn + (tid >> 3)) * K + gch * 8;
  int ldst = (tid & 192) * 8;          // wave-uniform: w*512 shorts
  int wr = (w >> 1) << 4, wc = (w & 1) << 5;
  int lr = lane & 15, kg = lane >> 4;
  int cs0 = ((kg)     ^ (lane & 7)) * 8;
  int cs1 = ((4 + kg) ^ (lane & 7)) * 8;
  f32x4 acc[2] = {};
#define STG32(buf, kt) do {                                                  \
    GLD16(Ab + (kt),                  &As[buf][ldst]);                       \
    GLD16(Bb + (kt),                  &Bs[buf][ldst]);                       \
    GLD16(Bb + (kt) + (size_t)32 * K, &Bs[buf][2048 + ldst]); } while (0)
  STG32(0, 0);
  __syncthreads();
  int nt = K >> 6;
  for (int t = 0; t < nt; t++) {
    int cur = t & 1;
    if (t + 1 < nt) STG32(cur ^ 1, (t + 1) << 6);
    short8 a_[2], b_[2][2];
    {
      int rb = (wr + lr) * 64;
      a_[0] = *(const short8*)&As[cur][rb + cs0];
      a_[1] = *(const short8*)&As[cur][rb + cs1];
    }
#pragma unroll
    for (int n = 0; n < 2; n++) {
      int rb = (wc + n * 16 + lr) * 64;
      b_[n][0] = *(const short8*)&Bs[cur][rb + cs0];
      b_[n][1] = *(const short8*)&Bs[cur][rb + cs1];
    }
#pragma unroll
    for (int ks = 0; ks < 2; ks++)
#pragma unroll
      for (int n = 0; n < 2; n++)
        acc[n] = __builtin_amdgcn_mfma_f32_16x16x32_bf16(a_[ks], b_[n][ks], acc[n], 0, 0, 0);
    __syncthreads();
  }
#undef STG32
  int r0 = bm + wr + kg * 4;
  int c0 = bn + wc + lr;
#pragma unroll
  for (int n = 0; n < 2; n++) {
    int col = c0 + n * 16;
    float bv = bias ? bias[col] : 0.0f;
#pragma unroll
    for (int j = 0; j < 4; j++) {
      int row = r0 + j;
      C[(size_t)row * N + col] = f2bf(acc[n][j] + bv);
    }
  }
}

// ---------------- pyramid conv level (bf16 in/out, f32 accumulate) ---------
__global__ __launch_bounds__(64) void pyr_conv(
    const ushort* __restrict__ in, int in_base, int in_bstr,
    ushort* __restrict__ out, int out_base, int out_bstr, int out_len,
    const float* __restrict__ w, const float* __restrict__ bias,
    const float* __restrict__ bng, const float* __restrict__ bnb) {
  int blk = blockIdx.x;
  int b = blk / out_len, to = blk - b * out_len;
  int co = threadIdx.x;
  __shared__ float xin[4][64];
  const ushort* src = in + (size_t)(b * in_bstr + in_base + 4 * to) * 64;
#pragma unroll
  for (int r2 = 0; r2 < 4; r2++) xin[r2][co] = bf2f(src[r2 * 64 + co]);
  __syncthreads();
  const float* wr = w + (size_t)co * 256;
  float acc = bias[co];
#pragma unroll 16
  for (int ci = 0; ci < 64; ci++) {
    acc = fmaf(xin[0][ci], wr[ci * 4 + 0], acc);
    acc = fmaf(xin[1][ci], wr[ci * 4 + 1], acc);
    acc = fmaf(xin[2][ci], wr[ci * 4 + 2], acc);
    acc = fmaf(xin[3][ci], wr[ci * 4 + 3], acc);
  }
  float y = fmaf(bng[co], acc, bnb[co]);
  y = y > 0.0f ? y : expm1f(y);
  out[(size_t)(b * out_bstr + out_base + to) * 64 + co] = f2bf(y);
}

// ---------------- LayerNorm concat, wave-per-row -> bf16 stream ------------
__global__ __launch_bounds__(256) void ln_concat(
    const float* __restrict__ e, const ushort* __restrict__ pyru,
    const float* __restrict__ g, const float* __restrict__ bta,
    ushort* __restrict__ seq_bf) {
  int r = (blockIdx.x << 2) + (threadIdx.x >> 6);
  int lane = threadIdx.x & 63;
  int b = r / 1360, i = r - b * 1360;
  int c = lane << 3;
  float v[8];
  if (i < 1024) {
    const float* src = e + (size_t)(b * 1024 + i) * 512 + c;
    float4 v0 = *(const float4*)&src[0];
    float4 v1 = *(const float4*)&src[4];
    v[0] = v0.x; v[1] = v0.y; v[2] = v0.z; v[3] = v0.w;
    v[4] = v1.x; v[5] = v1.y; v[6] = v1.z; v[7] = v1.w;
  } else {
    uint4 sv = *(const uint4*)(pyru + (size_t)(b * 336 + (i - 1024)) * 512 + c);
    v[0] = lo16(sv.x); v[1] = hi16(sv.x); v[2] = lo16(sv.y); v[3] = hi16(sv.y);
    v[4] = lo16(sv.z); v[5] = hi16(sv.z); v[6] = lo16(sv.w); v[7] = hi16(sv.w);
  }
  float sum = v[0]+v[1]+v[2]+v[3]+v[4]+v[5]+v[6]+v[7];
#pragma unroll
  for (int off = 1; off < 64; off <<= 1) sum += __shfl_xor(sum, off);
  float mu = sum * (1.0f / 512.0f);
  float sq = 0.0f;
#pragma unroll
  for (int k = 0; k < 8; k++) { v[k] -= mu; sq += v[k] * v[k]; }
#pragma unroll
  for (int off = 1; off < 64; off <<= 1) sq += __shfl_xor(sq, off);
  float inv = rsqrtf(sq * (1.0f / 512.0f) + 1e-5f);
  float4 g0 = *(const float4*)&g[c],   g1 = *(const float4*)&g[c + 4];
  float4 b0 = *(const float4*)&bta[c], b1 = *(const float4*)&bta[c + 4];
  uint4 pk;
  pk.x = pack2(v[0]*inv*g0.x + b0.x, v[1]*inv*g0.y + b0.y);
  pk.y = pack2(v[2]*inv*g0.z + b0.z, v[3]*inv*g0.w + b0.w);
  pk.z = pack2(v[4]*inv*g1.x + b1.x, v[5]*inv*g1.y + b1.y);
  pk.w = pack2(v[6]*inv*g1.z + b1.z, v[7]*inv*g1.w + b1.w);
  *(uint4*)(seq_bf + (size_t)r * 512 + c) = pk;
}

// ---------------- residual add + LayerNorm on bf16 stream ------------------
__global__ __launch_bounds__(256) void ln_add(
    ushort* __restrict__ seq_bf, const ushort* __restrict__ t1,
    const float* __restrict__ g, const float* __restrict__ bta) {
  int r = (blockIdx.x << 2) + (threadIdx.x >> 6);
  int lane = threadIdx.x & 63;
  int c = lane << 3;
  ushort* row = seq_bf + (size_t)r * 512 + c;
  uint4 sv = *(const uint4*)row;
  uint4 tv = *(const uint4*)(t1 + (size_t)r * 512 + c);
  float v[8] = {
    lo16(sv.x) + lo16(tv.x), hi16(sv.x) + hi16(tv.x),
    lo16(sv.y) + lo16(tv.y), hi16(sv.y) + hi16(tv.y),
    lo16(sv.z) + lo16(tv.z), hi16(sv.z) + hi16(tv.z),
    lo16(sv.w) + lo16(tv.w), hi16(sv.w) + hi16(tv.w) };
  float sum = v[0]+v[1]+v[2]+v[3]+v[4]+v[5]+v[6]+v[7];
#pragma unroll
  for (int off = 1; off < 64; off <<= 1) sum += __shfl_xor(sum, off);
  float mu = sum * (1.0f / 512.0f);
  float sq = 0.0f;
#pragma unroll
  for (int k = 0; k < 8; k++) { v[k] -= mu; sq += v[k] * v[k]; }
#pragma unroll
  for (int off = 1; off < 64; off <<= 1) sq += __shfl_xor(sq, off);
  float inv = rsqrtf(sq * (1.0f / 512.0f) + 1e-5f);
  float4 g0 = *(const float4*)&g[c],   g1 = *(const float4*)&g[c + 4];
  float4 b0 = *(const float4*)&bta[c], b1 = *(const float4*)&bta[c + 4];
  uint4 pk;
  pk.x = pack2(v[0]*inv*g0.x + b0.x, v[1]*inv*g0.y + b0.y);
  pk.y = pack2(v[2]*inv*g0.z + b0.z, v[3]*inv*g0.w + b0.w);
  pk.z = pack2(v[4]*inv*g1.x + b1.x, v[5]*inv*g1.y + b1.y);
  pk.w = pack2(v[6]*inv*g1.z + b1.z, v[7]*inv*g1.w + b1.w);
  *(uint4*)row = pk;
}

// ---------------- sparse pyramidal attention (wave-per-head, no LDS) -------
// Butterfly softmax: lane = (j2=lane>>2, c=lane&3); lane^{4,8,16,32} spans
// the 16 j2 groups with c fixed -> den = sum over j2 counted ONCE each.
__global__ __launch_bounds__(512) void attn_sparse(
    const ushort* __restrict__ qkv, ushort* __restrict__ o) {
  int r = blockIdx.x;
  int b = r / 1360, i = r - b * 1360;
  int h = threadIdx.x >> 6, lane = threadIdx.x & 63;
  int S, sz, li;
  if (i < 1024)      { li = 0; S = 0;    sz = 1024; }
  else if (i < 1280) { li = 1; S = 1024; sz = 256; }
  else if (i < 1344) { li = 2; S = 1280; sz = 64; }
  else               { li = 3; S = 1344; sz = 16; }
  int p = i - S;
  int lo = p - 2; if (lo < 0) lo = 0;
  int hi = p + 2; if (hi > sz - 1) hi = sz - 1;
  int cnt = hi - lo + 1;
  int nk = cnt + (li > 0 ? 4 : 0) + (li < 3 ? 1 : 0);
  int Sprev = (li == 1) ? 0 : (li == 2) ? 1024 : 1280;
  int Snext = (li == 0) ? 1024 : (li == 1) ? 1280 : 1344;
  int j2 = lane >> 2, c = lane & 3;
  int key;
  if (j2 < cnt)                      key = S + lo + j2;
  else if (li > 0 && j2 - cnt < 4)   key = Sprev + 4 * p + (j2 - cnt);
  else if (li < 3)                   key = Snext + (p >> 2);
  else                               key = S + p;
  float partial = 0.0f;
  {
    const uint4* qv = (const uint4*)(qkv + (size_t)r * 1536 + h * 64 + c * 16);
    const uint4* kv = (const uint4*)(qkv + (size_t)(b * 1360 + key) * 1536 + 512 + h * 64 + c * 16);
#pragma unroll
    for (int cc = 0; cc < 2; cc++) {
      uint4 a = qv[cc], k4 = kv[cc];
      partial = fmaf(lo16(a.x), lo16(k4.x), partial); partial = fmaf(hi16(a.x), hi16(k4.x), partial);
      partial = fmaf(lo16(a.y), lo16(k4.y), partial); partial = fmaf(hi16(a.y), hi16(k4.y), partial);
      partial = fmaf(lo16(a.z), lo16(k4.z), partial); partial = fmaf(hi16(a.z), hi16(k4.z), partial);
      partial = fmaf(lo16(a.w), lo16(k4.w), partial); partial = fmaf(hi16(a.w), hi16(k4.w), partial);
    }
  }
  partial += __shfl_xor(partial, 1);
  partial += __shfl_xor(partial, 2);
  float s = (j2 < nk) ? partial * 0.125f : -1e30f;
  float m = s;
  m = fmaxf(m, __shfl_xor(m, 4));
  m = fmaxf(m, __shfl_xor(m, 8));
  m = fmaxf(m, __shfl_xor(m, 16));
  m = fmaxf(m, __shfl_xor(m, 32));
  float ev = __expf(s - m);                  // 0 for idle j2 groups
  float den = ev;
  den += __shfl_xor(den, 4);
  den += __shfl_xor(den, 8);
  den += __shfl_xor(den, 16);
  den += __shfl_xor(den, 32);
  float inv = 1.0f / den;                    // den = sum over j2, once each
  float acc = 0.0f;
  for (int j = 0; j < nk; j++) {
    float pj = __shfl(ev, 4 * j) * inv;
    int kj = __shfl(key, 4 * j);
    float vv = bf2f(qkv[(size_t)(b * 1360 + kj) * 1536 + 1024 + h * 64 + lane]);
    acc = fmaf(pj, vv, acc);
  }
  o[(size_t)r * 512 + h * 64 + lane] = f2bf(acc);
}

// ---------------- output gather (bf16 stream -> f32 out), vectorized -------
__global__ __launch_bounds__(512) void gather_out(
    const ushort* __restrict__ seq_bf, float* __restrict__ out) {
  int bl = blockIdx.x;
  int b = bl >> 10, i = bl & 1023;
  int t = threadIdx.x;
  int q = t >> 7, e4 = (t & 127) << 2;
  int src_row = (q == 0) ? i
              : (q == 1) ? 1024 + (i >> 2)
              : (q == 2) ? 1280 + (i >> 4)
              :            1344 + (i >> 6);
  size_t base = (size_t)b * 1360;
  const ushort* sp = seq_bf + ((base + src_row) * 512 + e4);
  uint2 sv = *(const uint2*)sp;
  float4 ov;
  ov.x = lo16(sv.x); ov.y = hi16(sv.x);
  ov.z = lo16(sv.y); ov.w = hi16(sv.y);
  *(float4*)&out[(size_t)bl * 2048 + q * 512 + e4] = ov;
}

// ---------------------------------------------------------------------------
extern "C" void kernel_launch(void* const* d_in, const int* in_sizes, int n_in,
                              void* d_out, int out_size, void* d_ws, size_t ws_size,
                              hipStream_t stream) {
  const float* x_enc   = (const float*)d_in[0];
  const float* x_mark  = (const float*)d_in[1];
  const float* conv_w  = (const float*)d_in[2];
  const float* conv_b  = (const float*)d_in[3];
  const float* temp_w  = (const float*)d_in[4];
  const float* temp_b  = (const float*)d_in[5];
  const float* down_w  = (const float*)d_in[6];
  const float* down_b  = (const float*)d_in[7];
  const float* pyr_w   = (const float*)d_in[8];
  const float* pyr_b   = (const float*)d_in[9];
  const float* bn_g    = (const float*)d_in[10];
  const float* bn_b    = (const float*)d_in[11];
  const float* up_w    = (const float*)d_in[12];
  const float* up_b    = (const float*)d_in[13];
  const float* norm_g  = (const float*)d_in[14];
  const float* norm_b  = (const float*)d_in[15];
  const float* wq      = (const float*)d_in[16];
  const float* wk      = (const float*)d_in[17];
  const float* wv      = (const float*)d_in[18];
  const float* fc_w    = (const float*)d_in[19];
  const float* fc_b    = (const float*)d_in[20];
  const float* ln1_g   = (const float*)d_in[21];
  const float* ln1_b   = (const float*)d_in[22];
  const float* w1      = (const float*)d_in[23];
  const float* b1      = (const float*)d_in[24];
  const float* w2      = (const float*)d_in[25];
  const float* b2      = (const float*)d_in[26];
  const float* ln2_g   = (const float*)d_in[27];
  const float* ln2_b   = (const float*)d_in[28];

  // ---- workspace layout (f32-word offsets) ----
  float* ws = (float*)d_ws;
  float*  e       = ws;                        // [4096][512] f32
  ushort* e_bf    = (ushort*)(ws + 2097152);   // [4096][512] bf16
  ushort* tmp0_bf = (ushort*)(ws + 3145728);   // [4096][64] bf16
  ushort* pyrf_bf = (ushort*)(ws + 3276800);   // [1344][64] bf16
  ushort* pyru_bf = (ushort*)(ws + 3319808);   // [1344][512] bf16
  ushort* qkv_bf = (ushort*)ws;                // [5504][1536] bf16 (aliases)
  ushort* o_bf   = (ushort*)(ws + 4227072);    // [5504][512] bf16
  ushort* th_bf  = (ushort*)ws;                // [5504][2048] bf16
  ushort* t1     = (ushort*)(ws + 5636096);    // [5504][512] bf16
  ushort* dwt    = (ushort*)(ws + 7045120);    // down_w^T [64][512]
  ushort* uwt    = (ushort*)(ws + 7061504);    // up_w^T  [512][64]
  ushort* seq_bf = (ushort*)(ws + 11272192);   // [5504][512] bf16
  ushort* qkvw   = (ushort*)(ws + 12681216);   // 4 x [1536][512] bf16
  ushort* fcw    = (ushort*)(ws + 14254080);   // 4 x [512][512] bf16
  ushort* w1t    = (ushort*)(ws + 14778368);   // 4 x [2048][512] bf16
  ushort* w2t    = (ushort*)(ws + 16875520);   // 4 x [512][2048] bf16

  // ---- weight cast+transpose (once per call) ----
  dim3 tb(32, 8);
  transpose_cast<<<dim3(16, 16, 4), tb, 0, stream>>>(wq, qkvw,          512, 512,  262144, 786432);
  transpose_cast<<<dim3(16, 16, 4), tb, 0, stream>>>(wk, qkvw + 262144, 512, 512,  262144, 786432);
  transpose_cast<<<dim3(16, 16, 4), tb, 0, stream>>>(wv, qkvw + 524288, 512, 512,  262144, 786432);
  transpose_cast<<<dim3(16, 16, 4), tb, 0, stream>>>(fc_w, fcw,         512, 512,  262144, 262144);
  transpose_cast<<<dim3(64, 16, 4), tb, 0, stream>>>(w1, w1t,           512, 2048, 1048576, 1048576);
  transpose_cast<<<dim3(16, 64, 4), tb, 0, stream>>>(w2, w2t,           2048, 512, 1048576, 1048576);
  transpose_cast<<<dim3(2, 16, 1), tb, 0, stream>>>(down_w, dwt,        512, 64,   0, 0);
  transpose_cast<<<dim3(16, 2, 1), tb, 0, stream>>>(up_w, uwt,          64, 512,   0, 0);

  // ---- prologue (all-bf16 MFMA path) ----
  embed_kernel<<<4096, 512, 0, stream>>>(x_enc, x_mark, conv_w, conv_b,
                                         temp_w, temp_b, e, e_bf);
  gemm_bf16_t32<<<128, 256, 0, stream>>>(e_bf, dwt, down_b, tmp0_bf, 64, 512);
  pyr_conv<<<4 * 256, 64, 0, stream>>>(tmp0_bf, 0, 1024, pyrf_bf, 0, 336, 256,
                                       pyr_w, pyr_b, bn_g, bn_b);
  pyr_conv<<<4 * 64, 64, 0, stream>>>(pyrf_bf, 0, 336, pyrf_bf, 256, 336, 64,
                                      pyr_w + 16384, pyr_b + 64, bn_g + 64, bn_b + 64);
  pyr_conv<<<4 * 16, 64, 0, stream>>>(pyrf_bf, 256, 336, pyrf_bf, 320, 336, 16,
                                      pyr_w + 32768, pyr_b + 128, bn_g + 128, bn_b + 128);
  gemm_bf16_t32<<<8 * 42, 256, 0, stream>>>(pyrf_bf, uwt, up_b, pyru_bf, 512, 64);
  ln_concat<<<1360, 256, 0, stream>>>(e, pyru_bf, norm_g, norm_b, seq_bf);

  // ---- layers ----
  for (int l = 0; l < 4; l++) {
    gemm_bf16_t64w8<<<24 * 86, 512, 0, stream>>>(seq_bf, qkvw + (size_t)l * 786432,
                                                 nullptr, qkv_bf, 1536, 512, 0);
    attn_sparse<<<5440, 512, 0, stream>>>(qkv_bf, o_bf);
    gemm_bf16_t32<<<8 * 172, 256, 0, stream>>>(o_bf, fcw + (size_t)l * 262144,
                                               fc_b + l * 512, t1, 512, 512);
    ln_add<<<1360, 256, 0, stream>>>(seq_bf, t1, ln1_g + l * 512, ln1_b + l * 512);
    gemm_bf16_t64w8<<<32 * 86, 512, 0, stream>>>(seq_bf, w1t + (size_t)l * 1048576,
                                                 b1 + l * 2048, th_bf, 2048, 512, 1);
    gemm_bf16_t32<<<8 * 172, 256, 0, stream>>>(th_bf, w2t + (size_t)l * 1048576,
                                               b2 + l * 512, t1, 512, 2048);
    ln_add<<<1360, 256, 0, stream>>>(seq_bf, t1, ln2_g + l * 512, ln2_b + l * 512);
  }
  gather_out<<<4096, 512, 0, stream>>>(seq_bf, (float*)d_out);
}